// Round 1
// baseline (415.951 us; speedup 1.0000x reference)
//
#include <hip/hip_runtime.h>
#include <cstdint>
#include <cstddef>

#define B_ 16
#define C_ 256
#define HW_ 9216
#define S_ 128
#define N_ 64
#define KSPLIT 12
#define LCHUNK 768

typedef __attribute__((ext_vector_type(8))) short bf16x8;
typedef __attribute__((ext_vector_type(4))) float f32x4;
typedef __attribute__((ext_vector_type(2))) float f32x2;
typedef __attribute__((ext_vector_type(8))) unsigned short u16x8;

__device__ __forceinline__ unsigned short f2bf(float f) {
    unsigned int u = __builtin_bit_cast(unsigned int, f);
    u += 0x7fffu + ((u >> 16) & 1u);   // RNE; inputs are finite
    return (unsigned short)(u >> 16);
}

// ---------------------------------------------------------------------------
// K0: fold conv bias + BN into per-channel (scale, beta); bf16-ify combined
// projection weights Wc[256][256] (rows 0..127 = w_s, 128..191 = w_p,
// 192..255 = w_r); precompute output-BN scale/beta.
// ---------------------------------------------------------------------------
__global__ void k0_prep(
    const float* __restrict__ w_s, const float* __restrict__ w_p, const float* __restrict__ w_r,
    const float* __restrict__ b_s, const float* __restrict__ g_s, const float* __restrict__ bb_s,
    const float* __restrict__ m_s, const float* __restrict__ v_s,
    const float* __restrict__ b_p, const float* __restrict__ g_p, const float* __restrict__ bb_p,
    const float* __restrict__ m_p, const float* __restrict__ v_p,
    const float* __restrict__ b_r, const float* __restrict__ g_r, const float* __restrict__ bb_r,
    const float* __restrict__ m_r, const float* __restrict__ v_r,
    const float* __restrict__ og, const float* __restrict__ ob,
    const float* __restrict__ om, const float* __restrict__ ov,
    unsigned short* __restrict__ Wc, float* __restrict__ pscale, float* __restrict__ pbeta,
    float* __restrict__ oscale, float* __restrict__ obeta)
{
    const int gid = blockIdx.x * 256 + threadIdx.x;   // 0..65535
    const int oc = gid >> 8, c = gid & 255;
    const float* wsrc;
    if (oc < 128)      wsrc = w_s + oc * 256;
    else if (oc < 192) wsrc = w_p + (oc - 128) * 256;
    else               wsrc = w_r + (oc - 192) * 256;
    Wc[gid] = f2bf(wsrc[c]);
    if (gid < 256) {
        int i; const float *bp, *gp, *bbp, *mp, *vp;
        if (gid < 128)      { i = gid;       bp = b_s; gp = g_s; bbp = bb_s; mp = m_s; vp = v_s; }
        else if (gid < 192) { i = gid - 128; bp = b_p; gp = g_p; bbp = bb_p; mp = m_p; vp = v_p; }
        else                { i = gid - 192; bp = b_r; gp = g_r; bbp = bb_r; mp = m_r; vp = v_r; }
        const float sc = gp[i] / sqrtf(vp[i] + 1e-5f);
        pscale[gid] = sc;
        pbeta[gid]  = (bp[i] - mp[i]) * sc + bbp[i];
        const float so = og[gid] / sqrtf(ov[gid] + 1e-5f);
        oscale[gid] = so;
        obeta[gid]  = ob[gid] - om[gid] * so;
    }
}

// ---------------------------------------------------------------------------
// K1: fused projection GEMM.  out[oc][l] = relu(scale[oc]*(Wc[oc,:]·x[:,l]) + beta[oc])
// xs/xp -> xsp[b][oc][l] (oc 0..191);  xr -> xrt[b][l][n] TRANSPOSED (oc 192..255).
// Tiles: BM=128 (oc), BN=128 (l), BK=64 (c).  4 waves 2x2, 64x64 per wave.
// ---------------------------------------------------------------------------
__global__ __launch_bounds__(256) void k1_proj(
    const float* __restrict__ x, const unsigned short* __restrict__ Wc,
    const float* __restrict__ pscale, const float* __restrict__ pbeta,
    unsigned short* __restrict__ xsp, unsigned short* __restrict__ xrt)
{
    __shared__ unsigned short Alds[128 * 72];   // W tile [128 oc][64 c], pad stride 72
    __shared__ unsigned short Blds[64 * 132];   // x tile [64 c][128 l],  pad stride 132
    const int t = threadIdx.x;
    const int lane = t & 63;
    const int w = t >> 6;
    const int wr = w >> 1, wc = w & 1;
    const int l0 = blockIdx.x * 128;
    const int moff = blockIdx.y * 128;
    const int b = blockIdx.z;
    const float* xb = x + (size_t)b * C_ * HW_;

    f32x4 acc[4][4] = {};

    for (int kt = 0; kt < 4; ++kt) {
        const int k0 = kt * 64;
        {   // stage A (weights, bf16, k-contiguous rows)
            const int cq = (t & 15) * 4;
            const int rr = t >> 4;
            #pragma unroll
            for (int i = 0; i < 8; ++i) {
                const int r = rr + i * 16;
                *(ushort4*)&Alds[r * 72 + cq] =
                    *(const ushort4*)(Wc + (moff + r) * 256 + k0 + cq);
            }
        }
        {   // stage B (x fp32 -> bf16), natural [c][l] layout, coalesced
            const int lq = t & 31;
            const int c0 = t >> 5;
            #pragma unroll
            for (int i = 0; i < 8; ++i) {
                const int c = c0 + i * 8;
                const float4 v = *(const float4*)(xb + (size_t)(k0 + c) * HW_ + l0 + lq * 4);
                ushort4 h;
                h.x = f2bf(v.x); h.y = f2bf(v.y); h.z = f2bf(v.z); h.w = f2bf(v.w);
                *(ushort4*)&Blds[c * 132 + lq * 4] = h;
            }
        }
        __syncthreads();
        #pragma unroll
        for (int ks = 0; ks < 2; ++ks) {
            const int kg = ks * 32 + (lane >> 4) * 8;
            bf16x8 a[4];
            const int mrow = wr * 64 + (lane & 15);
            #pragma unroll
            for (int mi = 0; mi < 4; ++mi)
                a[mi] = *(const bf16x8*)&Alds[(mrow + mi * 16) * 72 + kg];
            const int nc = wc * 64 + (lane & 15);
            bf16x8 bv[4];
            #pragma unroll
            for (int ni = 0; ni < 4; ++ni) {
                bf16x8 tmp;
                #pragma unroll
                for (int j = 0; j < 8; ++j)
                    tmp[j] = (short)Blds[(kg + j) * 132 + nc + ni * 16];
                bv[ni] = tmp;
            }
            #pragma unroll
            for (int mi = 0; mi < 4; ++mi)
                #pragma unroll
                for (int ni = 0; ni < 4; ++ni)
                    acc[mi][ni] = __builtin_amdgcn_mfma_f32_16x16x32_bf16(a[mi], bv[ni], acc[mi][ni], 0, 0, 0);
        }
        __syncthreads();
    }
    // epilogue: BN-affine + relu, bf16 stores
    const int lf = lane & 15;
    const int r4 = (lane >> 4) * 4;
    #pragma unroll
    for (int mi = 0; mi < 4; ++mi) {
        const int oc0 = moff + wr * 64 + mi * 16 + r4;
        float sc[4], bt[4];
        #pragma unroll
        for (int r = 0; r < 4; ++r) { sc[r] = pscale[oc0 + r]; bt[r] = pbeta[oc0 + r]; }
        #pragma unroll
        for (int ni = 0; ni < 4; ++ni) {
            const int l = l0 + wc * 64 + ni * 16 + lf;
            if (oc0 < 192) {        // xs / xp  ->  [b][oc][l]
                #pragma unroll
                for (int r = 0; r < 4; ++r) {
                    float y = acc[mi][ni][r] * sc[r] + bt[r];
                    y = y > 0.f ? y : 0.f;
                    xsp[((size_t)b * 192 + oc0 + r) * HW_ + l] = f2bf(y);
                }
            } else {                // xr -> transposed [b][l][n], packed 8B store
                ushort4 pk;
                float y0 = acc[mi][ni][0] * sc[0] + bt[0];
                float y1 = acc[mi][ni][1] * sc[1] + bt[1];
                float y2 = acc[mi][ni][2] * sc[2] + bt[2];
                float y3 = acc[mi][ni][3] * sc[3] + bt[3];
                pk.x = f2bf(y0 > 0.f ? y0 : 0.f);
                pk.y = f2bf(y1 > 0.f ? y1 : 0.f);
                pk.z = f2bf(y2 > 0.f ? y2 : 0.f);
                pk.w = f2bf(y3 > 0.f ? y3 : 0.f);
                *(ushort4*)&xrt[((size_t)b * HW_ + l) * 64 + (oc0 - 192)] = pk;
            }
        }
    }
}

// ---------------------------------------------------------------------------
// K2: Gram partials.  gpart[ck][b][s][n] = sum over L-chunk of xs[s,l]*xp[n,l]
// Both operands naturally k(=l)-contiguous -> all-b128 LDS fragment reads.
// ---------------------------------------------------------------------------
__global__ __launch_bounds__(256) void k2_gram(
    const unsigned short* __restrict__ xsp, float* __restrict__ gpart)
{
    __shared__ unsigned short As[128 * 136];  // xs [128 s][128 l] pad 136
    __shared__ unsigned short Bs[64 * 136];   // xp [ 64 n][128 l] pad 136
    const int t = threadIdx.x;
    const int lane = t & 63;
    const int w = t >> 6;
    const int ck = blockIdx.x;
    const int b = blockIdx.y;

    f32x4 acc[2][4] = {};

    for (int it = 0; it < 6; ++it) {
        const int lg = ck * LCHUNK + it * 128;
        {
            const int rr = t >> 4;
            const int lq = (t & 15) * 8;
            #pragma unroll
            for (int i = 0; i < 8; ++i) {
                const int s = rr + 16 * i;
                *(u16x8*)&As[s * 136 + lq] =
                    *(const u16x8*)(xsp + ((size_t)b * 192 + s) * HW_ + lg + lq);
            }
            #pragma unroll
            for (int i = 0; i < 4; ++i) {
                const int n = rr + 16 * i;
                *(u16x8*)&Bs[n * 136 + lq] =
                    *(const u16x8*)(xsp + ((size_t)b * 192 + 128 + n) * HW_ + lg + lq);
            }
        }
        __syncthreads();
        #pragma unroll
        for (int ks = 0; ks < 4; ++ks) {
            const int kg = ks * 32 + (lane >> 4) * 8;
            bf16x8 a[2], bv[4];
            #pragma unroll
            for (int mi = 0; mi < 2; ++mi)
                a[mi] = *(const bf16x8*)&As[(w * 32 + mi * 16 + (lane & 15)) * 136 + kg];
            #pragma unroll
            for (int ni = 0; ni < 4; ++ni)
                bv[ni] = *(const bf16x8*)&Bs[(ni * 16 + (lane & 15)) * 136 + kg];
            #pragma unroll
            for (int mi = 0; mi < 2; ++mi)
                #pragma unroll
                for (int ni = 0; ni < 4; ++ni)
                    acc[mi][ni] = __builtin_amdgcn_mfma_f32_16x16x32_bf16(a[mi], bv[ni], acc[mi][ni], 0, 0, 0);
        }
        __syncthreads();
    }
    float* gp = gpart + (size_t)(ck * 16 + b) * (S_ * N_);
    const int lf = lane & 15, r4 = (lane >> 4) * 4;
    #pragma unroll
    for (int mi = 0; mi < 2; ++mi)
        #pragma unroll
        for (int ni = 0; ni < 4; ++ni)
            #pragma unroll
            for (int r = 0; r < 4; ++r) {
                const int s = w * 32 + mi * 16 + r4 + r;
                const int n = ni * 16 + lf;
                gp[s * 64 + n] = acc[mi][ni][r];
            }
}

// ---------------------------------------------------------------------------
// K_gcn: per-batch: reduce partials -> g; two GCN passes; hc = fc2 · g2 (the
// fc2-folding).  One block per batch, 1024 threads, everything in LDS (64KB).
// ---------------------------------------------------------------------------
__global__ __launch_bounds__(1024) void k_gcn(
    const float* __restrict__ gpart,
    const float* __restrict__ w1a, const float* __restrict__ b1a, const float* __restrict__ w2a,
    const float* __restrict__ w1b, const float* __restrict__ b1b, const float* __restrict__ w2b,
    const float* __restrict__ fc2w, unsigned short* __restrict__ hc)
{
    __shared__ float bufA[S_ * N_];   // 32KB
    __shared__ float bufB[S_ * N_];   // 32KB
    const int b = blockIdx.x;
    const int t = threadIdx.x;
    const int m = t & 63;        // lane-parallel column
    const int rg = t >> 6;       // 0..15 wave row-group (wave-uniform)

    // reduce K-split partials, apply 1/HW
    #pragma unroll
    for (int i = 0; i < 8; ++i) {
        const int idx = t + i * 1024;
        float s = 0.f;
        #pragma unroll
        for (int ck = 0; ck < KSPLIT; ++ck)
            s += gpart[(size_t)(ck * 16 + b) * (S_ * N_) + idx];
        bufA[idx] = s * (1.0f / (float)HW_);
    }
    __syncthreads();

    for (int pass = 0; pass < 2; ++pass) {
        const float* w1 = pass ? w1b : w1a;
        const float* b1 = pass ? b1b : b1a;
        const float* w2 = pass ? w2b : w2a;
        {   // node mix: bufB[s][m] = leaky( sum_n bufA[s][n]*w1[m][n] + b1[m] + bufA[s][m] )
            const float bm = b1[m];
            f32x2 accv[4] = {};
            for (int n = 0; n < 64; ++n) {
                const float wv = w1[m * 64 + n];
                f32x2 wv2; wv2[0] = wv; wv2[1] = wv;
                #pragma unroll
                for (int j = 0; j < 4; ++j) {
                    f32x2 gv;
                    gv[0] = bufA[(rg + 16 * (2 * j)) * 64 + n];
                    gv[1] = bufA[(rg + 16 * (2 * j + 1)) * 64 + n];
                    accv[j] += gv * wv2;
                }
            }
            #pragma unroll
            for (int j = 0; j < 4; ++j)
                #pragma unroll
                for (int e = 0; e < 2; ++e) {
                    const int s = rg + 16 * (2 * j + e);
                    const float v = accv[j][e] + bm + bufA[s * 64 + m];
                    bufB[s * 64 + m] = v > 0.f ? v : 0.2f * v;
                }
        }
        __syncthreads();
        {   // state mix: bufA[tt][m] = sum_s w2[tt][s] * bufB[s][m]
            f32x2 accv[4] = {};
            for (int s = 0; s < 128; ++s) {
                const float hv = bufB[s * 64 + m];
                f32x2 hv2; hv2[0] = hv; hv2[1] = hv;
                #pragma unroll
                for (int j = 0; j < 4; ++j) {
                    f32x2 wv;
                    wv[0] = w2[(rg + 16 * (2 * j)) * 128 + s];
                    wv[1] = w2[(rg + 16 * (2 * j + 1)) * 128 + s];
                    accv[j] += wv * hv2;
                }
            }
            #pragma unroll
            for (int j = 0; j < 4; ++j)
                #pragma unroll
                for (int e = 0; e < 2; ++e)
                    bufA[(rg + 16 * (2 * j + e)) * 64 + m] = accv[j][e];
        }
        __syncthreads();
    }
    {   // hc[c][n] = sum_s fc2w[c][s] * bufA[s][n]   (fc2-folding)
        f32x2 accv[8] = {};
        for (int s = 0; s < 128; ++s) {
            const float hv = bufA[s * 64 + m];
            f32x2 hv2; hv2[0] = hv; hv2[1] = hv;
            #pragma unroll
            for (int j = 0; j < 8; ++j) {
                f32x2 wv;
                wv[0] = fc2w[(rg + 16 * (2 * j)) * 128 + s];
                wv[1] = fc2w[(rg + 16 * (2 * j + 1)) * 128 + s];
                accv[j] += wv * hv2;
            }
        }
        #pragma unroll
        for (int j = 0; j < 8; ++j)
            #pragma unroll
            for (int e = 0; e < 2; ++e) {
                const int c = rg + 16 * (2 * j + e);
                hc[((size_t)b * 256 + c) * 64 + m] = f2bf(accv[j][e]);
            }
    }
}

// ---------------------------------------------------------------------------
// K3: out[b][c][l] = x[b][c][l] + oscale[c] * (sum_n hc[b][c][n]*xr[n][l]) + obeta[c]
// GEMM M=256(c), N=HW(l), K=64(n).  xr is pre-transposed so B-frags are b128.
// ---------------------------------------------------------------------------
__global__ __launch_bounds__(256) void k3_out(
    const float* __restrict__ x, const unsigned short* __restrict__ hc,
    const unsigned short* __restrict__ xrt,
    const float* __restrict__ oscale, const float* __restrict__ obeta,
    float* __restrict__ out)
{
    __shared__ unsigned short Alds[128 * 72];  // hc  [128 c][64 n] pad 72
    __shared__ unsigned short Blds[128 * 72];  // xrt [128 l][64 n] pad 72
    const int t = threadIdx.x;
    const int lane = t & 63;
    const int w = t >> 6;
    const int wr = w >> 1, wc = w & 1;
    const int l0 = blockIdx.x * 128;
    const int moff = blockIdx.y * 128;
    const int b = blockIdx.z;
    {
        const int rr = t >> 3;        // 0..31
        const int nq = (t & 7) * 8;
        #pragma unroll
        for (int i = 0; i < 4; ++i) {
            const int r = rr + 32 * i;
            *(u16x8*)&Alds[r * 72 + nq] =
                *(const u16x8*)(hc + ((size_t)b * 256 + moff + r) * 64 + nq);
            *(u16x8*)&Blds[r * 72 + nq] =
                *(const u16x8*)(xrt + ((size_t)b * HW_ + l0 + r) * 64 + nq);
        }
    }
    __syncthreads();
    f32x4 acc[4][4] = {};
    #pragma unroll
    for (int ks = 0; ks < 2; ++ks) {
        const int kg = ks * 32 + (lane >> 4) * 8;
        bf16x8 a[4], bv[4];
        #pragma unroll
        for (int mi = 0; mi < 4; ++mi)
            a[mi] = *(const bf16x8*)&Alds[(wr * 64 + mi * 16 + (lane & 15)) * 72 + kg];
        #pragma unroll
        for (int ni = 0; ni < 4; ++ni)
            bv[ni] = *(const bf16x8*)&Blds[(wc * 64 + ni * 16 + (lane & 15)) * 72 + kg];
        #pragma unroll
        for (int mi = 0; mi < 4; ++mi)
            #pragma unroll
            for (int ni = 0; ni < 4; ++ni)
                acc[mi][ni] = __builtin_amdgcn_mfma_f32_16x16x32_bf16(a[mi], bv[ni], acc[mi][ni], 0, 0, 0);
    }
    const int lf = lane & 15, r4 = (lane >> 4) * 4;
    #pragma unroll
    for (int mi = 0; mi < 4; ++mi) {
        const int c0 = moff + wr * 64 + mi * 16 + r4;
        float sc[4], bt[4];
        #pragma unroll
        for (int r = 0; r < 4; ++r) { sc[r] = oscale[c0 + r]; bt[r] = obeta[c0 + r]; }
        #pragma unroll
        for (int ni = 0; ni < 4; ++ni) {
            const int l = l0 + wc * 64 + ni * 16 + lf;
            #pragma unroll
            for (int r = 0; r < 4; ++r) {
                const size_t idx = ((size_t)b * 256 + c0 + r) * HW_ + l;
                out[idx] = x[idx] + acc[mi][ni][r] * sc[r] + bt[r];
            }
        }
    }
}

// ---------------------------------------------------------------------------
extern "C" void kernel_launch(void* const* d_in, const int* in_sizes, int n_in,
                              void* d_out, int out_size, void* d_ws, size_t ws_size,
                              hipStream_t stream) {
    (void)in_sizes; (void)n_in; (void)out_size;
    const float* x     = (const float*)d_in[0];
    const float* w_s   = (const float*)d_in[1];
    const float* b_s   = (const float*)d_in[2];
    const float* g_s   = (const float*)d_in[3];
    const float* bb_s  = (const float*)d_in[4];
    const float* m_s   = (const float*)d_in[5];
    const float* v_s   = (const float*)d_in[6];
    const float* w_p   = (const float*)d_in[7];
    const float* b_p   = (const float*)d_in[8];
    const float* g_p   = (const float*)d_in[9];
    const float* bb_p  = (const float*)d_in[10];
    const float* m_p   = (const float*)d_in[11];
    const float* v_p   = (const float*)d_in[12];
    const float* w_r   = (const float*)d_in[13];
    const float* b_r   = (const float*)d_in[14];
    const float* g_r   = (const float*)d_in[15];
    const float* bb_r  = (const float*)d_in[16];
    const float* m_r   = (const float*)d_in[17];
    const float* v_r   = (const float*)d_in[18];
    const float* g1w1  = (const float*)d_in[19];
    const float* g1b1  = (const float*)d_in[20];
    const float* g1w2  = (const float*)d_in[21];
    const float* g2w1  = (const float*)d_in[22];
    const float* g2b1  = (const float*)d_in[23];
    const float* g2w2  = (const float*)d_in[24];
    const float* fc2w  = (const float*)d_in[25];
    const float* bn_og = (const float*)d_in[26];
    const float* bn_ob = (const float*)d_in[27];
    const float* bn_om = (const float*)d_in[28];
    const float* bn_ov = (const float*)d_in[29];

    char* ws = (char*)d_ws;
    unsigned short* Wc = (unsigned short*)(ws + 0);          // 131072 B
    float* pscale = (float*)(ws + 131072);
    float* pbeta  = (float*)(ws + 132096);
    float* oscale = (float*)(ws + 133120);
    float* obeta  = (float*)(ws + 134144);
    const size_t o_fix = 135168;
    const size_t sz_xsp = (size_t)B_ * 192 * HW_ * 2;        // 56,623,104
    const size_t sz_xrt = (size_t)B_ * HW_ * 64 * 2;         // 18,874,368
    const size_t sz_gp  = (size_t)KSPLIT * B_ * S_ * N_ * 4; //  6,291,456
    const size_t sz_hc  = (size_t)B_ * 256 * 64 * 2;         //    524,288
    const size_t need_full = o_fix + sz_xsp + sz_xrt + sz_gp + sz_hc;

    unsigned short* xsp; size_t o2;
    if (ws_size >= need_full) { xsp = (unsigned short*)(ws + o_fix); o2 = o_fix + sz_xsp; }
    else { // fall back: stash xs/xp in d_out (K3 fully overwrites d_out afterwards)
        xsp = (unsigned short*)d_out; o2 = o_fix;
    }
    unsigned short* xrt = (unsigned short*)(ws + o2);
    float* gpart        = (float*)(ws + o2 + sz_xrt);
    unsigned short* hc  = (unsigned short*)(ws + o2 + sz_xrt + sz_gp);

    k0_prep<<<256, 256, 0, stream>>>(
        w_s, w_p, w_r,
        b_s, g_s, bb_s, m_s, v_s,
        b_p, g_p, bb_p, m_p, v_p,
        b_r, g_r, bb_r, m_r, v_r,
        bn_og, bn_ob, bn_om, bn_ov,
        Wc, pscale, pbeta, oscale, obeta);

    k1_proj<<<dim3(72, 2, 16), 256, 0, stream>>>(x, Wc, pscale, pbeta, xsp, xrt);

    k2_gram<<<dim3(KSPLIT, 16), 256, 0, stream>>>(xsp, gpart);

    k_gcn<<<16, 1024, 0, stream>>>(gpart, g1w1, g1b1, g1w2, g2w1, g2b1, g2w2, fc2w, hc);

    k3_out<<<dim3(72, 2, 16), 256, 0, stream>>>(x, hc, xrt, oscale, obeta, (float*)d_out);
}

// Round 2
// 235.990 us; speedup vs baseline: 1.7626x; 1.7626x over previous
//
#include <hip/hip_runtime.h>
#include <cstdint>
#include <cstddef>

#define B_ 16
#define C_ 256
#define HW_ 9216
#define S_ 128
#define N_ 64
#define KSPLIT 12
#define LCHUNK 768

typedef __attribute__((ext_vector_type(8))) short bf16x8;
typedef __attribute__((ext_vector_type(4))) float f32x4;
typedef __attribute__((ext_vector_type(2))) float f32x2;
typedef __attribute__((ext_vector_type(8))) unsigned short u16x8;

__device__ __forceinline__ unsigned short f2bf(float f) {
    unsigned int u = __builtin_bit_cast(unsigned int, f);
    u += 0x7fffu + ((u >> 16) & 1u);   // RNE; inputs are finite
    return (unsigned short)(u >> 16);
}
__device__ __forceinline__ float bf2f(unsigned short u) {
    unsigned int x = ((unsigned int)u) << 16;
    return __builtin_bit_cast(float, x);
}

// ---------------------------------------------------------------------------
// K0: fold conv bias + BN into per-channel (scale, beta); bf16-ify combined
// projection weights Wc[256][256]; precompute output-BN scale/beta.
// ---------------------------------------------------------------------------
__global__ void k0_prep(
    const float* __restrict__ w_s, const float* __restrict__ w_p, const float* __restrict__ w_r,
    const float* __restrict__ b_s, const float* __restrict__ g_s, const float* __restrict__ bb_s,
    const float* __restrict__ m_s, const float* __restrict__ v_s,
    const float* __restrict__ b_p, const float* __restrict__ g_p, const float* __restrict__ bb_p,
    const float* __restrict__ m_p, const float* __restrict__ v_p,
    const float* __restrict__ b_r, const float* __restrict__ g_r, const float* __restrict__ bb_r,
    const float* __restrict__ m_r, const float* __restrict__ v_r,
    const float* __restrict__ og, const float* __restrict__ ob,
    const float* __restrict__ om, const float* __restrict__ ov,
    unsigned short* __restrict__ Wc, float* __restrict__ pscale, float* __restrict__ pbeta,
    float* __restrict__ oscale, float* __restrict__ obeta)
{
    const int gid = blockIdx.x * 256 + threadIdx.x;   // 0..65535
    const int oc = gid >> 8, c = gid & 255;
    const float* wsrc;
    if (oc < 128)      wsrc = w_s + oc * 256;
    else if (oc < 192) wsrc = w_p + (oc - 128) * 256;
    else               wsrc = w_r + (oc - 192) * 256;
    Wc[gid] = f2bf(wsrc[c]);
    if (gid < 256) {
        int i; const float *bp, *gp, *bbp, *mp, *vp;
        if (gid < 128)      { i = gid;       bp = b_s; gp = g_s; bbp = bb_s; mp = m_s; vp = v_s; }
        else if (gid < 192) { i = gid - 128; bp = b_p; gp = g_p; bbp = bb_p; mp = m_p; vp = v_p; }
        else                { i = gid - 192; bp = b_r; gp = g_r; bbp = bb_r; mp = m_r; vp = v_r; }
        const float sc = gp[i] / sqrtf(vp[i] + 1e-5f);
        pscale[gid] = sc;
        pbeta[gid]  = (bp[i] - mp[i]) * sc + bbp[i];
        const float so = og[gid] / sqrtf(ov[gid] + 1e-5f);
        oscale[gid] = so;
        obeta[gid]  = ob[gid] - om[gid] * so;
    }
}

// ---------------------------------------------------------------------------
// K0b: bf16-ify the GCN + fc2 weights into one flat buffer.
// layout (elements): [0)w1a 4096 | [4096)w2a 16384 | [20480)w1b 4096 |
//                    [24576)w2b 16384 | [40960)fc2 32768   total 73728
// ---------------------------------------------------------------------------
__global__ void k0b_wbf(
    const float* __restrict__ g1w1, const float* __restrict__ g1w2,
    const float* __restrict__ g2w1, const float* __restrict__ g2w2,
    const float* __restrict__ fc2w, unsigned short* __restrict__ wbf)
{
    const int gid = blockIdx.x * 256 + threadIdx.x;   // 0..73727
    float v;
    if (gid < 4096)       v = g1w1[gid];
    else if (gid < 20480) v = g1w2[gid - 4096];
    else if (gid < 24576) v = g2w1[gid - 20480];
    else if (gid < 40960) v = g2w2[gid - 24576];
    else                  v = fc2w[gid - 40960];
    wbf[gid] = f2bf(v);
}

// ---------------------------------------------------------------------------
// K1: fused projection GEMM.  out[oc][l] = relu(scale[oc]*(Wc[oc,:]·x[:,l]) + beta[oc])
// xs/xp -> xsp[b][oc][l] (oc 0..191);  xr -> xrt[b][l][n] TRANSPOSED (oc 192..255).
// ---------------------------------------------------------------------------
__global__ __launch_bounds__(256) void k1_proj(
    const float* __restrict__ x, const unsigned short* __restrict__ Wc,
    const float* __restrict__ pscale, const float* __restrict__ pbeta,
    unsigned short* __restrict__ xsp, unsigned short* __restrict__ xrt)
{
    __shared__ unsigned short Alds[128 * 72];   // W tile [128 oc][64 c], pad stride 72
    __shared__ unsigned short Blds[64 * 132];   // x tile [64 c][128 l],  pad stride 132
    const int t = threadIdx.x;
    const int lane = t & 63;
    const int w = t >> 6;
    const int wr = w >> 1, wc = w & 1;
    const int l0 = blockIdx.x * 128;
    const int moff = blockIdx.y * 128;
    const int b = blockIdx.z;
    const float* xb = x + (size_t)b * C_ * HW_;

    f32x4 acc[4][4] = {};

    for (int kt = 0; kt < 4; ++kt) {
        const int k0 = kt * 64;
        {   // stage A (weights, bf16, k-contiguous rows)
            const int cq = (t & 15) * 4;
            const int rr = t >> 4;
            #pragma unroll
            for (int i = 0; i < 8; ++i) {
                const int r = rr + i * 16;
                *(ushort4*)&Alds[r * 72 + cq] =
                    *(const ushort4*)(Wc + (moff + r) * 256 + k0 + cq);
            }
        }
        {   // stage B (x fp32 -> bf16), natural [c][l] layout, coalesced
            const int lq = t & 31;
            const int c0 = t >> 5;
            #pragma unroll
            for (int i = 0; i < 8; ++i) {
                const int c = c0 + i * 8;
                const float4 v = *(const float4*)(xb + (size_t)(k0 + c) * HW_ + l0 + lq * 4);
                ushort4 h;
                h.x = f2bf(v.x); h.y = f2bf(v.y); h.z = f2bf(v.z); h.w = f2bf(v.w);
                *(ushort4*)&Blds[c * 132 + lq * 4] = h;
            }
        }
        __syncthreads();
        #pragma unroll
        for (int ks = 0; ks < 2; ++ks) {
            const int kg = ks * 32 + (lane >> 4) * 8;
            bf16x8 a[4];
            const int mrow = wr * 64 + (lane & 15);
            #pragma unroll
            for (int mi = 0; mi < 4; ++mi)
                a[mi] = *(const bf16x8*)&Alds[(mrow + mi * 16) * 72 + kg];
            const int nc = wc * 64 + (lane & 15);
            bf16x8 bv[4];
            #pragma unroll
            for (int ni = 0; ni < 4; ++ni) {
                bf16x8 tmp;
                #pragma unroll
                for (int j = 0; j < 8; ++j)
                    tmp[j] = (short)Blds[(kg + j) * 132 + nc + ni * 16];
                bv[ni] = tmp;
            }
            #pragma unroll
            for (int mi = 0; mi < 4; ++mi)
                #pragma unroll
                for (int ni = 0; ni < 4; ++ni)
                    acc[mi][ni] = __builtin_amdgcn_mfma_f32_16x16x32_bf16(a[mi], bv[ni], acc[mi][ni], 0, 0, 0);
        }
        __syncthreads();
    }
    // epilogue: BN-affine + relu, bf16 stores
    const int lf = lane & 15;
    const int r4 = (lane >> 4) * 4;
    #pragma unroll
    for (int mi = 0; mi < 4; ++mi) {
        const int oc0 = moff + wr * 64 + mi * 16 + r4;
        float sc[4], bt[4];
        #pragma unroll
        for (int r = 0; r < 4; ++r) { sc[r] = pscale[oc0 + r]; bt[r] = pbeta[oc0 + r]; }
        #pragma unroll
        for (int ni = 0; ni < 4; ++ni) {
            const int l = l0 + wc * 64 + ni * 16 + lf;
            if (oc0 < 192) {        // xs / xp  ->  [b][oc][l]
                #pragma unroll
                for (int r = 0; r < 4; ++r) {
                    float y = acc[mi][ni][r] * sc[r] + bt[r];
                    y = y > 0.f ? y : 0.f;
                    xsp[((size_t)b * 192 + oc0 + r) * HW_ + l] = f2bf(y);
                }
            } else {                // xr -> transposed [b][l][n], packed 8B store
                ushort4 pk;
                float y0 = acc[mi][ni][0] * sc[0] + bt[0];
                float y1 = acc[mi][ni][1] * sc[1] + bt[1];
                float y2 = acc[mi][ni][2] * sc[2] + bt[2];
                float y3 = acc[mi][ni][3] * sc[3] + bt[3];
                pk.x = f2bf(y0 > 0.f ? y0 : 0.f);
                pk.y = f2bf(y1 > 0.f ? y1 : 0.f);
                pk.z = f2bf(y2 > 0.f ? y2 : 0.f);
                pk.w = f2bf(y3 > 0.f ? y3 : 0.f);
                *(ushort4*)&xrt[((size_t)b * HW_ + l) * 64 + (oc0 - 192)] = pk;
            }
        }
    }
}

// ---------------------------------------------------------------------------
// K2: Gram partials.  gpart[ck][b][s][n] = sum over L-chunk of xs[s,l]*xp[n,l]
// ---------------------------------------------------------------------------
__global__ __launch_bounds__(256) void k2_gram(
    const unsigned short* __restrict__ xsp, float* __restrict__ gpart)
{
    __shared__ unsigned short As[128 * 136];  // xs [128 s][128 l] pad 136
    __shared__ unsigned short Bs[64 * 136];   // xp [ 64 n][128 l] pad 136
    const int t = threadIdx.x;
    const int lane = t & 63;
    const int w = t >> 6;
    const int ck = blockIdx.x;
    const int b = blockIdx.y;

    f32x4 acc[2][4] = {};

    for (int it = 0; it < 6; ++it) {
        const int lg = ck * LCHUNK + it * 128;
        {
            const int rr = t >> 4;
            const int lq = (t & 15) * 8;
            #pragma unroll
            for (int i = 0; i < 8; ++i) {
                const int s = rr + 16 * i;
                *(u16x8*)&As[s * 136 + lq] =
                    *(const u16x8*)(xsp + ((size_t)b * 192 + s) * HW_ + lg + lq);
            }
            #pragma unroll
            for (int i = 0; i < 4; ++i) {
                const int n = rr + 16 * i;
                *(u16x8*)&Bs[n * 136 + lq] =
                    *(const u16x8*)(xsp + ((size_t)b * 192 + 128 + n) * HW_ + lg + lq);
            }
        }
        __syncthreads();
        #pragma unroll
        for (int ks = 0; ks < 4; ++ks) {
            const int kg = ks * 32 + (lane >> 4) * 8;
            bf16x8 a[2], bv[4];
            #pragma unroll
            for (int mi = 0; mi < 2; ++mi)
                a[mi] = *(const bf16x8*)&As[(w * 32 + mi * 16 + (lane & 15)) * 136 + kg];
            #pragma unroll
            for (int ni = 0; ni < 4; ++ni)
                bv[ni] = *(const bf16x8*)&Bs[(ni * 16 + (lane & 15)) * 136 + kg];
            #pragma unroll
            for (int mi = 0; mi < 2; ++mi)
                #pragma unroll
                for (int ni = 0; ni < 4; ++ni)
                    acc[mi][ni] = __builtin_amdgcn_mfma_f32_16x16x32_bf16(a[mi], bv[ni], acc[mi][ni], 0, 0, 0);
        }
        __syncthreads();
    }
    float* gp = gpart + (size_t)(ck * 16 + b) * (S_ * N_);
    const int lf = lane & 15, r4 = (lane >> 4) * 4;
    #pragma unroll
    for (int mi = 0; mi < 2; ++mi)
        #pragma unroll
        for (int ni = 0; ni < 4; ++ni)
            #pragma unroll
            for (int r = 0; r < 4; ++r) {
                const int s = w * 32 + mi * 16 + r4 + r;
                const int n = ni * 16 + lf;
                gp[s * 64 + n] = acc[mi][ni][r];
            }
}

// ---------------------------------------------------------------------------
// K_gcn (MFMA rewrite): per batch, 4 waves.
// stages: reduce partials -> G | nm1 -> HT | sm1 -> G | nm2 -> HT | sm2 -> T2
//         | hc = fc2·g2 via T2.
// Weight fragments are read straight from global bf16 (k-contiguous 16B/lane).
// LDS: G[128][72] bf16 (g / g'), HT[64][136] bf16 (h transposed),
//      T2[64][136] bf16 (g2 transposed).  Total 53,248 B.
// ---------------------------------------------------------------------------
__global__ __launch_bounds__(256) void k_gcn(
    const float* __restrict__ gpart, const unsigned short* __restrict__ wbf,
    const float* __restrict__ b1a, const float* __restrict__ b1b,
    unsigned short* __restrict__ hc)
{
    __shared__ unsigned short G[128 * 72];
    __shared__ unsigned short HT[64 * 136];
    __shared__ unsigned short T2[64 * 136];
    const int b = blockIdx.x;
    const int t = threadIdx.x;
    const int lane = t & 63;
    const int w = t >> 6;
    const int lf = lane & 15;
    const int kg0 = (lane >> 4) * 8;
    const int r4 = (lane >> 4) * 4;

    const unsigned short* w1a = wbf;
    const unsigned short* w2a = wbf + 4096;
    const unsigned short* w1b = wbf + 20480;
    const unsigned short* w2b = wbf + 24576;
    const unsigned short* fc2 = wbf + 40960;

    // ---- stage 0: reduce K-split partials -> G (bf16, 1/HW applied) ----
    #pragma unroll
    for (int j = 0; j < 8; ++j) {
        const int v = t + j * 256;            // float4 index 0..2047
        f32x4 s = {};
        #pragma unroll
        for (int ck = 0; ck < KSPLIT; ++ck)
            s += *(const f32x4*)(gpart + (size_t)(ck * 16 + b) * (S_ * N_) + v * 4);
        s *= (1.0f / (float)HW_);
        const int e = v * 4;
        const int sr = e >> 6, nc = e & 63;
        ushort4 h;
        h.x = f2bf(s[0]); h.y = f2bf(s[1]); h.z = f2bf(s[2]); h.w = f2bf(s[3]);
        *(ushort4*)&G[sr * 72 + nc] = h;
    }
    __syncthreads();

    for (int pass = 0; pass < 2; ++pass) {
        const unsigned short* w1 = pass ? w1b : w1a;
        const unsigned short* w2 = pass ? w2b : w2a;
        const float* b1 = pass ? b1b : b1a;

        // ---- node mix: Y[s,m] = sum_n G[s,n]*w1[m,n]; h = leaky(Y+b1+G) -> HT[m][s]
        {
            f32x4 acc[2][4] = {};
            #pragma unroll
            for (int ks = 0; ks < 2; ++ks) {
                const int kg = ks * 32 + kg0;
                bf16x8 a[2], bv[4];
                #pragma unroll
                for (int mi = 0; mi < 2; ++mi)
                    a[mi] = *(const bf16x8*)&G[(w * 32 + mi * 16 + lf) * 72 + kg];
                #pragma unroll
                for (int ni = 0; ni < 4; ++ni)
                    bv[ni] = *(const bf16x8*)(w1 + (ni * 16 + lf) * 64 + kg);
                #pragma unroll
                for (int mi = 0; mi < 2; ++mi)
                    #pragma unroll
                    for (int ni = 0; ni < 4; ++ni)
                        acc[mi][ni] = __builtin_amdgcn_mfma_f32_16x16x32_bf16(a[mi], bv[ni], acc[mi][ni], 0, 0, 0);
            }
            #pragma unroll
            for (int mi = 0; mi < 2; ++mi) {
                const int s0 = w * 32 + mi * 16 + r4;
                #pragma unroll
                for (int ni = 0; ni < 4; ++ni) {
                    const int m = ni * 16 + lf;
                    const float bm = b1[m];
                    ushort4 pk;
                    #pragma unroll
                    for (int r = 0; r < 4; ++r) {
                        float v = acc[mi][ni][r] + bm + bf2f(G[(s0 + r) * 72 + m]);
                        v = v > 0.f ? v : 0.2f * v;
                        ((unsigned short*)&pk)[r] = f2bf(v);
                    }
                    *(ushort4*)&HT[m * 136 + s0] = pk;
                }
            }
        }
        __syncthreads();

        // ---- state mix: Z[t,m] = sum_s w2[t,s]*h[s,m]
        {
            f32x4 acc[2][4] = {};
            #pragma unroll
            for (int ks = 0; ks < 4; ++ks) {
                const int kg = ks * 32 + kg0;
                bf16x8 a[2], bv[4];
                #pragma unroll
                for (int mi = 0; mi < 2; ++mi)
                    a[mi] = *(const bf16x8*)(w2 + (w * 32 + mi * 16 + lf) * 128 + kg);
                #pragma unroll
                for (int ni = 0; ni < 4; ++ni)
                    bv[ni] = *(const bf16x8*)&HT[(ni * 16 + lf) * 136 + kg];
                #pragma unroll
                for (int mi = 0; mi < 2; ++mi)
                    #pragma unroll
                    for (int ni = 0; ni < 4; ++ni)
                        acc[mi][ni] = __builtin_amdgcn_mfma_f32_16x16x32_bf16(a[mi], bv[ni], acc[mi][ni], 0, 0, 0);
            }
            if (pass == 0) {   // write Z -> G[t][m] (scalar scatter)
                #pragma unroll
                for (int mi = 0; mi < 2; ++mi) {
                    const int t0 = w * 32 + mi * 16 + r4;
                    #pragma unroll
                    for (int ni = 0; ni < 4; ++ni) {
                        const int m = ni * 16 + lf;
                        #pragma unroll
                        for (int r = 0; r < 4; ++r)
                            G[(t0 + r) * 72 + m] = f2bf(acc[mi][ni][r]);
                    }
                }
            } else {           // write g2 transposed -> T2[n][t] (packed)
                #pragma unroll
                for (int mi = 0; mi < 2; ++mi) {
                    const int t0 = w * 32 + mi * 16 + r4;
                    #pragma unroll
                    for (int ni = 0; ni < 4; ++ni) {
                        const int m = ni * 16 + lf;
                        ushort4 pk;
                        #pragma unroll
                        for (int r = 0; r < 4; ++r)
                            ((unsigned short*)&pk)[r] = f2bf(acc[mi][ni][r]);
                        *(ushort4*)&T2[m * 136 + t0] = pk;
                    }
                }
            }
        }
        __syncthreads();
    }

    // ---- fc2 fold: hc[c,n] = sum_t fc2[c,t]*g2[t,n]  (B from T2) ----
    {
        f32x4 acc[4][4] = {};
        #pragma unroll
        for (int ks = 0; ks < 4; ++ks) {
            const int kg = ks * 32 + kg0;
            bf16x8 a[4], bv[4];
            #pragma unroll
            for (int mi = 0; mi < 4; ++mi)
                a[mi] = *(const bf16x8*)(fc2 + (w * 64 + mi * 16 + lf) * 128 + kg);
            #pragma unroll
            for (int ni = 0; ni < 4; ++ni)
                bv[ni] = *(const bf16x8*)&T2[(ni * 16 + lf) * 136 + kg];
            #pragma unroll
            for (int mi = 0; mi < 4; ++mi)
                #pragma unroll
                for (int ni = 0; ni < 4; ++ni)
                    acc[mi][ni] = __builtin_amdgcn_mfma_f32_16x16x32_bf16(a[mi], bv[ni], acc[mi][ni], 0, 0, 0);
        }
        #pragma unroll
        for (int mi = 0; mi < 4; ++mi) {
            const int c0 = w * 64 + mi * 16 + r4;
            #pragma unroll
            for (int ni = 0; ni < 4; ++ni) {
                const int n = ni * 16 + lf;
                #pragma unroll
                for (int r = 0; r < 4; ++r)
                    hc[((size_t)b * 256 + c0 + r) * 64 + n] = f2bf(acc[mi][ni][r]);
            }
        }
    }
}

// ---------------------------------------------------------------------------
// K3: out[b][c][l] = x[b][c][l] + oscale[c] * (sum_n hc[b][c][n]*xr[n][l]) + obeta[c]
// ---------------------------------------------------------------------------
__global__ __launch_bounds__(256) void k3_out(
    const float* __restrict__ x, const unsigned short* __restrict__ hc,
    const unsigned short* __restrict__ xrt,
    const float* __restrict__ oscale, const float* __restrict__ obeta,
    float* __restrict__ out)
{
    __shared__ unsigned short Alds[128 * 72];  // hc  [128 c][64 n] pad 72
    __shared__ unsigned short Blds[128 * 72];  // xrt [128 l][64 n] pad 72
    const int t = threadIdx.x;
    const int lane = t & 63;
    const int w = t >> 6;
    const int wr = w >> 1, wc = w & 1;
    const int l0 = blockIdx.x * 128;
    const int moff = blockIdx.y * 128;
    const int b = blockIdx.z;
    {
        const int rr = t >> 3;        // 0..31
        const int nq = (t & 7) * 8;
        #pragma unroll
        for (int i = 0; i < 4; ++i) {
            const int r = rr + 32 * i;
            *(u16x8*)&Alds[r * 72 + nq] =
                *(const u16x8*)(hc + ((size_t)b * 256 + moff + r) * 64 + nq);
            *(u16x8*)&Blds[r * 72 + nq] =
                *(const u16x8*)(xrt + ((size_t)b * HW_ + l0 + r) * 64 + nq);
        }
    }
    __syncthreads();
    f32x4 acc[4][4] = {};
    #pragma unroll
    for (int ks = 0; ks < 2; ++ks) {
        const int kg = ks * 32 + (lane >> 4) * 8;
        bf16x8 a[4], bv[4];
        #pragma unroll
        for (int mi = 0; mi < 4; ++mi)
            a[mi] = *(const bf16x8*)&Alds[(wr * 64 + mi * 16 + (lane & 15)) * 72 + kg];
        #pragma unroll
        for (int ni = 0; ni < 4; ++ni)
            bv[ni] = *(const bf16x8*)&Blds[(wc * 64 + ni * 16 + (lane & 15)) * 72 + kg];
        #pragma unroll
        for (int mi = 0; mi < 4; ++mi)
            #pragma unroll
            for (int ni = 0; ni < 4; ++ni)
                acc[mi][ni] = __builtin_amdgcn_mfma_f32_16x16x32_bf16(a[mi], bv[ni], acc[mi][ni], 0, 0, 0);
    }
    const int lf = lane & 15, r4 = (lane >> 4) * 4;
    #pragma unroll
    for (int mi = 0; mi < 4; ++mi) {
        const int c0 = moff + wr * 64 + mi * 16 + r4;
        float sc[4], bt[4];
        #pragma unroll
        for (int r = 0; r < 4; ++r) { sc[r] = oscale[c0 + r]; bt[r] = obeta[c0 + r]; }
        #pragma unroll
        for (int ni = 0; ni < 4; ++ni) {
            const int l = l0 + wc * 64 + ni * 16 + lf;
            #pragma unroll
            for (int r = 0; r < 4; ++r) {
                const size_t idx = ((size_t)b * 256 + c0 + r) * HW_ + l;
                out[idx] = x[idx] + acc[mi][ni][r] * sc[r] + bt[r];
            }
        }
    }
}

// ---------------------------------------------------------------------------
extern "C" void kernel_launch(void* const* d_in, const int* in_sizes, int n_in,
                              void* d_out, int out_size, void* d_ws, size_t ws_size,
                              hipStream_t stream) {
    (void)in_sizes; (void)n_in; (void)out_size;
    const float* x     = (const float*)d_in[0];
    const float* w_s   = (const float*)d_in[1];
    const float* b_s   = (const float*)d_in[2];
    const float* g_s   = (const float*)d_in[3];
    const float* bb_s  = (const float*)d_in[4];
    const float* m_s   = (const float*)d_in[5];
    const float* v_s   = (const float*)d_in[6];
    const float* w_p   = (const float*)d_in[7];
    const float* b_p   = (const float*)d_in[8];
    const float* g_p   = (const float*)d_in[9];
    const float* bb_p  = (const float*)d_in[10];
    const float* m_p   = (const float*)d_in[11];
    const float* v_p   = (const float*)d_in[12];
    const float* w_r   = (const float*)d_in[13];
    const float* b_r   = (const float*)d_in[14];
    const float* g_r   = (const float*)d_in[15];
    const float* bb_r  = (const float*)d_in[16];
    const float* m_r   = (const float*)d_in[17];
    const float* v_r   = (const float*)d_in[18];
    const float* g1w1  = (const float*)d_in[19];
    const float* g1b1  = (const float*)d_in[20];
    const float* g1w2  = (const float*)d_in[21];
    const float* g2w1  = (const float*)d_in[22];
    const float* g2b1  = (const float*)d_in[23];
    const float* g2w2  = (const float*)d_in[24];
    const float* fc2w  = (const float*)d_in[25];
    const float* bn_og = (const float*)d_in[26];
    const float* bn_ob = (const float*)d_in[27];
    const float* bn_om = (const float*)d_in[28];
    const float* bn_ov = (const float*)d_in[29];

    char* ws = (char*)d_ws;
    unsigned short* Wc = (unsigned short*)(ws + 0);          // 131072 B
    float* pscale = (float*)(ws + 131072);
    float* pbeta  = (float*)(ws + 132096);
    float* oscale = (float*)(ws + 133120);
    float* obeta  = (float*)(ws + 134144);
    unsigned short* wbf = (unsigned short*)(ws + 135168);    // 147456 B (73728 bf16)
    const size_t o_fix = 135168 + 147456;                    // 282624
    const size_t sz_xsp = (size_t)B_ * 192 * HW_ * 2;        // 56,623,104
    const size_t sz_xrt = (size_t)B_ * HW_ * 64 * 2;         // 18,874,368
    const size_t sz_gp  = (size_t)KSPLIT * B_ * S_ * N_ * 4; //  6,291,456
    const size_t sz_hc  = (size_t)B_ * 256 * 64 * 2;         //    524,288
    const size_t need_full = o_fix + sz_xsp + sz_xrt + sz_gp + sz_hc;

    unsigned short* xsp; size_t o2;
    if (ws_size >= need_full) { xsp = (unsigned short*)(ws + o_fix); o2 = o_fix + sz_xsp; }
    else { // fall back: stash xs/xp in d_out (K3 fully overwrites d_out afterwards)
        xsp = (unsigned short*)d_out; o2 = o_fix;
    }
    unsigned short* xrt = (unsigned short*)(ws + o2);
    float* gpart        = (float*)(ws + o2 + sz_xrt);
    unsigned short* hc  = (unsigned short*)(ws + o2 + sz_xrt + sz_gp);

    k0_prep<<<256, 256, 0, stream>>>(
        w_s, w_p, w_r,
        b_s, g_s, bb_s, m_s, v_s,
        b_p, g_p, bb_p, m_p, v_p,
        b_r, g_r, bb_r, m_r, v_r,
        bn_og, bn_ob, bn_om, bn_ov,
        Wc, pscale, pbeta, oscale, obeta);

    k0b_wbf<<<288, 256, 0, stream>>>(g1w1, g1w2, g2w1, g2w2, fc2w, wbf);

    k1_proj<<<dim3(72, 2, 16), 256, 0, stream>>>(x, Wc, pscale, pbeta, xsp, xrt);

    k2_gram<<<dim3(KSPLIT, 16), 256, 0, stream>>>(xsp, gpart);

    k_gcn<<<16, 256, 0, stream>>>(gpart, wbf, g1b1, g2b1, hc);

    k3_out<<<dim3(72, 2, 16), 256, 0, stream>>>(x, hc, xrt, oscale, obeta, (float*)d_out);
}

// Round 3
// 202.597 us; speedup vs baseline: 2.0531x; 1.1648x over previous
//
#include <hip/hip_runtime.h>
#include <cstdint>
#include <cstddef>

#define B_ 16
#define C_ 256
#define HW_ 9216
#define S_ 128
#define N_ 64
#define KSPLIT 12
#define LCHUNK 768

typedef __attribute__((ext_vector_type(8))) short bf16x8;
typedef __attribute__((ext_vector_type(4))) float f32x4;
typedef __attribute__((ext_vector_type(2))) float f32x2;
typedef __attribute__((ext_vector_type(8))) unsigned short u16x8;

__device__ __forceinline__ unsigned short f2bf(float f) {
    unsigned int u = __builtin_bit_cast(unsigned int, f);
    u += 0x7fffu + ((u >> 16) & 1u);   // RNE; inputs are finite
    return (unsigned short)(u >> 16);
}
__device__ __forceinline__ float bf2f(unsigned short u) {
    unsigned int x = ((unsigned int)u) << 16;
    return __builtin_bit_cast(float, x);
}

// ---------------------------------------------------------------------------
// K0: fold conv bias + BN into per-channel (scale, beta); bf16-ify combined
// projection weights Wc[256][256]; precompute output-BN scale/beta.
// ---------------------------------------------------------------------------
__global__ void k0_prep(
    const float* __restrict__ w_s, const float* __restrict__ w_p, const float* __restrict__ w_r,
    const float* __restrict__ b_s, const float* __restrict__ g_s, const float* __restrict__ bb_s,
    const float* __restrict__ m_s, const float* __restrict__ v_s,
    const float* __restrict__ b_p, const float* __restrict__ g_p, const float* __restrict__ bb_p,
    const float* __restrict__ m_p, const float* __restrict__ v_p,
    const float* __restrict__ b_r, const float* __restrict__ g_r, const float* __restrict__ bb_r,
    const float* __restrict__ m_r, const float* __restrict__ v_r,
    const float* __restrict__ og, const float* __restrict__ ob,
    const float* __restrict__ om, const float* __restrict__ ov,
    unsigned short* __restrict__ Wc, float* __restrict__ pscale, float* __restrict__ pbeta,
    float* __restrict__ oscale, float* __restrict__ obeta)
{
    const int gid = blockIdx.x * 256 + threadIdx.x;   // 0..65535
    const int oc = gid >> 8, c = gid & 255;
    const float* wsrc;
    if (oc < 128)      wsrc = w_s + oc * 256;
    else if (oc < 192) wsrc = w_p + (oc - 128) * 256;
    else               wsrc = w_r + (oc - 192) * 256;
    Wc[gid] = f2bf(wsrc[c]);
    if (gid < 256) {
        int i; const float *bp, *gp, *bbp, *mp, *vp;
        if (gid < 128)      { i = gid;       bp = b_s; gp = g_s; bbp = bb_s; mp = m_s; vp = v_s; }
        else if (gid < 192) { i = gid - 128; bp = b_p; gp = g_p; bbp = bb_p; mp = m_p; vp = v_p; }
        else                { i = gid - 192; bp = b_r; gp = g_r; bbp = bb_r; mp = m_r; vp = v_r; }
        const float sc = gp[i] / sqrtf(vp[i] + 1e-5f);
        pscale[gid] = sc;
        pbeta[gid]  = (bp[i] - mp[i]) * sc + bbp[i];
        const float so = og[gid] / sqrtf(ov[gid] + 1e-5f);
        oscale[gid] = so;
        obeta[gid]  = ob[gid] - om[gid] * so;
    }
}

// ---------------------------------------------------------------------------
// K0b: bf16-ify the GCN + fc2 weights into one flat buffer.
// ---------------------------------------------------------------------------
__global__ void k0b_wbf(
    const float* __restrict__ g1w1, const float* __restrict__ g1w2,
    const float* __restrict__ g2w1, const float* __restrict__ g2w2,
    const float* __restrict__ fc2w, unsigned short* __restrict__ wbf)
{
    const int gid = blockIdx.x * 256 + threadIdx.x;   // 0..73727
    float v;
    if (gid < 4096)       v = g1w1[gid];
    else if (gid < 20480) v = g1w2[gid - 4096];
    else if (gid < 24576) v = g2w1[gid - 20480];
    else if (gid < 40960) v = g2w2[gid - 24576];
    else                  v = fc2w[gid - 40960];
    wbf[gid] = f2bf(v);
}

// ---------------------------------------------------------------------------
// K1: fused projection GEMM.  out[oc][l] = relu(scale[oc]*(Wc[oc,:]·x[:,l]) + beta[oc])
// xs/xp -> xsp[b][oc][l] (oc 0..191);  xr -> xrt[b][l][n] TRANSPOSED (oc 192..255).
// ---------------------------------------------------------------------------
__global__ __launch_bounds__(256) void k1_proj(
    const float* __restrict__ x, const unsigned short* __restrict__ Wc,
    const float* __restrict__ pscale, const float* __restrict__ pbeta,
    unsigned short* __restrict__ xsp, unsigned short* __restrict__ xrt)
{
    __shared__ unsigned short Alds[128 * 72];   // W tile [128 oc][64 c], pad stride 72
    __shared__ unsigned short Blds[64 * 132];   // x tile [64 c][128 l],  pad stride 132
    const int t = threadIdx.x;
    const int lane = t & 63;
    const int w = t >> 6;
    const int wr = w >> 1, wc = w & 1;
    const int l0 = blockIdx.x * 128;
    const int moff = blockIdx.y * 128;
    const int b = blockIdx.z;
    const float* xb = x + (size_t)b * C_ * HW_;

    f32x4 acc[4][4] = {};

    for (int kt = 0; kt < 4; ++kt) {
        const int k0 = kt * 64;
        {   // stage A (weights, bf16, k-contiguous rows)
            const int cq = (t & 15) * 4;
            const int rr = t >> 4;
            #pragma unroll
            for (int i = 0; i < 8; ++i) {
                const int r = rr + i * 16;
                *(ushort4*)&Alds[r * 72 + cq] =
                    *(const ushort4*)(Wc + (moff + r) * 256 + k0 + cq);
            }
        }
        {   // stage B (x fp32 -> bf16), natural [c][l] layout, coalesced
            const int lq = t & 31;
            const int c0 = t >> 5;
            #pragma unroll
            for (int i = 0; i < 8; ++i) {
                const int c = c0 + i * 8;
                const float4 v = *(const float4*)(xb + (size_t)(k0 + c) * HW_ + l0 + lq * 4);
                ushort4 h;
                h.x = f2bf(v.x); h.y = f2bf(v.y); h.z = f2bf(v.z); h.w = f2bf(v.w);
                *(ushort4*)&Blds[c * 132 + lq * 4] = h;
            }
        }
        __syncthreads();
        #pragma unroll
        for (int ks = 0; ks < 2; ++ks) {
            const int kg = ks * 32 + (lane >> 4) * 8;
            bf16x8 a[4];
            const int mrow = wr * 64 + (lane & 15);
            #pragma unroll
            for (int mi = 0; mi < 4; ++mi)
                a[mi] = *(const bf16x8*)&Alds[(mrow + mi * 16) * 72 + kg];
            const int nc = wc * 64 + (lane & 15);
            bf16x8 bv[4];
            #pragma unroll
            for (int ni = 0; ni < 4; ++ni) {
                bf16x8 tmp;
                #pragma unroll
                for (int j = 0; j < 8; ++j)
                    tmp[j] = (short)Blds[(kg + j) * 132 + nc + ni * 16];
                bv[ni] = tmp;
            }
            #pragma unroll
            for (int mi = 0; mi < 4; ++mi)
                #pragma unroll
                for (int ni = 0; ni < 4; ++ni)
                    acc[mi][ni] = __builtin_amdgcn_mfma_f32_16x16x32_bf16(a[mi], bv[ni], acc[mi][ni], 0, 0, 0);
        }
        __syncthreads();
    }
    // epilogue: BN-affine + relu, bf16 stores
    const int lf = lane & 15;
    const int r4 = (lane >> 4) * 4;
    #pragma unroll
    for (int mi = 0; mi < 4; ++mi) {
        const int oc0 = moff + wr * 64 + mi * 16 + r4;
        float sc[4], bt[4];
        #pragma unroll
        for (int r = 0; r < 4; ++r) { sc[r] = pscale[oc0 + r]; bt[r] = pbeta[oc0 + r]; }
        #pragma unroll
        for (int ni = 0; ni < 4; ++ni) {
            const int l = l0 + wc * 64 + ni * 16 + lf;
            if (oc0 < 192) {        // xs / xp  ->  [b][oc][l]
                #pragma unroll
                for (int r = 0; r < 4; ++r) {
                    float y = acc[mi][ni][r] * sc[r] + bt[r];
                    y = y > 0.f ? y : 0.f;
                    xsp[((size_t)b * 192 + oc0 + r) * HW_ + l] = f2bf(y);
                }
            } else {                // xr -> transposed [b][l][n], packed 8B store
                ushort4 pk;
                float y0 = acc[mi][ni][0] * sc[0] + bt[0];
                float y1 = acc[mi][ni][1] * sc[1] + bt[1];
                float y2 = acc[mi][ni][2] * sc[2] + bt[2];
                float y3 = acc[mi][ni][3] * sc[3] + bt[3];
                pk.x = f2bf(y0 > 0.f ? y0 : 0.f);
                pk.y = f2bf(y1 > 0.f ? y1 : 0.f);
                pk.z = f2bf(y2 > 0.f ? y2 : 0.f);
                pk.w = f2bf(y3 > 0.f ? y3 : 0.f);
                *(ushort4*)&xrt[((size_t)b * HW_ + l) * 64 + (oc0 - 192)] = pk;
            }
        }
    }
}

// ---------------------------------------------------------------------------
// K2: Gram partials.  gpart[ck][b][s][n] = sum over L-chunk of xs[s,l]*xp[n,l]
// ---------------------------------------------------------------------------
__global__ __launch_bounds__(256) void k2_gram(
    const unsigned short* __restrict__ xsp, float* __restrict__ gpart)
{
    __shared__ unsigned short As[128 * 136];  // xs [128 s][128 l] pad 136
    __shared__ unsigned short Bs[64 * 136];   // xp [ 64 n][128 l] pad 136
    const int t = threadIdx.x;
    const int lane = t & 63;
    const int w = t >> 6;
    const int ck = blockIdx.x;
    const int b = blockIdx.y;

    f32x4 acc[2][4] = {};

    for (int it = 0; it < 6; ++it) {
        const int lg = ck * LCHUNK + it * 128;
        {
            const int rr = t >> 4;
            const int lq = (t & 15) * 8;
            #pragma unroll
            for (int i = 0; i < 8; ++i) {
                const int s = rr + 16 * i;
                *(u16x8*)&As[s * 136 + lq] =
                    *(const u16x8*)(xsp + ((size_t)b * 192 + s) * HW_ + lg + lq);
            }
            #pragma unroll
            for (int i = 0; i < 4; ++i) {
                const int n = rr + 16 * i;
                *(u16x8*)&Bs[n * 136 + lq] =
                    *(const u16x8*)(xsp + ((size_t)b * 192 + 128 + n) * HW_ + lg + lq);
            }
        }
        __syncthreads();
        #pragma unroll
        for (int ks = 0; ks < 4; ++ks) {
            const int kg = ks * 32 + (lane >> 4) * 8;
            bf16x8 a[2], bv[4];
            #pragma unroll
            for (int mi = 0; mi < 2; ++mi)
                a[mi] = *(const bf16x8*)&As[(w * 32 + mi * 16 + (lane & 15)) * 136 + kg];
            #pragma unroll
            for (int ni = 0; ni < 4; ++ni)
                bv[ni] = *(const bf16x8*)&Bs[(ni * 16 + (lane & 15)) * 136 + kg];
            #pragma unroll
            for (int mi = 0; mi < 2; ++mi)
                #pragma unroll
                for (int ni = 0; ni < 4; ++ni)
                    acc[mi][ni] = __builtin_amdgcn_mfma_f32_16x16x32_bf16(a[mi], bv[ni], acc[mi][ni], 0, 0, 0);
        }
        __syncthreads();
    }
    float* gp = gpart + (size_t)(ck * 16 + b) * (S_ * N_);
    const int lf = lane & 15, r4 = (lane >> 4) * 4;
    #pragma unroll
    for (int mi = 0; mi < 2; ++mi)
        #pragma unroll
        for (int ni = 0; ni < 4; ++ni)
            #pragma unroll
            for (int r = 0; r < 4; ++r) {
                const int s = w * 32 + mi * 16 + r4 + r;
                const int n = ni * 16 + lf;
                gp[s * 64 + n] = acc[mi][ni][r];
            }
}

// ---------------------------------------------------------------------------
// K_gcn (MFMA): per batch, 4 waves; 6 barrier-separated MFMA stages.
// ---------------------------------------------------------------------------
__global__ __launch_bounds__(256) void k_gcn(
    const float* __restrict__ gpart, const unsigned short* __restrict__ wbf,
    const float* __restrict__ b1a, const float* __restrict__ b1b,
    unsigned short* __restrict__ hc)
{
    __shared__ unsigned short G[128 * 72];
    __shared__ unsigned short HT[64 * 136];
    __shared__ unsigned short T2[64 * 136];
    const int b = blockIdx.x;
    const int t = threadIdx.x;
    const int lane = t & 63;
    const int w = t >> 6;
    const int lf = lane & 15;
    const int kg0 = (lane >> 4) * 8;
    const int r4 = (lane >> 4) * 4;

    const unsigned short* w1a = wbf;
    const unsigned short* w2a = wbf + 4096;
    const unsigned short* w1b = wbf + 20480;
    const unsigned short* w2b = wbf + 24576;
    const unsigned short* fc2 = wbf + 40960;

    // ---- stage 0: reduce K-split partials -> G (bf16, 1/HW applied) ----
    #pragma unroll
    for (int j = 0; j < 8; ++j) {
        const int v = t + j * 256;            // float4 index 0..2047
        f32x4 s = {};
        #pragma unroll
        for (int ck = 0; ck < KSPLIT; ++ck)
            s += *(const f32x4*)(gpart + (size_t)(ck * 16 + b) * (S_ * N_) + v * 4);
        s *= (1.0f / (float)HW_);
        const int e = v * 4;
        const int sr = e >> 6, nc = e & 63;
        ushort4 h;
        h.x = f2bf(s[0]); h.y = f2bf(s[1]); h.z = f2bf(s[2]); h.w = f2bf(s[3]);
        *(ushort4*)&G[sr * 72 + nc] = h;
    }
    __syncthreads();

    for (int pass = 0; pass < 2; ++pass) {
        const unsigned short* w1 = pass ? w1b : w1a;
        const unsigned short* w2 = pass ? w2b : w2a;
        const float* b1 = pass ? b1b : b1a;

        // ---- node mix: Y[s,m] = sum_n G[s,n]*w1[m,n]; h = leaky(Y+b1+G) -> HT[m][s]
        {
            f32x4 acc[2][4] = {};
            #pragma unroll
            for (int ks = 0; ks < 2; ++ks) {
                const int kg = ks * 32 + kg0;
                bf16x8 a[2], bv[4];
                #pragma unroll
                for (int mi = 0; mi < 2; ++mi)
                    a[mi] = *(const bf16x8*)&G[(w * 32 + mi * 16 + lf) * 72 + kg];
                #pragma unroll
                for (int ni = 0; ni < 4; ++ni)
                    bv[ni] = *(const bf16x8*)(w1 + (ni * 16 + lf) * 64 + kg);
                #pragma unroll
                for (int mi = 0; mi < 2; ++mi)
                    #pragma unroll
                    for (int ni = 0; ni < 4; ++ni)
                        acc[mi][ni] = __builtin_amdgcn_mfma_f32_16x16x32_bf16(a[mi], bv[ni], acc[mi][ni], 0, 0, 0);
            }
            #pragma unroll
            for (int mi = 0; mi < 2; ++mi) {
                const int s0 = w * 32 + mi * 16 + r4;
                #pragma unroll
                for (int ni = 0; ni < 4; ++ni) {
                    const int m = ni * 16 + lf;
                    const float bm = b1[m];
                    ushort4 pk;
                    #pragma unroll
                    for (int r = 0; r < 4; ++r) {
                        float v = acc[mi][ni][r] + bm + bf2f(G[(s0 + r) * 72 + m]);
                        v = v > 0.f ? v : 0.2f * v;
                        ((unsigned short*)&pk)[r] = f2bf(v);
                    }
                    *(ushort4*)&HT[m * 136 + s0] = pk;
                }
            }
        }
        __syncthreads();

        // ---- state mix: Z[t,m] = sum_s w2[t,s]*h[s,m]
        {
            f32x4 acc[2][4] = {};
            #pragma unroll
            for (int ks = 0; ks < 4; ++ks) {
                const int kg = ks * 32 + kg0;
                bf16x8 a[2], bv[4];
                #pragma unroll
                for (int mi = 0; mi < 2; ++mi)
                    a[mi] = *(const bf16x8*)(w2 + (w * 32 + mi * 16 + lf) * 128 + kg);
                #pragma unroll
                for (int ni = 0; ni < 4; ++ni)
                    bv[ni] = *(const bf16x8*)&HT[(ni * 16 + lf) * 136 + kg];
                #pragma unroll
                for (int mi = 0; mi < 2; ++mi)
                    #pragma unroll
                    for (int ni = 0; ni < 4; ++ni)
                        acc[mi][ni] = __builtin_amdgcn_mfma_f32_16x16x32_bf16(a[mi], bv[ni], acc[mi][ni], 0, 0, 0);
            }
            if (pass == 0) {   // write Z -> G[t][m] (scalar scatter)
                #pragma unroll
                for (int mi = 0; mi < 2; ++mi) {
                    const int t0 = w * 32 + mi * 16 + r4;
                    #pragma unroll
                    for (int ni = 0; ni < 4; ++ni) {
                        const int m = ni * 16 + lf;
                        #pragma unroll
                        for (int r = 0; r < 4; ++r)
                            G[(t0 + r) * 72 + m] = f2bf(acc[mi][ni][r]);
                    }
                }
            } else {           // write g2 transposed -> T2[n][t] (packed)
                #pragma unroll
                for (int mi = 0; mi < 2; ++mi) {
                    const int t0 = w * 32 + mi * 16 + r4;
                    #pragma unroll
                    for (int ni = 0; ni < 4; ++ni) {
                        const int m = ni * 16 + lf;
                        ushort4 pk;
                        #pragma unroll
                        for (int r = 0; r < 4; ++r)
                            ((unsigned short*)&pk)[r] = f2bf(acc[mi][ni][r]);
                        *(ushort4*)&T2[m * 136 + t0] = pk;
                    }
                }
            }
        }
        __syncthreads();
    }

    // ---- fc2 fold: hc[c,n] = sum_t fc2[c,t]*g2[t,n]  (B from T2) ----
    {
        f32x4 acc[4][4] = {};
        #pragma unroll
        for (int ks = 0; ks < 4; ++ks) {
            const int kg = ks * 32 + kg0;
            bf16x8 a[4], bv[4];
            #pragma unroll
            for (int mi = 0; mi < 4; ++mi)
                a[mi] = *(const bf16x8*)(fc2 + (w * 64 + mi * 16 + lf) * 128 + kg);
            #pragma unroll
            for (int ni = 0; ni < 4; ++ni)
                bv[ni] = *(const bf16x8*)&T2[(ni * 16 + lf) * 136 + kg];
            #pragma unroll
            for (int mi = 0; mi < 4; ++mi)
                #pragma unroll
                for (int ni = 0; ni < 4; ++ni)
                    acc[mi][ni] = __builtin_amdgcn_mfma_f32_16x16x32_bf16(a[mi], bv[ni], acc[mi][ni], 0, 0, 0);
        }
        #pragma unroll
        for (int mi = 0; mi < 4; ++mi) {
            const int c0 = w * 64 + mi * 16 + r4;
            #pragma unroll
            for (int ni = 0; ni < 4; ++ni) {
                const int n = ni * 16 + lf;
                #pragma unroll
                for (int r = 0; r < 4; ++r)
                    hc[((size_t)b * 256 + c0 + r) * 64 + n] = f2bf(acc[mi][ni][r]);
            }
        }
    }
}

// ---------------------------------------------------------------------------
// K3: out[b][c][l] = x[b][c][l] + oscale[c] * (sum_n hc[b][c][n]*xr[n][l]) + obeta[c]
// OPERAND-SWAPPED: D[l][c] = mfma(xrt_frag, hc_frag) so each lane holds 4
// CONSECUTIVE l for a fixed c -> float4 x-load + float4 out-store.
// ---------------------------------------------------------------------------
__global__ __launch_bounds__(256) void k3_out(
    const float* __restrict__ x, const unsigned short* __restrict__ hc,
    const unsigned short* __restrict__ xrt,
    const float* __restrict__ oscale, const float* __restrict__ obeta,
    float* __restrict__ out)
{
    __shared__ unsigned short Alds[128 * 72];  // hc  [128 c][64 n] pad 72
    __shared__ unsigned short Blds[128 * 72];  // xrt [128 l][64 n] pad 72
    const int t = threadIdx.x;
    const int lane = t & 63;
    const int w = t >> 6;
    const int wr = w >> 1, wc = w & 1;
    const int l0 = blockIdx.x * 128;
    const int moff = blockIdx.y * 128;
    const int b = blockIdx.z;
    {
        const int rr = t >> 3;        // 0..31
        const int nq = (t & 7) * 8;
        #pragma unroll
        for (int i = 0; i < 4; ++i) {
            const int r = rr + 32 * i;
            *(u16x8*)&Alds[r * 72 + nq] =
                *(const u16x8*)(hc + ((size_t)b * 256 + moff + r) * 64 + nq);
            *(u16x8*)&Blds[r * 72 + nq] =
                *(const u16x8*)(xrt + ((size_t)b * HW_ + l0 + r) * 64 + nq);
        }
    }
    __syncthreads();
    const int lf = lane & 15;
    f32x4 acc[4][4] = {};   // [mi = l-repeat][ni = c-repeat]
    #pragma unroll
    for (int ks = 0; ks < 2; ++ks) {
        const int kg = ks * 32 + (lane >> 4) * 8;
        bf16x8 al[4], bc[4];
        #pragma unroll
        for (int mi = 0; mi < 4; ++mi)   // A = xrt rows (M = l)
            al[mi] = *(const bf16x8*)&Blds[(wc * 64 + mi * 16 + lf) * 72 + kg];
        #pragma unroll
        for (int ni = 0; ni < 4; ++ni)   // B = hc rows (N = c)
            bc[ni] = *(const bf16x8*)&Alds[(wr * 64 + ni * 16 + lf) * 72 + kg];
        #pragma unroll
        for (int mi = 0; mi < 4; ++mi)
            #pragma unroll
            for (int ni = 0; ni < 4; ++ni)
                acc[mi][ni] = __builtin_amdgcn_mfma_f32_16x16x32_bf16(al[mi], bc[ni], acc[mi][ni], 0, 0, 0);
    }
    const int r4 = (lane >> 4) * 4;
    #pragma unroll
    for (int ni = 0; ni < 4; ++ni) {
        const int c = moff + wr * 64 + ni * 16 + lf;      // per-lane channel
        const float sc = oscale[c];
        const float bt = obeta[c];
        const size_t rowb = ((size_t)b * 256 + c) * HW_;
        #pragma unroll
        for (int mi = 0; mi < 4; ++mi) {
            const int l = l0 + wc * 64 + mi * 16 + r4;    // 4 consecutive l
            const f32x4 xv = *(const f32x4*)(x + rowb + l);
            f32x4 o;
            #pragma unroll
            for (int r = 0; r < 4; ++r)
                o[r] = xv[r] + acc[mi][ni][r] * sc + bt;
            *(f32x4*)(out + rowb + l) = o;
        }
    }
}

// ---------------------------------------------------------------------------
extern "C" void kernel_launch(void* const* d_in, const int* in_sizes, int n_in,
                              void* d_out, int out_size, void* d_ws, size_t ws_size,
                              hipStream_t stream) {
    (void)in_sizes; (void)n_in; (void)out_size;
    const float* x     = (const float*)d_in[0];
    const float* w_s   = (const float*)d_in[1];
    const float* b_s   = (const float*)d_in[2];
    const float* g_s   = (const float*)d_in[3];
    const float* bb_s  = (const float*)d_in[4];
    const float* m_s   = (const float*)d_in[5];
    const float* v_s   = (const float*)d_in[6];
    const float* w_p   = (const float*)d_in[7];
    const float* b_p   = (const float*)d_in[8];
    const float* g_p   = (const float*)d_in[9];
    const float* bb_p  = (const float*)d_in[10];
    const float* m_p   = (const float*)d_in[11];
    const float* v_p   = (const float*)d_in[12];
    const float* w_r   = (const float*)d_in[13];
    const float* b_r   = (const float*)d_in[14];
    const float* g_r   = (const float*)d_in[15];
    const float* bb_r  = (const float*)d_in[16];
    const float* m_r   = (const float*)d_in[17];
    const float* v_r   = (const float*)d_in[18];
    const float* g1w1  = (const float*)d_in[19];
    const float* g1b1  = (const float*)d_in[20];
    const float* g1w2  = (const float*)d_in[21];
    const float* g2w1  = (const float*)d_in[22];
    const float* g2b1  = (const float*)d_in[23];
    const float* g2w2  = (const float*)d_in[24];
    const float* fc2w  = (const float*)d_in[25];
    const float* bn_og = (const float*)d_in[26];
    const float* bn_ob = (const float*)d_in[27];
    const float* bn_om = (const float*)d_in[28];
    const float* bn_ov = (const float*)d_in[29];

    char* ws = (char*)d_ws;
    unsigned short* Wc = (unsigned short*)(ws + 0);          // 131072 B
    float* pscale = (float*)(ws + 131072);
    float* pbeta  = (float*)(ws + 132096);
    float* oscale = (float*)(ws + 133120);
    float* obeta  = (float*)(ws + 134144);
    unsigned short* wbf = (unsigned short*)(ws + 135168);    // 147456 B (73728 bf16)
    const size_t o_fix = 135168 + 147456;                    // 282624
    const size_t sz_xsp = (size_t)B_ * 192 * HW_ * 2;        // 56,623,104
    const size_t sz_xrt = (size_t)B_ * HW_ * 64 * 2;         // 18,874,368
    const size_t sz_gp  = (size_t)KSPLIT * B_ * S_ * N_ * 4; //  6,291,456
    const size_t sz_hc  = (size_t)B_ * 256 * 64 * 2;         //    524,288
    const size_t need_full = o_fix + sz_xsp + sz_xrt + sz_gp + sz_hc;

    unsigned short* xsp; size_t o2;
    if (ws_size >= need_full) { xsp = (unsigned short*)(ws + o_fix); o2 = o_fix + sz_xsp; }
    else { // fall back: stash xs/xp in d_out (K3 fully overwrites d_out afterwards)
        xsp = (unsigned short*)d_out; o2 = o_fix;
    }
    unsigned short* xrt = (unsigned short*)(ws + o2);
    float* gpart        = (float*)(ws + o2 + sz_xrt);
    unsigned short* hc  = (unsigned short*)(ws + o2 + sz_xrt + sz_gp);

    k0_prep<<<256, 256, 0, stream>>>(
        w_s, w_p, w_r,
        b_s, g_s, bb_s, m_s, v_s,
        b_p, g_p, bb_p, m_p, v_p,
        b_r, g_r, bb_r, m_r, v_r,
        bn_og, bn_ob, bn_om, bn_ov,
        Wc, pscale, pbeta, oscale, obeta);

    k0b_wbf<<<288, 256, 0, stream>>>(g1w1, g1w2, g2w1, g2w2, fc2w, wbf);

    k1_proj<<<dim3(72, 2, 16), 256, 0, stream>>>(x, Wc, pscale, pbeta, xsp, xrt);

    k2_gram<<<dim3(KSPLIT, 16), 256, 0, stream>>>(xsp, gpart);

    k_gcn<<<16, 256, 0, stream>>>(gpart, wbf, g1b1, g2b1, hc);

    k3_out<<<dim3(72, 2, 16), 256, 0, stream>>>(x, hc, xrt, oscale, obeta, (float*)d_out);
}

// Round 4
// 201.274 us; speedup vs baseline: 2.0666x; 1.0066x over previous
//
#include <hip/hip_runtime.h>
#include <cstdint>
#include <cstddef>

#define B_ 16
#define C_ 256
#define HW_ 9216
#define S_ 128
#define N_ 64
#define KSPLIT 12
#define LCHUNK 768

typedef __attribute__((ext_vector_type(8))) short bf16x8;
typedef __attribute__((ext_vector_type(4))) float f32x4;
typedef __attribute__((ext_vector_type(2))) float f32x2;
typedef __attribute__((ext_vector_type(8))) unsigned short u16x8;

__device__ __forceinline__ unsigned short f2bf(float f) {
    unsigned int u = __builtin_bit_cast(unsigned int, f);
    u += 0x7fffu + ((u >> 16) & 1u);   // RNE; inputs are finite
    return (unsigned short)(u >> 16);
}
__device__ __forceinline__ float bf2f(unsigned short u) {
    unsigned int x = ((unsigned int)u) << 16;
    return __builtin_bit_cast(float, x);
}

// ---------------------------------------------------------------------------
// K0: fold conv bias + BN into per-channel (scale, beta); bf16-ify combined
// projection weights Wc[256][256]; precompute output-BN scale/beta.
// ---------------------------------------------------------------------------
__global__ void k0_prep(
    const float* __restrict__ w_s, const float* __restrict__ w_p, const float* __restrict__ w_r,
    const float* __restrict__ b_s, const float* __restrict__ g_s, const float* __restrict__ bb_s,
    const float* __restrict__ m_s, const float* __restrict__ v_s,
    const float* __restrict__ b_p, const float* __restrict__ g_p, const float* __restrict__ bb_p,
    const float* __restrict__ m_p, const float* __restrict__ v_p,
    const float* __restrict__ b_r, const float* __restrict__ g_r, const float* __restrict__ bb_r,
    const float* __restrict__ m_r, const float* __restrict__ v_r,
    const float* __restrict__ og, const float* __restrict__ ob,
    const float* __restrict__ om, const float* __restrict__ ov,
    unsigned short* __restrict__ Wc, float* __restrict__ pscale, float* __restrict__ pbeta,
    float* __restrict__ oscale, float* __restrict__ obeta)
{
    const int gid = blockIdx.x * 256 + threadIdx.x;   // 0..65535
    const int oc = gid >> 8, c = gid & 255;
    const float* wsrc;
    if (oc < 128)      wsrc = w_s + oc * 256;
    else if (oc < 192) wsrc = w_p + (oc - 128) * 256;
    else               wsrc = w_r + (oc - 192) * 256;
    Wc[gid] = f2bf(wsrc[c]);
    if (gid < 256) {
        int i; const float *bp, *gp, *bbp, *mp, *vp;
        if (gid < 128)      { i = gid;       bp = b_s; gp = g_s; bbp = bb_s; mp = m_s; vp = v_s; }
        else if (gid < 192) { i = gid - 128; bp = b_p; gp = g_p; bbp = bb_p; mp = m_p; vp = v_p; }
        else                { i = gid - 192; bp = b_r; gp = g_r; bbp = bb_r; mp = m_r; vp = v_r; }
        const float sc = gp[i] / sqrtf(vp[i] + 1e-5f);
        pscale[gid] = sc;
        pbeta[gid]  = (bp[i] - mp[i]) * sc + bbp[i];
        const float so = og[gid] / sqrtf(ov[gid] + 1e-5f);
        oscale[gid] = so;
        obeta[gid]  = ob[gid] - om[gid] * so;
    }
}

// ---------------------------------------------------------------------------
// K0b: bf16-ify the GCN + fc2 weights into one flat buffer.
// ---------------------------------------------------------------------------
__global__ void k0b_wbf(
    const float* __restrict__ g1w1, const float* __restrict__ g1w2,
    const float* __restrict__ g2w1, const float* __restrict__ g2w2,
    const float* __restrict__ fc2w, unsigned short* __restrict__ wbf)
{
    const int gid = blockIdx.x * 256 + threadIdx.x;   // 0..73727
    float v;
    if (gid < 4096)       v = g1w1[gid];
    else if (gid < 20480) v = g1w2[gid - 4096];
    else if (gid < 24576) v = g2w1[gid - 20480];
    else if (gid < 40960) v = g2w2[gid - 24576];
    else                  v = fc2w[gid - 40960];
    wbf[gid] = f2bf(v);
}

// ---------------------------------------------------------------------------
// K1: fused projection GEMM.  out[oc][l] = relu(scale[oc]*(Wc[oc,:]·x[:,l]) + beta[oc])
// xs/xp -> xsp[b][oc][l] (oc 0..191);  xr -> xrt[b][l][n] TRANSPOSED (oc 192..255).
// B tile is now stored TRANSPOSED [l][c] via in-register 4x4 transpose at
// write time (vector ds_write_b64, XOR-swizzled) -> all fragment reads b128.
// ---------------------------------------------------------------------------
__global__ __launch_bounds__(256) void k1_proj(
    const float* __restrict__ x, const unsigned short* __restrict__ Wc,
    const float* __restrict__ pscale, const float* __restrict__ pbeta,
    unsigned short* __restrict__ xsp, unsigned short* __restrict__ xrt)
{
    __shared__ unsigned short Alds[128 * 72];   // W tile [128 oc][64 c], stride 72
    __shared__ unsigned short Blds[128 * 72];   // x tile [128 l][64 c], stride 72, swizzled
    const int t = threadIdx.x;
    const int lane = t & 63;
    const int w = t >> 6;
    const int wr = w >> 1, wc = w & 1;
    const int l0 = blockIdx.x * 128;
    const int moff = blockIdx.y * 128;
    const int b = blockIdx.z;
    const float* xb = x + (size_t)b * C_ * HW_;

    f32x4 acc[4][4] = {};

    const int lq = t & 31;          // l-quad index (l = lq*4)
    const int cq = (t >> 5) * 4;    // c-quad base within 32-half

    for (int kt = 0; kt < 4; ++kt) {
        const int k0 = kt * 64;
        {   // stage A (weights, bf16, k-contiguous rows)
            const int cqa = (t & 15) * 4;
            const int rr = t >> 4;
            #pragma unroll
            for (int i = 0; i < 8; ++i) {
                const int r = rr + i * 16;
                *(ushort4*)&Alds[r * 72 + cqa] =
                    *(const ushort4*)(Wc + (moff + r) * 256 + k0 + cqa);
            }
        }
        {   // stage B: load 4c x 4l fp32 blocks, transpose in-register, store [l][c]
            #pragma unroll
            for (int half = 0; half < 2; ++half) {
                const int cc0 = half * 32 + cq;          // local c 0..63
                f32x4 v[4];
                #pragma unroll
                for (int j = 0; j < 4; ++j)
                    v[j] = *(const f32x4*)(xb + (size_t)(k0 + cc0 + j) * HW_ + l0 + lq * 4);
                #pragma unroll
                for (int r = 0; r < 4; ++r) {
                    const int ll = lq * 4 + r;
                    ushort4 wv;
                    wv.x = f2bf(v[0][r]);
                    wv.y = f2bf(v[1][r]);
                    wv.z = f2bf(v[2][r]);
                    wv.w = f2bf(v[3][r]);
                    int idx = ll * 72 + cc0;
                    idx ^= (((ll >> 2) & 7) << 3) ^ (((ll >> 5) & 1) << 5);
                    *(ushort4*)&Blds[idx] = wv;
                }
            }
        }
        __syncthreads();
        const int lf = lane & 15;
        #pragma unroll
        for (int ks = 0; ks < 2; ++ks) {
            const int kg = ks * 32 + (lane >> 4) * 8;
            bf16x8 a[4];
            const int mrow = wr * 64 + lf;
            #pragma unroll
            for (int mi = 0; mi < 4; ++mi)
                a[mi] = *(const bf16x8*)&Alds[(mrow + mi * 16) * 72 + kg];
            bf16x8 bv[4];
            #pragma unroll
            for (int ni = 0; ni < 4; ++ni) {
                const int ll = wc * 64 + ni * 16 + lf;
                int idx = ll * 72 + kg;
                idx ^= (((ll >> 2) & 7) << 3) ^ (((ll >> 5) & 1) << 5);
                bv[ni] = *(const bf16x8*)&Blds[idx];
            }
            #pragma unroll
            for (int mi = 0; mi < 4; ++mi)
                #pragma unroll
                for (int ni = 0; ni < 4; ++ni)
                    acc[mi][ni] = __builtin_amdgcn_mfma_f32_16x16x32_bf16(a[mi], bv[ni], acc[mi][ni], 0, 0, 0);
        }
        __syncthreads();
    }
    // epilogue: BN-affine + relu, bf16 stores
    const int lf = lane & 15;
    const int r4 = (lane >> 4) * 4;
    #pragma unroll
    for (int mi = 0; mi < 4; ++mi) {
        const int oc0 = moff + wr * 64 + mi * 16 + r4;
        float sc[4], bt[4];
        #pragma unroll
        for (int r = 0; r < 4; ++r) { sc[r] = pscale[oc0 + r]; bt[r] = pbeta[oc0 + r]; }
        #pragma unroll
        for (int ni = 0; ni < 4; ++ni) {
            const int l = l0 + wc * 64 + ni * 16 + lf;
            if (oc0 < 192) {        // xs / xp  ->  [b][oc][l]
                #pragma unroll
                for (int r = 0; r < 4; ++r) {
                    float y = acc[mi][ni][r] * sc[r] + bt[r];
                    y = y > 0.f ? y : 0.f;
                    xsp[((size_t)b * 192 + oc0 + r) * HW_ + l] = f2bf(y);
                }
            } else {                // xr -> transposed [b][l][n], packed 8B store
                ushort4 pk;
                float y0 = acc[mi][ni][0] * sc[0] + bt[0];
                float y1 = acc[mi][ni][1] * sc[1] + bt[1];
                float y2 = acc[mi][ni][2] * sc[2] + bt[2];
                float y3 = acc[mi][ni][3] * sc[3] + bt[3];
                pk.x = f2bf(y0 > 0.f ? y0 : 0.f);
                pk.y = f2bf(y1 > 0.f ? y1 : 0.f);
                pk.z = f2bf(y2 > 0.f ? y2 : 0.f);
                pk.w = f2bf(y3 > 0.f ? y3 : 0.f);
                *(ushort4*)&xrt[((size_t)b * HW_ + l) * 64 + (oc0 - 192)] = pk;
            }
        }
    }
}

// ---------------------------------------------------------------------------
// K2: Gram partials.  gpart[ck][b][s][n] = sum over L-chunk of xs[s,l]*xp[n,l]
// ---------------------------------------------------------------------------
__global__ __launch_bounds__(256) void k2_gram(
    const unsigned short* __restrict__ xsp, float* __restrict__ gpart)
{
    __shared__ unsigned short As[128 * 136];  // xs [128 s][128 l] pad 136
    __shared__ unsigned short Bs[64 * 136];   // xp [ 64 n][128 l] pad 136
    const int t = threadIdx.x;
    const int lane = t & 63;
    const int w = t >> 6;
    const int ck = blockIdx.x;
    const int b = blockIdx.y;

    f32x4 acc[2][4] = {};

    for (int it = 0; it < 6; ++it) {
        const int lg = ck * LCHUNK + it * 128;
        {
            const int rr = t >> 4;
            const int lq2 = (t & 15) * 8;
            #pragma unroll
            for (int i = 0; i < 8; ++i) {
                const int s = rr + 16 * i;
                *(u16x8*)&As[s * 136 + lq2] =
                    *(const u16x8*)(xsp + ((size_t)b * 192 + s) * HW_ + lg + lq2);
            }
            #pragma unroll
            for (int i = 0; i < 4; ++i) {
                const int n = rr + 16 * i;
                *(u16x8*)&Bs[n * 136 + lq2] =
                    *(const u16x8*)(xsp + ((size_t)b * 192 + 128 + n) * HW_ + lg + lq2);
            }
        }
        __syncthreads();
        #pragma unroll
        for (int ks = 0; ks < 4; ++ks) {
            const int kg = ks * 32 + (lane >> 4) * 8;
            bf16x8 a[2], bv[4];
            #pragma unroll
            for (int mi = 0; mi < 2; ++mi)
                a[mi] = *(const bf16x8*)&As[(w * 32 + mi * 16 + (lane & 15)) * 136 + kg];
            #pragma unroll
            for (int ni = 0; ni < 4; ++ni)
                bv[ni] = *(const bf16x8*)&Bs[(ni * 16 + (lane & 15)) * 136 + kg];
            #pragma unroll
            for (int mi = 0; mi < 2; ++mi)
                #pragma unroll
                for (int ni = 0; ni < 4; ++ni)
                    acc[mi][ni] = __builtin_amdgcn_mfma_f32_16x16x32_bf16(a[mi], bv[ni], acc[mi][ni], 0, 0, 0);
        }
        __syncthreads();
    }
    float* gp = gpart + (size_t)(ck * 16 + b) * (S_ * N_);
    const int lf = lane & 15, r4 = (lane >> 4) * 4;
    #pragma unroll
    for (int mi = 0; mi < 2; ++mi)
        #pragma unroll
        for (int ni = 0; ni < 4; ++ni)
            #pragma unroll
            for (int r = 0; r < 4; ++r) {
                const int s = w * 32 + mi * 16 + r4 + r;
                const int n = ni * 16 + lf;
                gp[s * 64 + n] = acc[mi][ni][r];
            }
}

// ---------------------------------------------------------------------------
// K_gcn (MFMA): per batch, 4 waves; 6 barrier-separated MFMA stages.
// ---------------------------------------------------------------------------
__global__ __launch_bounds__(256) void k_gcn(
    const float* __restrict__ gpart, const unsigned short* __restrict__ wbf,
    const float* __restrict__ b1a, const float* __restrict__ b1b,
    unsigned short* __restrict__ hc)
{
    __shared__ unsigned short G[128 * 72];
    __shared__ unsigned short HT[64 * 136];
    __shared__ unsigned short T2[64 * 136];
    const int b = blockIdx.x;
    const int t = threadIdx.x;
    const int lane = t & 63;
    const int w = t >> 6;
    const int lf = lane & 15;
    const int kg0 = (lane >> 4) * 8;
    const int r4 = (lane >> 4) * 4;

    const unsigned short* w1a = wbf;
    const unsigned short* w2a = wbf + 4096;
    const unsigned short* w1b = wbf + 20480;
    const unsigned short* w2b = wbf + 24576;
    const unsigned short* fc2 = wbf + 40960;

    // ---- stage 0: reduce K-split partials -> G (bf16, 1/HW applied) ----
    #pragma unroll
    for (int j = 0; j < 8; ++j) {
        const int v = t + j * 256;            // float4 index 0..2047
        f32x4 s = {};
        #pragma unroll
        for (int ck = 0; ck < KSPLIT; ++ck)
            s += *(const f32x4*)(gpart + (size_t)(ck * 16 + b) * (S_ * N_) + v * 4);
        s *= (1.0f / (float)HW_);
        const int e = v * 4;
        const int sr = e >> 6, nc = e & 63;
        ushort4 h;
        h.x = f2bf(s[0]); h.y = f2bf(s[1]); h.z = f2bf(s[2]); h.w = f2bf(s[3]);
        *(ushort4*)&G[sr * 72 + nc] = h;
    }
    __syncthreads();

    for (int pass = 0; pass < 2; ++pass) {
        const unsigned short* w1 = pass ? w1b : w1a;
        const unsigned short* w2 = pass ? w2b : w2a;
        const float* b1 = pass ? b1b : b1a;

        // ---- node mix: Y[s,m] = sum_n G[s,n]*w1[m,n]; h = leaky(Y+b1+G) -> HT[m][s]
        {
            f32x4 acc[2][4] = {};
            #pragma unroll
            for (int ks = 0; ks < 2; ++ks) {
                const int kg = ks * 32 + kg0;
                bf16x8 a[2], bv[4];
                #pragma unroll
                for (int mi = 0; mi < 2; ++mi)
                    a[mi] = *(const bf16x8*)&G[(w * 32 + mi * 16 + lf) * 72 + kg];
                #pragma unroll
                for (int ni = 0; ni < 4; ++ni)
                    bv[ni] = *(const bf16x8*)(w1 + (ni * 16 + lf) * 64 + kg);
                #pragma unroll
                for (int mi = 0; mi < 2; ++mi)
                    #pragma unroll
                    for (int ni = 0; ni < 4; ++ni)
                        acc[mi][ni] = __builtin_amdgcn_mfma_f32_16x16x32_bf16(a[mi], bv[ni], acc[mi][ni], 0, 0, 0);
            }
            #pragma unroll
            for (int mi = 0; mi < 2; ++mi) {
                const int s0 = w * 32 + mi * 16 + r4;
                #pragma unroll
                for (int ni = 0; ni < 4; ++ni) {
                    const int m = ni * 16 + lf;
                    const float bm = b1[m];
                    ushort4 pk;
                    #pragma unroll
                    for (int r = 0; r < 4; ++r) {
                        float v = acc[mi][ni][r] + bm + bf2f(G[(s0 + r) * 72 + m]);
                        v = v > 0.f ? v : 0.2f * v;
                        ((unsigned short*)&pk)[r] = f2bf(v);
                    }
                    *(ushort4*)&HT[m * 136 + s0] = pk;
                }
            }
        }
        __syncthreads();

        // ---- state mix: Z[t,m] = sum_s w2[t,s]*h[s,m]
        {
            f32x4 acc[2][4] = {};
            #pragma unroll
            for (int ks = 0; ks < 4; ++ks) {
                const int kg = ks * 32 + kg0;
                bf16x8 a[2], bv[4];
                #pragma unroll
                for (int mi = 0; mi < 2; ++mi)
                    a[mi] = *(const bf16x8*)(w2 + (w * 32 + mi * 16 + lf) * 128 + kg);
                #pragma unroll
                for (int ni = 0; ni < 4; ++ni)
                    bv[ni] = *(const bf16x8*)&HT[(ni * 16 + lf) * 136 + kg];
                #pragma unroll
                for (int mi = 0; mi < 2; ++mi)
                    #pragma unroll
                    for (int ni = 0; ni < 4; ++ni)
                        acc[mi][ni] = __builtin_amdgcn_mfma_f32_16x16x32_bf16(a[mi], bv[ni], acc[mi][ni], 0, 0, 0);
            }
            if (pass == 0) {   // write Z -> G[t][m] (scalar scatter)
                #pragma unroll
                for (int mi = 0; mi < 2; ++mi) {
                    const int t0 = w * 32 + mi * 16 + r4;
                    #pragma unroll
                    for (int ni = 0; ni < 4; ++ni) {
                        const int m = ni * 16 + lf;
                        #pragma unroll
                        for (int r = 0; r < 4; ++r)
                            G[(t0 + r) * 72 + m] = f2bf(acc[mi][ni][r]);
                    }
                }
            } else {           // write g2 transposed -> T2[n][t] (packed)
                #pragma unroll
                for (int mi = 0; mi < 2; ++mi) {
                    const int t0 = w * 32 + mi * 16 + r4;
                    #pragma unroll
                    for (int ni = 0; ni < 4; ++ni) {
                        const int m = ni * 16 + lf;
                        ushort4 pk;
                        #pragma unroll
                        for (int r = 0; r < 4; ++r)
                            ((unsigned short*)&pk)[r] = f2bf(acc[mi][ni][r]);
                        *(ushort4*)&T2[m * 136 + t0] = pk;
                    }
                }
            }
        }
        __syncthreads();
    }

    // ---- fc2 fold: hc[c,n] = sum_t fc2[c,t]*g2[t,n]  (B from T2) ----
    {
        f32x4 acc[4][4] = {};
        #pragma unroll
        for (int ks = 0; ks < 4; ++ks) {
            const int kg = ks * 32 + kg0;
            bf16x8 a[4], bv[4];
            #pragma unroll
            for (int mi = 0; mi < 4; ++mi)
                a[mi] = *(const bf16x8*)(fc2 + (w * 64 + mi * 16 + lf) * 128 + kg);
            #pragma unroll
            for (int ni = 0; ni < 4; ++ni)
                bv[ni] = *(const bf16x8*)&T2[(ni * 16 + lf) * 136 + kg];
            #pragma unroll
            for (int mi = 0; mi < 4; ++mi)
                #pragma unroll
                for (int ni = 0; ni < 4; ++ni)
                    acc[mi][ni] = __builtin_amdgcn_mfma_f32_16x16x32_bf16(a[mi], bv[ni], acc[mi][ni], 0, 0, 0);
        }
        #pragma unroll
        for (int mi = 0; mi < 4; ++mi) {
            const int c0 = w * 64 + mi * 16 + r4;
            #pragma unroll
            for (int ni = 0; ni < 4; ++ni) {
                const int n = ni * 16 + lf;
                #pragma unroll
                for (int r = 0; r < 4; ++r)
                    hc[((size_t)b * 256 + c0 + r) * 64 + n] = f2bf(acc[mi][ni][r]);
            }
        }
    }
}

// ---------------------------------------------------------------------------
// K3: out[b][c][l] = x[b][c][l] + oscale[c] * (sum_n hc[b][c][n]*xr[n][l]) + obeta[c]
// OPERAND-SWAPPED: D[l][c] = mfma(xrt_frag, hc_frag) so each lane holds 4
// CONSECUTIVE l for a fixed c -> float4 x-load + float4 out-store.
// ---------------------------------------------------------------------------
__global__ __launch_bounds__(256) void k3_out(
    const float* __restrict__ x, const unsigned short* __restrict__ hc,
    const unsigned short* __restrict__ xrt,
    const float* __restrict__ oscale, const float* __restrict__ obeta,
    float* __restrict__ out)
{
    __shared__ unsigned short Alds[128 * 72];  // hc  [128 c][64 n] pad 72
    __shared__ unsigned short Blds[128 * 72];  // xrt [128 l][64 n] pad 72
    const int t = threadIdx.x;
    const int lane = t & 63;
    const int w = t >> 6;
    const int wr = w >> 1, wc = w & 1;
    const int l0 = blockIdx.x * 128;
    const int moff = blockIdx.y * 128;
    const int b = blockIdx.z;
    {
        const int rr = t >> 3;        // 0..31
        const int nq = (t & 7) * 8;
        #pragma unroll
        for (int i = 0; i < 4; ++i) {
            const int r = rr + 32 * i;
            *(u16x8*)&Alds[r * 72 + nq] =
                *(const u16x8*)(hc + ((size_t)b * 256 + moff + r) * 64 + nq);
            *(u16x8*)&Blds[r * 72 + nq] =
                *(const u16x8*)(xrt + ((size_t)b * HW_ + l0 + r) * 64 + nq);
        }
    }
    __syncthreads();
    const int lf = lane & 15;
    f32x4 acc[4][4] = {};   // [mi = l-repeat][ni = c-repeat]
    #pragma unroll
    for (int ks = 0; ks < 2; ++ks) {
        const int kg = ks * 32 + (lane >> 4) * 8;
        bf16x8 al[4], bc[4];
        #pragma unroll
        for (int mi = 0; mi < 4; ++mi)   // A = xrt rows (M = l)
            al[mi] = *(const bf16x8*)&Blds[(wc * 64 + mi * 16 + lf) * 72 + kg];
        #pragma unroll
        for (int ni = 0; ni < 4; ++ni)   // B = hc rows (N = c)
            bc[ni] = *(const bf16x8*)&Alds[(wr * 64 + ni * 16 + lf) * 72 + kg];
        #pragma unroll
        for (int mi = 0; mi < 4; ++mi)
            #pragma unroll
            for (int ni = 0; ni < 4; ++ni)
                acc[mi][ni] = __builtin_amdgcn_mfma_f32_16x16x32_bf16(al[mi], bc[ni], acc[mi][ni], 0, 0, 0);
    }
    const int r4 = (lane >> 4) * 4;
    #pragma unroll
    for (int ni = 0; ni < 4; ++ni) {
        const int c = moff + wr * 64 + ni * 16 + lf;      // per-lane channel
        const float sc = oscale[c];
        const float bt = obeta[c];
        const size_t rowb = ((size_t)b * 256 + c) * HW_;
        #pragma unroll
        for (int mi = 0; mi < 4; ++mi) {
            const int l = l0 + wc * 64 + mi * 16 + r4;    // 4 consecutive l
            const f32x4 xv = *(const f32x4*)(x + rowb + l);
            f32x4 o;
            #pragma unroll
            for (int r = 0; r < 4; ++r)
                o[r] = xv[r] + acc[mi][ni][r] * sc + bt;
            *(f32x4*)(out + rowb + l) = o;
        }
    }
}

// ---------------------------------------------------------------------------
extern "C" void kernel_launch(void* const* d_in, const int* in_sizes, int n_in,
                              void* d_out, int out_size, void* d_ws, size_t ws_size,
                              hipStream_t stream) {
    (void)in_sizes; (void)n_in; (void)out_size;
    const float* x     = (const float*)d_in[0];
    const float* w_s   = (const float*)d_in[1];
    const float* b_s   = (const float*)d_in[2];
    const float* g_s   = (const float*)d_in[3];
    const float* bb_s  = (const float*)d_in[4];
    const float* m_s   = (const float*)d_in[5];
    const float* v_s   = (const float*)d_in[6];
    const float* w_p   = (const float*)d_in[7];
    const float* b_p   = (const float*)d_in[8];
    const float* g_p   = (const float*)d_in[9];
    const float* bb_p  = (const float*)d_in[10];
    const float* m_p   = (const float*)d_in[11];
    const float* v_p   = (const float*)d_in[12];
    const float* w_r   = (const float*)d_in[13];
    const float* b_r   = (const float*)d_in[14];
    const float* g_r   = (const float*)d_in[15];
    const float* bb_r  = (const float*)d_in[16];
    const float* m_r   = (const float*)d_in[17];
    const float* v_r   = (const float*)d_in[18];
    const float* g1w1  = (const float*)d_in[19];
    const float* g1b1  = (const float*)d_in[20];
    const float* g1w2  = (const float*)d_in[21];
    const float* g2w1  = (const float*)d_in[22];
    const float* g2b1  = (const float*)d_in[23];
    const float* g2w2  = (const float*)d_in[24];
    const float* fc2w  = (const float*)d_in[25];
    const float* bn_og = (const float*)d_in[26];
    const float* bn_ob = (const float*)d_in[27];
    const float* bn_om = (const float*)d_in[28];
    const float* bn_ov = (const float*)d_in[29];

    char* ws = (char*)d_ws;
    unsigned short* Wc = (unsigned short*)(ws + 0);          // 131072 B
    float* pscale = (float*)(ws + 131072);
    float* pbeta  = (float*)(ws + 132096);
    float* oscale = (float*)(ws + 133120);
    float* obeta  = (float*)(ws + 134144);
    unsigned short* wbf = (unsigned short*)(ws + 135168);    // 147456 B (73728 bf16)
    const size_t o_fix = 135168 + 147456;                    // 282624
    const size_t sz_xsp = (size_t)B_ * 192 * HW_ * 2;        // 56,623,104
    const size_t sz_xrt = (size_t)B_ * HW_ * 64 * 2;         // 18,874,368
    const size_t sz_gp  = (size_t)KSPLIT * B_ * S_ * N_ * 4; //  6,291,456
    const size_t sz_hc  = (size_t)B_ * 256 * 64 * 2;         //    524,288
    const size_t need_full = o_fix + sz_xsp + sz_xrt + sz_gp + sz_hc;

    unsigned short* xsp; size_t o2;
    if (ws_size >= need_full) { xsp = (unsigned short*)(ws + o_fix); o2 = o_fix + sz_xsp; }
    else { // fall back: stash xs/xp in d_out (K3 fully overwrites d_out afterwards)
        xsp = (unsigned short*)d_out; o2 = o_fix;
    }
    unsigned short* xrt = (unsigned short*)(ws + o2);
    float* gpart        = (float*)(ws + o2 + sz_xrt);
    unsigned short* hc  = (unsigned short*)(ws + o2 + sz_xrt + sz_gp);

    k0_prep<<<256, 256, 0, stream>>>(
        w_s, w_p, w_r,
        b_s, g_s, bb_s, m_s, v_s,
        b_p, g_p, bb_p, m_p, v_p,
        b_r, g_r, bb_r, m_r, v_r,
        bn_og, bn_ob, bn_om, bn_ov,
        Wc, pscale, pbeta, oscale, obeta);

    k0b_wbf<<<288, 256, 0, stream>>>(g1w1, g1w2, g2w1, g2w2, fc2w, wbf);

    k1_proj<<<dim3(72, 2, 16), 256, 0, stream>>>(x, Wc, pscale, pbeta, xsp, xrt);

    k2_gram<<<dim3(KSPLIT, 16), 256, 0, stream>>>(xsp, gpart);

    k_gcn<<<16, 256, 0, stream>>>(gpart, wbf, g1b1, g2b1, hc);

    k3_out<<<dim3(72, 2, 16), 256, 0, stream>>>(x, hc, xrt, oscale, obeta, (float*)d_out);
}

// Round 5
// 197.999 us; speedup vs baseline: 2.1008x; 1.0165x over previous
//
#include <hip/hip_runtime.h>
#include <cstdint>
#include <cstddef>

#define B_ 16
#define C_ 256
#define HW_ 9216
#define S_ 128
#define N_ 64
#define LT_ 72          // number of 128-wide l tiles

typedef __attribute__((ext_vector_type(8))) short bf16x8;
typedef __attribute__((ext_vector_type(4))) float f32x4;
typedef __attribute__((ext_vector_type(8))) unsigned short u16x8;

__device__ __forceinline__ unsigned short f2bf(float f) {
    unsigned int u = __builtin_bit_cast(unsigned int, f);
    u += 0x7fffu + ((u >> 16) & 1u);   // RNE; inputs are finite
    return (unsigned short)(u >> 16);
}
__device__ __forceinline__ float bf2f(unsigned short u) {
    unsigned int x = ((unsigned int)u) << 16;
    return __builtin_bit_cast(float, x);
}

// ---------------------------------------------------------------------------
// K0: fold conv bias + BN into per-channel (scale, beta); bf16 Wc[256][256];
// output-BN scale/beta.
// ---------------------------------------------------------------------------
__global__ void k0_prep(
    const float* __restrict__ w_s, const float* __restrict__ w_p, const float* __restrict__ w_r,
    const float* __restrict__ b_s, const float* __restrict__ g_s, const float* __restrict__ bb_s,
    const float* __restrict__ m_s, const float* __restrict__ v_s,
    const float* __restrict__ b_p, const float* __restrict__ g_p, const float* __restrict__ bb_p,
    const float* __restrict__ m_p, const float* __restrict__ v_p,
    const float* __restrict__ b_r, const float* __restrict__ g_r, const float* __restrict__ bb_r,
    const float* __restrict__ m_r, const float* __restrict__ v_r,
    const float* __restrict__ og, const float* __restrict__ ob,
    const float* __restrict__ om, const float* __restrict__ ov,
    unsigned short* __restrict__ Wc, float* __restrict__ pscale, float* __restrict__ pbeta,
    float* __restrict__ oscale, float* __restrict__ obeta)
{
    const int gid = blockIdx.x * 256 + threadIdx.x;   // 0..65535
    const int oc = gid >> 8, c = gid & 255;
    const float* wsrc;
    if (oc < 128)      wsrc = w_s + oc * 256;
    else if (oc < 192) wsrc = w_p + (oc - 128) * 256;
    else               wsrc = w_r + (oc - 192) * 256;
    Wc[gid] = f2bf(wsrc[c]);
    if (gid < 256) {
        int i; const float *bp, *gp, *bbp, *mp, *vp;
        if (gid < 128)      { i = gid;       bp = b_s; gp = g_s; bbp = bb_s; mp = m_s; vp = v_s; }
        else if (gid < 192) { i = gid - 128; bp = b_p; gp = g_p; bbp = bb_p; mp = m_p; vp = v_p; }
        else                { i = gid - 192; bp = b_r; gp = g_r; bbp = bb_r; mp = m_r; vp = v_r; }
        const float sc = gp[i] / sqrtf(vp[i] + 1e-5f);
        pscale[gid] = sc;
        pbeta[gid]  = (bp[i] - mp[i]) * sc + bbp[i];
        const float so = og[gid] / sqrtf(ov[gid] + 1e-5f);
        oscale[gid] = so;
        obeta[gid]  = ob[gid] - om[gid] * so;
    }
}

// ---------------------------------------------------------------------------
// K0b: bf16-ify the GCN + fc2 weights into one flat buffer.
// ---------------------------------------------------------------------------
__global__ void k0b_wbf(
    const float* __restrict__ g1w1, const float* __restrict__ g1w2,
    const float* __restrict__ g2w1, const float* __restrict__ g2w2,
    const float* __restrict__ fc2w, unsigned short* __restrict__ wbf)
{
    const int gid = blockIdx.x * 256 + threadIdx.x;   // 0..73727
    float v;
    if (gid < 4096)       v = g1w1[gid];
    else if (gid < 20480) v = g1w2[gid - 4096];
    else if (gid < 24576) v = g2w1[gid - 20480];
    else if (gid < 40960) v = g2w2[gid - 24576];
    else                  v = fc2w[gid - 40960];
    wbf[gid] = f2bf(v);
}

// ---------------------------------------------------------------------------
// K1_FUSED: per (l-tile, b):
//  phase 1: proj GEMM D[l][oc] over all 256 oc, BK=64 x4, T14 reg-staged.
//  phase 2: BN+relu -> P[256 oc][128 l] bf16 in LDS (swizzled).
//  phase 3: gram partial gpart[lt][b][128 s][64 n] = P[s,:]·P[128+n,:].
//  phase 4: xrt[b][l][n] from P rows 192..255.
// Eliminates the xsp global buffer and the separate k2 kernel.
// ---------------------------------------------------------------------------
__global__ __launch_bounds__(512, 4) void k1_fused(
    const float* __restrict__ x, const unsigned short* __restrict__ Wc,
    const float* __restrict__ pscale, const float* __restrict__ pbeta,
    unsigned short* __restrict__ xrt, float* __restrict__ gpart)
{
    __shared__ unsigned short SH[32768];        // 64 KB
    unsigned short* Alds = SH;                  // [256 oc][72] (Wc tile)
    unsigned short* Blds = SH + 18432;          // [128 l][72] (x^T tile, swizzled)
    // phase>=2: SH = P[256 oc][128 l], swizzled

    const int t = threadIdx.x;
    const int lane = t & 63;
    const int w = t >> 6;          // 0..7
    const int wl = w >> 2;         // 0..1  l-dim wave (64 each)
    const int wo = w & 3;          // 0..3  oc-dim wave (64 each)
    const int lt = blockIdx.x;
    const int b  = blockIdx.y;
    const int l0 = lt * 128;
    const float* xb = x + (size_t)b * C_ * HW_;
    const int lf = lane & 15;
    const int q4 = lane >> 4;
    const int kg0 = q4 * 8;
    const int r4 = q4 * 4;

    const int lq = t & 31;          // B-stage l-quad (l = lq*4)
    const int c0 = (t >> 5) * 4;    // B-stage c base 0..60

    f32x4 acc[4][4] = {};
    u16x8 Areg[4];
    f32x4 Breg[4];

    // ---- prologue loads (kt = 0) ----
    #pragma unroll
    for (int i = 0; i < 4; ++i) {
        const int id = t + i * 512;
        Areg[i] = *(const u16x8*)(Wc + (id >> 3) * 256 + 0 + (id & 7) * 8);
    }
    #pragma unroll
    for (int j = 0; j < 4; ++j)
        Breg[j] = *(const f32x4*)(xb + (size_t)(0 + c0 + j) * HW_ + l0 + lq * 4);

    for (int kt = 0; kt < 4; ++kt) {
        // ---- write staged regs -> LDS ----
        #pragma unroll
        for (int i = 0; i < 4; ++i) {
            const int id = t + i * 512;
            *(u16x8*)&Alds[(id >> 3) * 72 + (id & 7) * 8] = Areg[i];
        }
        #pragma unroll
        for (int r = 0; r < 4; ++r) {
            const int ll = lq * 4 + r;
            ushort4 wv;
            wv.x = f2bf(Breg[0][r]); wv.y = f2bf(Breg[1][r]);
            wv.z = f2bf(Breg[2][r]); wv.w = f2bf(Breg[3][r]);
            *(ushort4*)&Blds[ll * 72 + (c0 ^ (((ll >> 3) & 7) << 3))] = wv;
        }
        __syncthreads();
        // ---- issue next tile's loads (latency hides under MFMA) ----
        if (kt < 3) {
            const int k0n = (kt + 1) * 64;
            #pragma unroll
            for (int i = 0; i < 4; ++i) {
                const int id = t + i * 512;
                Areg[i] = *(const u16x8*)(Wc + (id >> 3) * 256 + k0n + (id & 7) * 8);
            }
            #pragma unroll
            for (int j = 0; j < 4; ++j)
                Breg[j] = *(const f32x4*)(xb + (size_t)(k0n + c0 + j) * HW_ + l0 + lq * 4);
        }
        // ---- MFMA: D[l][oc] += x^T · Wc ----
        #pragma unroll
        for (int ks = 0; ks < 2; ++ks) {
            const int kg = ks * 32 + kg0;
            bf16x8 al[4], bo[4];
            #pragma unroll
            for (int mi = 0; mi < 4; ++mi) {
                const int ll = wl * 64 + mi * 16 + lf;
                al[mi] = *(const bf16x8*)&Blds[ll * 72 + (kg ^ (((ll >> 3) & 7) << 3))];
            }
            #pragma unroll
            for (int ni = 0; ni < 4; ++ni)
                bo[ni] = *(const bf16x8*)&Alds[(wo * 64 + ni * 16 + lf) * 72 + kg];
            #pragma unroll
            for (int mi = 0; mi < 4; ++mi)
                #pragma unroll
                for (int ni = 0; ni < 4; ++ni)
                    acc[mi][ni] = __builtin_amdgcn_mfma_f32_16x16x32_bf16(al[mi], bo[ni], acc[mi][ni], 0, 0, 0);
        }
        __syncthreads();
    }

    // ---- phase 2: BN + relu -> P[oc][l] bf16 (swizzled), vector writes ----
    #pragma unroll
    for (int ni = 0; ni < 4; ++ni) {
        const int oc = wo * 64 + ni * 16 + lf;
        const float sc = pscale[oc];
        const float bt = pbeta[oc];
        const int fsw = ((oc & 7) << 3);
        #pragma unroll
        for (int mi = 0; mi < 4; ++mi) {
            const int lcol = wl * 64 + mi * 16 + r4;
            ushort4 pk;
            #pragma unroll
            for (int r = 0; r < 4; ++r) {
                float y = acc[mi][ni][r] * sc + bt;
                y = y > 0.f ? y : 0.f;
                ((unsigned short*)&pk)[r] = f2bf(y);
            }
            *(ushort4*)&SH[oc * 128 + (lcol ^ fsw)] = pk;
        }
    }
    __syncthreads();

    // ---- phase 3: gram partial  D[s][n] = sum_l P[s][l]*P[128+n][l] ----
    {
        const int ws_ = w >> 1;      // 0..3  s-wave (32 each)
        const int wn  = w & 1;       // 0..1  n-wave (32 each)
        f32x4 acc2[2][2] = {};
        #pragma unroll
        for (int ks = 0; ks < 4; ++ks) {
            const int kg = ks * 32 + kg0;
            bf16x8 sa[2], nb[2];
            #pragma unroll
            for (int mi = 0; mi < 2; ++mi) {
                const int row = ws_ * 32 + mi * 16 + lf;
                sa[mi] = *(const bf16x8*)&SH[row * 128 + (kg ^ ((row & 7) << 3))];
            }
            #pragma unroll
            for (int ni = 0; ni < 2; ++ni) {
                const int row = 128 + wn * 32 + ni * 16 + lf;
                nb[ni] = *(const bf16x8*)&SH[row * 128 + (kg ^ ((row & 7) << 3))];
            }
            #pragma unroll
            for (int mi = 0; mi < 2; ++mi)
                #pragma unroll
                for (int ni = 0; ni < 2; ++ni)
                    acc2[mi][ni] = __builtin_amdgcn_mfma_f32_16x16x32_bf16(sa[mi], nb[ni], acc2[mi][ni], 0, 0, 0);
        }
        float* gp = gpart + (size_t)(lt * 16 + b) * (S_ * N_);
        #pragma unroll
        for (int mi = 0; mi < 2; ++mi)
            #pragma unroll
            for (int ni = 0; ni < 2; ++ni) {
                const int n = wn * 32 + ni * 16 + lf;
                #pragma unroll
                for (int r = 0; r < 4; ++r) {
                    const int s = ws_ * 32 + mi * 16 + r4 + r;
                    gp[s * 64 + n] = acc2[mi][ni][r];
                }
            }
    }

    // ---- phase 4: xrt[b][l][n] from P rows 192..255 ----
    #pragma unroll
    for (int i = 0; i < 4; ++i) {
        const int idx = t + i * 512;          // 0..2047
        const int l = idx >> 4;               // 0..127
        const int n0 = (idx & 15) * 4;        // 0..60
        ushort4 pk;
        #pragma unroll
        for (int j = 0; j < 4; ++j) {
            const int row = 192 + n0 + j;
            ((unsigned short*)&pk)[j] = SH[row * 128 + (l ^ ((row & 7) << 3))];
        }
        *(ushort4*)&xrt[((size_t)b * HW_ + l0 + l) * 64 + n0] = pk;
    }
}

// ---------------------------------------------------------------------------
// KRED: g[b][s*64+n] = (sum_lt gpart[lt][b][s*64+n]) / HW  -> bf16
// ---------------------------------------------------------------------------
__global__ __launch_bounds__(128) void kred(
    const float* __restrict__ gpart, unsigned short* __restrict__ gred)
{
    const int id = blockIdx.x * 128 + threadIdx.x;    // 0..32767, f32x4 units
    f32x4 s = {};
    const float* p = gpart + (size_t)id * 4;
    #pragma unroll 8
    for (int ltc = 0; ltc < LT_; ++ltc)
        s += *(const f32x4*)(p + (size_t)ltc * 16 * (S_ * N_));
    s *= (1.0f / (float)HW_);
    ushort4 h;
    h.x = f2bf(s[0]); h.y = f2bf(s[1]); h.z = f2bf(s[2]); h.w = f2bf(s[3]);
    *(ushort4*)&gred[(size_t)id * 4] = h;
}

// ---------------------------------------------------------------------------
// K_gcn (MFMA): per batch, 4 waves; 6 barrier-separated MFMA stages.
// ---------------------------------------------------------------------------
__global__ __launch_bounds__(256) void k_gcn(
    const unsigned short* __restrict__ gred, const unsigned short* __restrict__ wbf,
    const float* __restrict__ b1a, const float* __restrict__ b1b,
    unsigned short* __restrict__ hc)
{
    __shared__ unsigned short G[128 * 72];
    __shared__ unsigned short HT[64 * 136];
    __shared__ unsigned short T2[64 * 136];
    const int b = blockIdx.x;
    const int t = threadIdx.x;
    const int lane = t & 63;
    const int w = t >> 6;
    const int lf = lane & 15;
    const int kg0 = (lane >> 4) * 8;
    const int r4 = (lane >> 4) * 4;

    const unsigned short* w1a = wbf;
    const unsigned short* w2a = wbf + 4096;
    const unsigned short* w1b = wbf + 20480;
    const unsigned short* w2b = wbf + 24576;
    const unsigned short* fc2 = wbf + 40960;

    // ---- stage 0: load g (bf16) into padded LDS ----
    #pragma unroll
    for (int i = 0; i < 4; ++i) {
        const int chunk = t + i * 256;        // 0..1023, 8 ush each
        const u16x8 v = *(const u16x8*)(gred + (size_t)b * (S_ * N_) + chunk * 8);
        const int s = chunk >> 3, n = (chunk & 7) * 8;
        *(u16x8*)&G[s * 72 + n] = v;
    }
    __syncthreads();

    for (int pass = 0; pass < 2; ++pass) {
        const unsigned short* w1 = pass ? w1b : w1a;
        const unsigned short* w2 = pass ? w2b : w2a;
        const float* b1 = pass ? b1b : b1a;

        {   // node mix: Y[s,m]=sum_n G[s,n]*w1[m,n]; h=leaky(Y+b1+G) -> HT[m][s]
            f32x4 acc[2][4] = {};
            #pragma unroll
            for (int ks = 0; ks < 2; ++ks) {
                const int kg = ks * 32 + kg0;
                bf16x8 a[2], bv[4];
                #pragma unroll
                for (int mi = 0; mi < 2; ++mi)
                    a[mi] = *(const bf16x8*)&G[(w * 32 + mi * 16 + lf) * 72 + kg];
                #pragma unroll
                for (int ni = 0; ni < 4; ++ni)
                    bv[ni] = *(const bf16x8*)(w1 + (ni * 16 + lf) * 64 + kg);
                #pragma unroll
                for (int mi = 0; mi < 2; ++mi)
                    #pragma unroll
                    for (int ni = 0; ni < 4; ++ni)
                        acc[mi][ni] = __builtin_amdgcn_mfma_f32_16x16x32_bf16(a[mi], bv[ni], acc[mi][ni], 0, 0, 0);
            }
            #pragma unroll
            for (int mi = 0; mi < 2; ++mi) {
                const int s0 = w * 32 + mi * 16 + r4;
                #pragma unroll
                for (int ni = 0; ni < 4; ++ni) {
                    const int m = ni * 16 + lf;
                    const float bm = b1[m];
                    ushort4 pk;
                    #pragma unroll
                    for (int r = 0; r < 4; ++r) {
                        float v = acc[mi][ni][r] + bm + bf2f(G[(s0 + r) * 72 + m]);
                        v = v > 0.f ? v : 0.2f * v;
                        ((unsigned short*)&pk)[r] = f2bf(v);
                    }
                    *(ushort4*)&HT[m * 136 + s0] = pk;
                }
            }
        }
        __syncthreads();

        {   // state mix: Z[t,m] = sum_s w2[t,s]*h[s,m]
            f32x4 acc[2][4] = {};
            #pragma unroll
            for (int ks = 0; ks < 4; ++ks) {
                const int kg = ks * 32 + kg0;
                bf16x8 a[2], bv[4];
                #pragma unroll
                for (int mi = 0; mi < 2; ++mi)
                    a[mi] = *(const bf16x8*)(w2 + (w * 32 + mi * 16 + lf) * 128 + kg);
                #pragma unroll
                for (int ni = 0; ni < 4; ++ni)
                    bv[ni] = *(const bf16x8*)&HT[(ni * 16 + lf) * 136 + kg];
                #pragma unroll
                for (int mi = 0; mi < 2; ++mi)
                    #pragma unroll
                    for (int ni = 0; ni < 4; ++ni)
                        acc[mi][ni] = __builtin_amdgcn_mfma_f32_16x16x32_bf16(a[mi], bv[ni], acc[mi][ni], 0, 0, 0);
            }
            if (pass == 0) {
                #pragma unroll
                for (int mi = 0; mi < 2; ++mi) {
                    const int t0 = w * 32 + mi * 16 + r4;
                    #pragma unroll
                    for (int ni = 0; ni < 4; ++ni) {
                        const int m = ni * 16 + lf;
                        #pragma unroll
                        for (int r = 0; r < 4; ++r)
                            G[(t0 + r) * 72 + m] = f2bf(acc[mi][ni][r]);
                    }
                }
            } else {
                #pragma unroll
                for (int mi = 0; mi < 2; ++mi) {
                    const int t0 = w * 32 + mi * 16 + r4;
                    #pragma unroll
                    for (int ni = 0; ni < 4; ++ni) {
                        const int m = ni * 16 + lf;
                        ushort4 pk;
                        #pragma unroll
                        for (int r = 0; r < 4; ++r)
                            ((unsigned short*)&pk)[r] = f2bf(acc[mi][ni][r]);
                        *(ushort4*)&T2[m * 136 + t0] = pk;
                    }
                }
            }
        }
        __syncthreads();
    }

    {   // fc2 fold: hc[c,n] = sum_t fc2[c,t]*g2[t,n]
        f32x4 acc[4][4] = {};
        #pragma unroll
        for (int ks = 0; ks < 4; ++ks) {
            const int kg = ks * 32 + kg0;
            bf16x8 a[4], bv[4];
            #pragma unroll
            for (int mi = 0; mi < 4; ++mi)
                a[mi] = *(const bf16x8*)(fc2 + (w * 64 + mi * 16 + lf) * 128 + kg);
            #pragma unroll
            for (int ni = 0; ni < 4; ++ni)
                bv[ni] = *(const bf16x8*)&T2[(ni * 16 + lf) * 136 + kg];
            #pragma unroll
            for (int mi = 0; mi < 4; ++mi)
                #pragma unroll
                for (int ni = 0; ni < 4; ++ni)
                    acc[mi][ni] = __builtin_amdgcn_mfma_f32_16x16x32_bf16(a[mi], bv[ni], acc[mi][ni], 0, 0, 0);
        }
        #pragma unroll
        for (int mi = 0; mi < 4; ++mi) {
            const int c0 = w * 64 + mi * 16 + r4;
            #pragma unroll
            for (int ni = 0; ni < 4; ++ni) {
                const int n = ni * 16 + lf;
                #pragma unroll
                for (int r = 0; r < 4; ++r)
                    hc[((size_t)b * 256 + c0 + r) * 64 + n] = f2bf(acc[mi][ni][r]);
            }
        }
    }
}

// ---------------------------------------------------------------------------
// K3: out[b][c][l] = x[b][c][l] + oscale[c]*(sum_n hc[b][c][n]*xr[n][l]) + obeta[c]
// D[l][c] operand-swap; 8-deep x prefetch issued before the barrier so HBM
// latency hides under MFMA.
// ---------------------------------------------------------------------------
__global__ __launch_bounds__(256) void k3_out(
    const float* __restrict__ x, const unsigned short* __restrict__ hc,
    const unsigned short* __restrict__ xrt,
    const float* __restrict__ oscale, const float* __restrict__ obeta,
    float* __restrict__ out)
{
    __shared__ unsigned short Alds[128 * 72];  // hc  [128 c][64 n] pad 72
    __shared__ unsigned short Blds[128 * 72];  // xrt [128 l][64 n] pad 72
    const int t = threadIdx.x;
    const int lane = t & 63;
    const int w = t >> 6;
    const int wr = w >> 1, wc = w & 1;
    const int l0 = blockIdx.x * 128;
    const int moff = blockIdx.y * 128;
    const int b = blockIdx.z;
    const int lf = lane & 15;
    const int r4 = (lane >> 4) * 4;
    {
        const int rr = t >> 3;        // 0..31
        const int nq = (t & 7) * 8;
        #pragma unroll
        for (int i = 0; i < 4; ++i) {
            const int r = rr + 32 * i;
            *(u16x8*)&Alds[r * 72 + nq] =
                *(const u16x8*)(hc + ((size_t)b * 256 + moff + r) * 64 + nq);
            *(u16x8*)&Blds[r * 72 + nq] =
                *(const u16x8*)(xrt + ((size_t)b * HW_ + l0 + r) * 64 + nq);
        }
    }
    // prefetch x for ni = 0..1 epilogue rows (issued before barrier)
    f32x4 xpre[8];
    #pragma unroll
    for (int p = 0; p < 8; ++p) {
        const int ni = p >> 2, mi = p & 3;
        const int c = moff + wr * 64 + ni * 16 + lf;
        const int l = l0 + wc * 64 + mi * 16 + r4;
        xpre[p] = *(const f32x4*)(x + ((size_t)b * 256 + c) * HW_ + l);
    }
    __syncthreads();
    f32x4 acc[4][4] = {};   // [mi = l][ni = c]
    #pragma unroll
    for (int ks = 0; ks < 2; ++ks) {
        const int kg = ks * 32 + (lane >> 4) * 8;
        bf16x8 al[4], bc[4];
        #pragma unroll
        for (int mi = 0; mi < 4; ++mi)
            al[mi] = *(const bf16x8*)&Blds[(wc * 64 + mi * 16 + lf) * 72 + kg];
        #pragma unroll
        for (int ni = 0; ni < 4; ++ni)
            bc[ni] = *(const bf16x8*)&Alds[(wr * 64 + ni * 16 + lf) * 72 + kg];
        #pragma unroll
        for (int mi = 0; mi < 4; ++mi)
            #pragma unroll
            for (int ni = 0; ni < 4; ++ni)
                acc[mi][ni] = __builtin_amdgcn_mfma_f32_16x16x32_bf16(al[mi], bc[ni], acc[mi][ni], 0, 0, 0);
    }
    #pragma unroll
    for (int ni = 0; ni < 4; ++ni) {
        const int c = moff + wr * 64 + ni * 16 + lf;
        const float sc = oscale[c];
        const float bt = obeta[c];
        const size_t rowb = ((size_t)b * 256 + c) * HW_;
        #pragma unroll
        for (int mi = 0; mi < 4; ++mi) {
            const int l = l0 + wc * 64 + mi * 16 + r4;
            const f32x4 xv = (ni < 2) ? xpre[ni * 4 + mi]
                                      : *(const f32x4*)(x + rowb + l);
            f32x4 o;
            #pragma unroll
            for (int r = 0; r < 4; ++r)
                o[r] = xv[r] + acc[mi][ni][r] * sc + bt;
            *(f32x4*)(out + rowb + l) = o;
        }
    }
}

// ---------------------------------------------------------------------------
extern "C" void kernel_launch(void* const* d_in, const int* in_sizes, int n_in,
                              void* d_out, int out_size, void* d_ws, size_t ws_size,
                              hipStream_t stream) {
    (void)in_sizes; (void)n_in; (void)out_size;
    const float* x     = (const float*)d_in[0];
    const float* w_s   = (const float*)d_in[1];
    const float* b_s   = (const float*)d_in[2];
    const float* g_s   = (const float*)d_in[3];
    const float* bb_s  = (const float*)d_in[4];
    const float* m_s   = (const float*)d_in[5];
    const float* v_s   = (const float*)d_in[6];
    const float* w_p   = (const float*)d_in[7];
    const float* b_p   = (const float*)d_in[8];
    const float* g_p   = (const float*)d_in[9];
    const float* bb_p  = (const float*)d_in[10];
    const float* m_p   = (const float*)d_in[11];
    const float* v_p   = (const float*)d_in[12];
    const float* w_r   = (const float*)d_in[13];
    const float* b_r   = (const float*)d_in[14];
    const float* g_r   = (const float*)d_in[15];
    const float* bb_r  = (const float*)d_in[16];
    const float* m_r   = (const float*)d_in[17];
    const float* v_r   = (const float*)d_in[18];
    const float* g1w1  = (const float*)d_in[19];
    const float* g1b1  = (const float*)d_in[20];
    const float* g1w2  = (const float*)d_in[21];
    const float* g2w1  = (const float*)d_in[22];
    const float* g2b1  = (const float*)d_in[23];
    const float* g2w2  = (const float*)d_in[24];
    const float* fc2w  = (const float*)d_in[25];
    const float* bn_og = (const float*)d_in[26];
    const float* bn_ob = (const float*)d_in[27];
    const float* bn_om = (const float*)d_in[28];
    const float* bn_ov = (const float*)d_in[29];

    char* ws = (char*)d_ws;
    unsigned short* Wc = (unsigned short*)(ws + 0);          // 131072 B
    float* pscale = (float*)(ws + 131072);
    float* pbeta  = (float*)(ws + 132096);
    float* oscale = (float*)(ws + 133120);
    float* obeta  = (float*)(ws + 134144);
    unsigned short* wbf = (unsigned short*)(ws + 135168);    // 147456 B
    const size_t o_fix = 135168 + 147456;                    // 282624
    const size_t sz_xrt = (size_t)B_ * HW_ * 64 * 2;         // 18,874,368
    const size_t sz_gr  = (size_t)B_ * S_ * N_ * 2;          //    262,144
    const size_t sz_hc  = (size_t)B_ * 256 * 64 * 2;         //    524,288
    const size_t sz_gp  = (size_t)LT_ * B_ * S_ * N_ * 4;    // 37,748,736
    const size_t need_full = o_fix + sz_xrt + sz_gr + sz_hc + sz_gp;

    unsigned short* xrt  = (unsigned short*)(ws + o_fix);
    unsigned short* gred = (unsigned short*)(ws + o_fix + sz_xrt);
    unsigned short* hc   = (unsigned short*)(ws + o_fix + sz_xrt + sz_gr);
    float* gpart;
    if (ws_size >= need_full)
        gpart = (float*)(ws + o_fix + sz_xrt + sz_gr + sz_hc);
    else  // fall back: gpart in d_out (fully consumed by kred before k3 writes out)
        gpart = (float*)d_out;

    k0_prep<<<256, 256, 0, stream>>>(
        w_s, w_p, w_r,
        b_s, g_s, bb_s, m_s, v_s,
        b_p, g_p, bb_p, m_p, v_p,
        b_r, g_r, bb_r, m_r, v_r,
        bn_og, bn_ob, bn_om, bn_ov,
        Wc, pscale, pbeta, oscale, obeta);

    k0b_wbf<<<288, 256, 0, stream>>>(g1w1, g1w2, g2w1, g2w2, fc2w, wbf);

    k1_fused<<<dim3(LT_, B_), 512, 0, stream>>>(x, Wc, pscale, pbeta, xrt, gpart);

    kred<<<256, 128, 0, stream>>>(gpart, gred);

    k_gcn<<<16, 256, 0, stream>>>(gred, wbf, g1b1, g2b1, hc);

    k3_out<<<dim3(72, 2, 16), 256, 0, stream>>>(x, hc, xrt, oscale, obeta, (float*)d_out);
}

// Round 6
// 193.482 us; speedup vs baseline: 2.1498x; 1.0233x over previous
//
#include <hip/hip_runtime.h>
#include <cstdint>
#include <cstddef>

#define B_ 16
#define C_ 256
#define HW_ 9216
#define S_ 128
#define N_ 64
#define LT_ 72          // number of 128-wide l tiles

typedef __attribute__((ext_vector_type(8))) short bf16x8;
typedef __attribute__((ext_vector_type(4))) float f32x4;
typedef __attribute__((ext_vector_type(8))) unsigned short u16x8;

// column-slot swizzle for Blds (stride 136): both b64 writes and b128 reads <=2-way
#define SWZ(ll) ((((((ll) >> 3) & 7) ^ ((((ll) >> 2) & 1) << 2)) << 3))

__device__ __forceinline__ unsigned short f2bf(float f) {
    unsigned int u = __builtin_bit_cast(unsigned int, f);
    u += 0x7fffu + ((u >> 16) & 1u);   // RNE; inputs are finite
    return (unsigned short)(u >> 16);
}
__device__ __forceinline__ float bf2f(unsigned short u) {
    unsigned int x = ((unsigned int)u) << 16;
    return __builtin_bit_cast(float, x);
}

// ---------------------------------------------------------------------------
// K0: fold conv bias + BN into per-channel (scale, beta); bf16 Wc[256][256];
// output-BN scale/beta.
// ---------------------------------------------------------------------------
__global__ void k0_prep(
    const float* __restrict__ w_s, const float* __restrict__ w_p, const float* __restrict__ w_r,
    const float* __restrict__ b_s, const float* __restrict__ g_s, const float* __restrict__ bb_s,
    const float* __restrict__ m_s, const float* __restrict__ v_s,
    const float* __restrict__ b_p, const float* __restrict__ g_p, const float* __restrict__ bb_p,
    const float* __restrict__ m_p, const float* __restrict__ v_p,
    const float* __restrict__ b_r, const float* __restrict__ g_r, const float* __restrict__ bb_r,
    const float* __restrict__ m_r, const float* __restrict__ v_r,
    const float* __restrict__ og, const float* __restrict__ ob,
    const float* __restrict__ om, const float* __restrict__ ov,
    unsigned short* __restrict__ Wc, float* __restrict__ pscale, float* __restrict__ pbeta,
    float* __restrict__ oscale, float* __restrict__ obeta)
{
    const int gid = blockIdx.x * 256 + threadIdx.x;   // 0..65535
    const int oc = gid >> 8, c = gid & 255;
    const float* wsrc;
    if (oc < 128)      wsrc = w_s + oc * 256;
    else if (oc < 192) wsrc = w_p + (oc - 128) * 256;
    else               wsrc = w_r + (oc - 192) * 256;
    Wc[gid] = f2bf(wsrc[c]);
    if (gid < 256) {
        int i; const float *bp, *gp, *bbp, *mp, *vp;
        if (gid < 128)      { i = gid;       bp = b_s; gp = g_s; bbp = bb_s; mp = m_s; vp = v_s; }
        else if (gid < 192) { i = gid - 128; bp = b_p; gp = g_p; bbp = bb_p; mp = m_p; vp = v_p; }
        else                { i = gid - 192; bp = b_r; gp = g_r; bbp = bb_r; mp = m_r; vp = v_r; }
        const float sc = gp[i] / sqrtf(vp[i] + 1e-5f);
        pscale[gid] = sc;
        pbeta[gid]  = (bp[i] - mp[i]) * sc + bbp[i];
        const float so = og[gid] / sqrtf(ov[gid] + 1e-5f);
        oscale[gid] = so;
        obeta[gid]  = ob[gid] - om[gid] * so;
    }
}

// ---------------------------------------------------------------------------
// K0b: bf16-ify the GCN + fc2 weights into one flat buffer.
// ---------------------------------------------------------------------------
__global__ void k0b_wbf(
    const float* __restrict__ g1w1, const float* __restrict__ g1w2,
    const float* __restrict__ g2w1, const float* __restrict__ g2w2,
    const float* __restrict__ fc2w, unsigned short* __restrict__ wbf)
{
    const int gid = blockIdx.x * 256 + threadIdx.x;   // 0..73727
    float v;
    if (gid < 4096)       v = g1w1[gid];
    else if (gid < 20480) v = g1w2[gid - 4096];
    else if (gid < 24576) v = g2w1[gid - 20480];
    else if (gid < 40960) v = g2w2[gid - 24576];
    else                  v = fc2w[gid - 40960];
    wbf[gid] = f2bf(v);
}

// ---------------------------------------------------------------------------
// K1_FUSED v2: per (l-tile, b):
//  phase 1: proj GEMM D[l][oc]: A = x^T from double-buffered LDS (1 barrier/kt,
//           swizzled), B = Wc fragments DIRECT FROM GLOBAL (L2-hot).
//  phase 2: BN+relu: wo<3 waves -> P[192 oc][128 l] LDS; wo=3 waves store
//           xrt[b][l][n] straight from accumulators (no LDS round-trip).
//  phase 3: gram partial gpart[lt][b][s][n] from P.
// ---------------------------------------------------------------------------
__global__ __launch_bounds__(512, 4) void k1_fused(
    const float* __restrict__ x, const unsigned short* __restrict__ Wc,
    const float* __restrict__ pscale, const float* __restrict__ pbeta,
    unsigned short* __restrict__ xrt, float* __restrict__ gpart)
{
    __shared__ unsigned short SH[2 * 128 * 136];   // 69632 B; P[192][136] aliases
    const int t = threadIdx.x;
    const int lane = t & 63;
    const int w = t >> 6;          // 0..7
    const int wl = w >> 2;         // 0..1  l wave (64 each)
    const int wo = w & 3;          // 0..3  oc wave (64 each)
    const int lt = blockIdx.x;
    const int b  = blockIdx.y;
    const int l0 = lt * 128;
    const float* xb = x + (size_t)b * C_ * HW_;
    const int lf = lane & 15;
    const int q4 = lane >> 4;
    const int kg0 = q4 * 8;
    const int r4 = q4 * 4;

    const int lq = t & 31;          // stage l-quad (l = lq*4)
    const int c0 = (t >> 5) * 4;    // stage c base 0..60
    const int swz_w = SWZ(lq * 4);  // write swizzle (constant per thread)

    f32x4 acc[4][4] = {};
    f32x4 Breg[4];

    // ---- prologue: stage kt=0 into buf0 ----
    #pragma unroll
    for (int j = 0; j < 4; ++j)
        Breg[j] = *(const f32x4*)(xb + (size_t)(c0 + j) * HW_ + l0 + lq * 4);
    #pragma unroll
    for (int r = 0; r < 4; ++r) {
        const int ll = lq * 4 + r;
        ushort4 wv;
        wv.x = f2bf(Breg[0][r]); wv.y = f2bf(Breg[1][r]);
        wv.z = f2bf(Breg[2][r]); wv.w = f2bf(Breg[3][r]);
        *(ushort4*)&SH[ll * 136 + (c0 ^ swz_w)] = wv;
    }
    __syncthreads();

    for (int kt = 0; kt < 4; ++kt) {
        const int cur = (kt & 1) * 128 * 136;
        // issue next tile's x loads early (hide under MFMA)
        if (kt < 3) {
            const int k0n = (kt + 1) * 64;
            #pragma unroll
            for (int j = 0; j < 4; ++j)
                Breg[j] = *(const f32x4*)(xb + (size_t)(k0n + c0 + j) * HW_ + l0 + lq * 4);
        }
        // MFMA: A = x^T rows (LDS), B = Wc rows (global, L2-hot)
        #pragma unroll
        for (int ks = 0; ks < 2; ++ks) {
            const int kg = ks * 32 + kg0;
            bf16x8 al[4], bo[4];
            #pragma unroll
            for (int mi = 0; mi < 4; ++mi) {
                const int ll = wl * 64 + mi * 16 + lf;
                al[mi] = *(const bf16x8*)&SH[cur + ll * 136 + (kg ^ SWZ(ll))];
            }
            #pragma unroll
            for (int ni = 0; ni < 4; ++ni)
                bo[ni] = *(const bf16x8*)(Wc + (wo * 64 + ni * 16 + lf) * 256 + kt * 64 + kg);
            #pragma unroll
            for (int mi = 0; mi < 4; ++mi)
                #pragma unroll
                for (int ni = 0; ni < 4; ++ni)
                    acc[mi][ni] = __builtin_amdgcn_mfma_f32_16x16x32_bf16(al[mi], bo[ni], acc[mi][ni], 0, 0, 0);
        }
        // stage next tile into the other buffer
        if (kt < 3) {
            const int nxt = ((kt + 1) & 1) * 128 * 136;
            #pragma unroll
            for (int r = 0; r < 4; ++r) {
                const int ll = lq * 4 + r;
                ushort4 wv;
                wv.x = f2bf(Breg[0][r]); wv.y = f2bf(Breg[1][r]);
                wv.z = f2bf(Breg[2][r]); wv.w = f2bf(Breg[3][r]);
                *(ushort4*)&SH[nxt + ll * 136 + (c0 ^ swz_w)] = wv;
            }
        }
        __syncthreads();
    }

    // ---- phase 2: BN + relu ----
    if (wo < 3) {          // xs/xp rows -> P[oc][l] (stride 136), vector writes
        #pragma unroll
        for (int ni = 0; ni < 4; ++ni) {
            const int oc = wo * 64 + ni * 16 + lf;
            const float sc = pscale[oc];
            const float bt = pbeta[oc];
            #pragma unroll
            for (int mi = 0; mi < 4; ++mi) {
                const int lcol = wl * 64 + mi * 16 + r4;
                ushort4 pk;
                #pragma unroll
                for (int r = 0; r < 4; ++r) {
                    float y = acc[mi][ni][r] * sc + bt;
                    y = y > 0.f ? y : 0.f;
                    ((unsigned short*)&pk)[r] = f2bf(y);
                }
                *(ushort4*)&SH[oc * 136 + lcol] = pk;
            }
        }
    } else {               // xr rows -> xrt[b][l][n] straight from acc
        #pragma unroll
        for (int ni = 0; ni < 4; ++ni) {
            const int oc = 192 + ni * 16 + lf;
            const float sc = pscale[oc];
            const float bt = pbeta[oc];
            const int n = ni * 16 + lf;
            #pragma unroll
            for (int mi = 0; mi < 4; ++mi) {
                const int lbase = wl * 64 + mi * 16 + r4;
                #pragma unroll
                for (int r = 0; r < 4; ++r) {
                    float y = acc[mi][ni][r] * sc + bt;
                    y = y > 0.f ? y : 0.f;
                    xrt[((size_t)b * HW_ + l0 + lbase + r) * 64 + n] = f2bf(y);
                }
            }
        }
    }
    __syncthreads();

    // ---- phase 3: gram partial  D[s][n] = sum_l P[s][l]*P[128+n][l] ----
    {
        const int ws_ = w >> 1;      // 0..3  s-wave (32 each)
        const int wn  = w & 1;       // 0..1  n-wave (32 each)
        f32x4 acc2[2][2] = {};
        #pragma unroll
        for (int ks = 0; ks < 4; ++ks) {
            const int kg = ks * 32 + kg0;
            bf16x8 sa[2], nb[2];
            #pragma unroll
            for (int mi = 0; mi < 2; ++mi) {
                const int row = ws_ * 32 + mi * 16 + lf;
                sa[mi] = *(const bf16x8*)&SH[row * 136 + kg];
            }
            #pragma unroll
            for (int ni = 0; ni < 2; ++ni) {
                const int row = 128 + wn * 32 + ni * 16 + lf;
                nb[ni] = *(const bf16x8*)&SH[row * 136 + kg];
            }
            #pragma unroll
            for (int mi = 0; mi < 2; ++mi)
                #pragma unroll
                for (int ni = 0; ni < 2; ++ni)
                    acc2[mi][ni] = __builtin_amdgcn_mfma_f32_16x16x32_bf16(sa[mi], nb[ni], acc2[mi][ni], 0, 0, 0);
        }
        float* gp = gpart + (size_t)(lt * 16 + b) * (S_ * N_);
        #pragma unroll
        for (int mi = 0; mi < 2; ++mi)
            #pragma unroll
            for (int ni = 0; ni < 2; ++ni) {
                const int n = wn * 32 + ni * 16 + lf;
                #pragma unroll
                for (int r = 0; r < 4; ++r) {
                    const int s = ws_ * 32 + mi * 16 + r4 + r;
                    gp[s * 64 + n] = acc2[mi][ni][r];
                }
            }
    }
}

// ---------------------------------------------------------------------------
// KRED: g[b][s*64+n] = (sum_lt gpart[lt][b][s*64+n]) / HW  -> bf16
// ---------------------------------------------------------------------------
__global__ __launch_bounds__(128) void kred(
    const float* __restrict__ gpart, unsigned short* __restrict__ gred)
{
    const int id = blockIdx.x * 128 + threadIdx.x;    // 0..32767, f32x4 units
    f32x4 s = {};
    const float* p = gpart + (size_t)id * 4;
    #pragma unroll 8
    for (int ltc = 0; ltc < LT_; ++ltc)
        s += *(const f32x4*)(p + (size_t)ltc * 16 * (S_ * N_));
    s *= (1.0f / (float)HW_);
    ushort4 h;
    h.x = f2bf(s[0]); h.y = f2bf(s[1]); h.z = f2bf(s[2]); h.w = f2bf(s[3]);
    *(ushort4*)&gred[(size_t)id * 4] = h;
}

// ---------------------------------------------------------------------------
// K_gcn (MFMA): per batch, 4 waves; 6 barrier-separated MFMA stages.
// ---------------------------------------------------------------------------
__global__ __launch_bounds__(256) void k_gcn(
    const unsigned short* __restrict__ gred, const unsigned short* __restrict__ wbf,
    const float* __restrict__ b1a, const float* __restrict__ b1b,
    unsigned short* __restrict__ hc)
{
    __shared__ unsigned short G[128 * 72];
    __shared__ unsigned short HT[64 * 136];
    __shared__ unsigned short T2[64 * 136];
    const int b = blockIdx.x;
    const int t = threadIdx.x;
    const int lane = t & 63;
    const int w = t >> 6;
    const int lf = lane & 15;
    const int kg0 = (lane >> 4) * 8;
    const int r4 = (lane >> 4) * 4;

    const unsigned short* w1a = wbf;
    const unsigned short* w2a = wbf + 4096;
    const unsigned short* w1b = wbf + 20480;
    const unsigned short* w2b = wbf + 24576;
    const unsigned short* fc2 = wbf + 40960;

    #pragma unroll
    for (int i = 0; i < 4; ++i) {
        const int chunk = t + i * 256;        // 0..1023, 8 ush each
        const u16x8 v = *(const u16x8*)(gred + (size_t)b * (S_ * N_) + chunk * 8);
        const int s = chunk >> 3, n = (chunk & 7) * 8;
        *(u16x8*)&G[s * 72 + n] = v;
    }
    __syncthreads();

    for (int pass = 0; pass < 2; ++pass) {
        const unsigned short* w1 = pass ? w1b : w1a;
        const unsigned short* w2 = pass ? w2b : w2a;
        const float* b1 = pass ? b1b : b1a;

        {   // node mix: Y[s,m]=sum_n G[s,n]*w1[m,n]; h=leaky(Y+b1+G) -> HT[m][s]
            f32x4 acc[2][4] = {};
            #pragma unroll
            for (int ks = 0; ks < 2; ++ks) {
                const int kg = ks * 32 + kg0;
                bf16x8 a[2], bv[4];
                #pragma unroll
                for (int mi = 0; mi < 2; ++mi)
                    a[mi] = *(const bf16x8*)&G[(w * 32 + mi * 16 + lf) * 72 + kg];
                #pragma unroll
                for (int ni = 0; ni < 4; ++ni)
                    bv[ni] = *(const bf16x8*)(w1 + (ni * 16 + lf) * 64 + kg);
                #pragma unroll
                for (int mi = 0; mi < 2; ++mi)
                    #pragma unroll
                    for (int ni = 0; ni < 4; ++ni)
                        acc[mi][ni] = __builtin_amdgcn_mfma_f32_16x16x32_bf16(a[mi], bv[ni], acc[mi][ni], 0, 0, 0);
            }
            #pragma unroll
            for (int mi = 0; mi < 2; ++mi) {
                const int s0 = w * 32 + mi * 16 + r4;
                #pragma unroll
                for (int ni = 0; ni < 4; ++ni) {
                    const int m = ni * 16 + lf;
                    const float bm = b1[m];
                    ushort4 pk;
                    #pragma unroll
                    for (int r = 0; r < 4; ++r) {
                        float v = acc[mi][ni][r] + bm + bf2f(G[(s0 + r) * 72 + m]);
                        v = v > 0.f ? v : 0.2f * v;
                        ((unsigned short*)&pk)[r] = f2bf(v);
                    }
                    *(ushort4*)&HT[m * 136 + s0] = pk;
                }
            }
        }
        __syncthreads();

        {   // state mix: Z[t,m] = sum_s w2[t,s]*h[s,m]
            f32x4 acc[2][4] = {};
            #pragma unroll
            for (int ks = 0; ks < 4; ++ks) {
                const int kg = ks * 32 + kg0;
                bf16x8 a[2], bv[4];
                #pragma unroll
                for (int mi = 0; mi < 2; ++mi)
                    a[mi] = *(const bf16x8*)(w2 + (w * 32 + mi * 16 + lf) * 128 + kg);
                #pragma unroll
                for (int ni = 0; ni < 4; ++ni)
                    bv[ni] = *(const bf16x8*)&HT[(ni * 16 + lf) * 136 + kg];
                #pragma unroll
                for (int mi = 0; mi < 2; ++mi)
                    #pragma unroll
                    for (int ni = 0; ni < 4; ++ni)
                        acc[mi][ni] = __builtin_amdgcn_mfma_f32_16x16x32_bf16(a[mi], bv[ni], acc[mi][ni], 0, 0, 0);
            }
            if (pass == 0) {
                #pragma unroll
                for (int mi = 0; mi < 2; ++mi) {
                    const int t0 = w * 32 + mi * 16 + r4;
                    #pragma unroll
                    for (int ni = 0; ni < 4; ++ni) {
                        const int m = ni * 16 + lf;
                        #pragma unroll
                        for (int r = 0; r < 4; ++r)
                            G[(t0 + r) * 72 + m] = f2bf(acc[mi][ni][r]);
                    }
                }
            } else {
                #pragma unroll
                for (int mi = 0; mi < 2; ++mi) {
                    const int t0 = w * 32 + mi * 16 + r4;
                    #pragma unroll
                    for (int ni = 0; ni < 4; ++ni) {
                        const int m = ni * 16 + lf;
                        ushort4 pk;
                        #pragma unroll
                        for (int r = 0; r < 4; ++r)
                            ((unsigned short*)&pk)[r] = f2bf(acc[mi][ni][r]);
                        *(ushort4*)&T2[m * 136 + t0] = pk;
                    }
                }
            }
        }
        __syncthreads();
    }

    {   // fc2 fold: hc[c,n] = sum_t fc2[c,t]*g2[t,n]
        f32x4 acc[4][4] = {};
        #pragma unroll
        for (int ks = 0; ks < 4; ++ks) {
            const int kg = ks * 32 + kg0;
            bf16x8 a[4], bv[4];
            #pragma unroll
            for (int mi = 0; mi < 4; ++mi)
                a[mi] = *(const bf16x8*)(fc2 + (w * 64 + mi * 16 + lf) * 128 + kg);
            #pragma unroll
            for (int ni = 0; ni < 4; ++ni)
                bv[ni] = *(const bf16x8*)&T2[(ni * 16 + lf) * 136 + kg];
            #pragma unroll
            for (int mi = 0; mi < 4; ++mi)
                #pragma unroll
                for (int ni = 0; ni < 4; ++ni)
                    acc[mi][ni] = __builtin_amdgcn_mfma_f32_16x16x32_bf16(a[mi], bv[ni], acc[mi][ni], 0, 0, 0);
        }
        #pragma unroll
        for (int mi = 0; mi < 4; ++mi) {
            const int c0 = w * 64 + mi * 16 + r4;
            #pragma unroll
            for (int ni = 0; ni < 4; ++ni) {
                const int n = ni * 16 + lf;
                #pragma unroll
                for (int r = 0; r < 4; ++r)
                    hc[((size_t)b * 256 + c0 + r) * 64 + n] = f2bf(acc[mi][ni][r]);
            }
        }
    }
}

// ---------------------------------------------------------------------------
// K3 v2 (no-LDS): out[b][c][l] = x[b][c][l] + oscale[c]*(hc[b][c,:]·xr[:,l]) + obeta[c]
// Both operands k(n)-contiguous in global -> fragments loaded directly
// (L2/L3-hot), zero LDS, zero barriers, D[l][c] swap for float4 epilogue.
// ---------------------------------------------------------------------------
__global__ __launch_bounds__(256) void k3_out(
    const float* __restrict__ x, const unsigned short* __restrict__ hc,
    const unsigned short* __restrict__ xrt,
    const float* __restrict__ oscale, const float* __restrict__ obeta,
    float* __restrict__ out)
{
    const int t = threadIdx.x;
    const int lane = t & 63;
    const int w = t >> 6;
    const int wr = w >> 1, wc = w & 1;
    const int l0 = blockIdx.x * 128;
    const int moff = blockIdx.y * 128;
    const int b = blockIdx.z;
    const int lf = lane & 15;
    const int q4 = lane >> 4;
    const int kg0 = q4 * 8;
    const int r4 = q4 * 4;

    const unsigned short* hb = hc + (size_t)b * 256 * 64 + (size_t)(moff + wr * 64) * 64;
    const unsigned short* xrb = xrt + ((size_t)b * HW_ + l0 + wc * 64) * 64;

    f32x4 acc[4][4] = {};   // [mi = l][ni = c]
    #pragma unroll
    for (int ks = 0; ks < 2; ++ks) {
        const int kg = ks * 32 + kg0;
        bf16x8 al[4], bc[4];
        #pragma unroll
        for (int mi = 0; mi < 4; ++mi)
            al[mi] = *(const bf16x8*)(xrb + (size_t)(mi * 16 + lf) * 64 + kg);
        #pragma unroll
        for (int ni = 0; ni < 4; ++ni)
            bc[ni] = *(const bf16x8*)(hb + (size_t)(ni * 16 + lf) * 64 + kg);
        #pragma unroll
        for (int mi = 0; mi < 4; ++mi)
            #pragma unroll
            for (int ni = 0; ni < 4; ++ni)
                acc[mi][ni] = __builtin_amdgcn_mfma_f32_16x16x32_bf16(al[mi], bc[ni], acc[mi][ni], 0, 0, 0);
    }
    #pragma unroll
    for (int ni = 0; ni < 4; ++ni) {
        const int c = moff + wr * 64 + ni * 16 + lf;
        const float sc = oscale[c];
        const float bt = obeta[c];
        const size_t rowb = ((size_t)b * 256 + c) * HW_;
        #pragma unroll
        for (int mi = 0; mi < 4; ++mi) {
            const int l = l0 + wc * 64 + mi * 16 + r4;
            const f32x4 xv = *(const f32x4*)(x + rowb + l);
            f32x4 o;
            #pragma unroll
            for (int r = 0; r < 4; ++r)
                o[r] = xv[r] + acc[mi][ni][r] * sc + bt;
            *(f32x4*)(out + rowb + l) = o;
        }
    }
}

// ---------------------------------------------------------------------------
extern "C" void kernel_launch(void* const* d_in, const int* in_sizes, int n_in,
                              void* d_out, int out_size, void* d_ws, size_t ws_size,
                              hipStream_t stream) {
    (void)in_sizes; (void)n_in; (void)out_size;
    const float* x     = (const float*)d_in[0];
    const float* w_s   = (const float*)d_in[1];
    const float* b_s   = (const float*)d_in[2];
    const float* g_s   = (const float*)d_in[3];
    const float* bb_s  = (const float*)d_in[4];
    const float* m_s   = (const float*)d_in[5];
    const float* v_s   = (const float*)d_in[6];
    const float* w_p   = (const float*)d_in[7];
    const float* b_p   = (const float*)d_in[8];
    const float* g_p   = (const float*)d_in[9];
    const float* bb_p  = (const float*)d_in[10];
    const float* m_p   = (const float*)d_in[11];
    const float* v_p   = (const float*)d_in[12];
    const float* w_r   = (const float*)d_in[13];
    const float* b_r   = (const float*)d_in[14];
    const float* g_r   = (const float*)d_in[15];
    const float* bb_r  = (const float*)d_in[16];
    const float* m_r   = (const float*)d_in[17];
    const float* v_r   = (const float*)d_in[18];
    const float* g1w1  = (const float*)d_in[19];
    const float* g1b1  = (const float*)d_in[20];
    const float* g1w2  = (const float*)d_in[21];
    const float* g2w1  = (const float*)d_in[22];
    const float* g2b1  = (const float*)d_in[23];
    const float* g2w2  = (const float*)d_in[24];
    const float* fc2w  = (const float*)d_in[25];
    const float* bn_og = (const float*)d_in[26];
    const float* bn_ob = (const float*)d_in[27];
    const float* bn_om = (const float*)d_in[28];
    const float* bn_ov = (const float*)d_in[29];

    char* ws = (char*)d_ws;
    unsigned short* Wc = (unsigned short*)(ws + 0);          // 131072 B
    float* pscale = (float*)(ws + 131072);
    float* pbeta  = (float*)(ws + 132096);
    float* oscale = (float*)(ws + 133120);
    float* obeta  = (float*)(ws + 134144);
    unsigned short* wbf = (unsigned short*)(ws + 135168);    // 147456 B
    const size_t o_fix = 135168 + 147456;                    // 282624
    const size_t sz_xrt = (size_t)B_ * HW_ * 64 * 2;         // 18,874,368
    const size_t sz_gr  = (size_t)B_ * S_ * N_ * 2;          //    262,144
    const size_t sz_hc  = (size_t)B_ * 256 * 64 * 2;         //    524,288
    const size_t sz_gp  = (size_t)LT_ * B_ * S_ * N_ * 4;    // 37,748,736
    const size_t need_full = o_fix + sz_xrt + sz_gr + sz_hc + sz_gp;

    unsigned short* xrt  = (unsigned short*)(ws + o_fix);
    unsigned short* gred = (unsigned short*)(ws + o_fix + sz_xrt);
    unsigned short* hc   = (unsigned short*)(ws + o_fix + sz_xrt + sz_gr);
    float* gpart;
    if (ws_size >= need_full)
        gpart = (float*)(ws + o_fix + sz_xrt + sz_gr + sz_hc);
    else  // fall back: gpart in d_out (fully consumed by kred before k3 writes out)
        gpart = (float*)d_out;

    k0_prep<<<256, 256, 0, stream>>>(
        w_s, w_p, w_r,
        b_s, g_s, bb_s, m_s, v_s,
        b_p, g_p, bb_p, m_p, v_p,
        b_r, g_r, bb_r, m_r, v_r,
        bn_og, bn_ob, bn_om, bn_ov,
        Wc, pscale, pbeta, oscale, obeta);

    k0b_wbf<<<288, 256, 0, stream>>>(g1w1, g1w2, g2w1, g2w2, fc2w, wbf);

    k1_fused<<<dim3(LT_, B_), 512, 0, stream>>>(x, Wc, pscale, pbeta, xrt, gpart);

    kred<<<256, 128, 0, stream>>>(gpart, gred);

    k_gcn<<<16, 256, 0, stream>>>(gred, wbf, g1b1, g2b1, hc);

    k3_out<<<dim3(72, 2, 16), 256, 0, stream>>>(x, hc, xrt, oscale, obeta, (float*)d_out);
}

// Round 7
// 183.893 us; speedup vs baseline: 2.2619x; 1.0521x over previous
//
#include <hip/hip_runtime.h>
#include <cstdint>
#include <cstddef>

#define B_ 16
#define C_ 256
#define HW_ 9216
#define S_ 128
#define N_ 64
#define LT_ 72          // number of 128-wide l tiles

typedef __attribute__((ext_vector_type(8))) short bf16x8;
typedef __attribute__((ext_vector_type(4))) float f32x4;
typedef __attribute__((ext_vector_type(8))) unsigned short u16x8;

__device__ __forceinline__ unsigned short f2bf(float f) {
    unsigned int u = __builtin_bit_cast(unsigned int, f);
    u += 0x7fffu + ((u >> 16) & 1u);   // RNE; inputs are finite
    return (unsigned short)(u >> 16);
}
__device__ __forceinline__ float bf2f(unsigned short u) {
    unsigned int x = ((unsigned int)u) << 16;
    return __builtin_bit_cast(float, x);
}

// ---------------------------------------------------------------------------
// K0: fold conv bias + BN into per-channel (scale, beta); bf16 Wc[256][256];
// output-BN scale/beta.
// ---------------------------------------------------------------------------
__global__ void k0_prep(
    const float* __restrict__ w_s, const float* __restrict__ w_p, const float* __restrict__ w_r,
    const float* __restrict__ b_s, const float* __restrict__ g_s, const float* __restrict__ bb_s,
    const float* __restrict__ m_s, const float* __restrict__ v_s,
    const float* __restrict__ b_p, const float* __restrict__ g_p, const float* __restrict__ bb_p,
    const float* __restrict__ m_p, const float* __restrict__ v_p,
    const float* __restrict__ b_r, const float* __restrict__ g_r, const float* __restrict__ bb_r,
    const float* __restrict__ m_r, const float* __restrict__ v_r,
    const float* __restrict__ og, const float* __restrict__ ob,
    const float* __restrict__ om, const float* __restrict__ ov,
    unsigned short* __restrict__ Wc, float* __restrict__ pscale, float* __restrict__ pbeta,
    float* __restrict__ oscale, float* __restrict__ obeta)
{
    const int gid = blockIdx.x * 256 + threadIdx.x;   // 0..65535
    const int oc = gid >> 8, c = gid & 255;
    const float* wsrc;
    if (oc < 128)      wsrc = w_s + oc * 256;
    else if (oc < 192) wsrc = w_p + (oc - 128) * 256;
    else               wsrc = w_r + (oc - 192) * 256;
    Wc[gid] = f2bf(wsrc[c]);
    if (gid < 256) {
        int i; const float *bp, *gp, *bbp, *mp, *vp;
        if (gid < 128)      { i = gid;       bp = b_s; gp = g_s; bbp = bb_s; mp = m_s; vp = v_s; }
        else if (gid < 192) { i = gid - 128; bp = b_p; gp = g_p; bbp = bb_p; mp = m_p; vp = v_p; }
        else                { i = gid - 192; bp = b_r; gp = g_r; bbp = bb_r; mp = m_r; vp = v_r; }
        const float sc = gp[i] / sqrtf(vp[i] + 1e-5f);
        pscale[gid] = sc;
        pbeta[gid]  = (bp[i] - mp[i]) * sc + bbp[i];
        const float so = og[gid] / sqrtf(ov[gid] + 1e-5f);
        oscale[gid] = so;
        obeta[gid]  = ob[gid] - om[gid] * so;
    }
}

// ---------------------------------------------------------------------------
// K0b: bf16-ify the GCN + fc2 weights into one flat buffer.
// ---------------------------------------------------------------------------
__global__ void k0b_wbf(
    const float* __restrict__ g1w1, const float* __restrict__ g1w2,
    const float* __restrict__ g2w1, const float* __restrict__ g2w2,
    const float* __restrict__ fc2w, unsigned short* __restrict__ wbf)
{
    const int gid = blockIdx.x * 256 + threadIdx.x;   // 0..73727
    float v;
    if (gid < 4096)       v = g1w1[gid];
    else if (gid < 20480) v = g1w2[gid - 4096];
    else if (gid < 24576) v = g2w1[gid - 20480];
    else if (gid < 40960) v = g2w2[gid - 24576];
    else                  v = fc2w[gid - 40960];
    wbf[gid] = f2bf(v);
}

// ---------------------------------------------------------------------------
// K1_FUSED v3: single-shot K=256 (no k-loop).
//  stage: ALL 16 x-loads upfront (full MLP) -> in-reg 4x4 transpose ->
//         one LDS write burst into x^T[128 l][264] bf16.  ONE barrier.
//  mfma : 8 ks x 16 MFMA unbroken; Wc fragments direct from global (L2-hot).
//  phase2: BN+relu -> P[192][136] in LDS; wo=3 wave stores xrt from acc.
//  phase3: gram partial -> gpart[lt][b][s][n].
//  3 barriers total; __launch_bounds__(512,2) so no VGPR cap pressure.
// ---------------------------------------------------------------------------
__global__ __launch_bounds__(512, 2) void k1_fused(
    const float* __restrict__ x, const unsigned short* __restrict__ Wc,
    const float* __restrict__ pscale, const float* __restrict__ pbeta,
    unsigned short* __restrict__ xrt, float* __restrict__ gpart)
{
    __shared__ unsigned short SH[128 * 264];   // 67584 B; P[192][136] aliases later
    const int t = threadIdx.x;
    const int lane = t & 63;
    const int w = t >> 6;          // 0..7
    const int wl = w >> 2;         // 0..1  l wave (64 each)
    const int wo = w & 3;          // 0..3  oc wave (64 each)
    const int lt = blockIdx.x;
    const int b  = blockIdx.y;
    const int l0 = lt * 128;
    const float* xb = x + (size_t)b * C_ * HW_;
    const int lf = lane & 15;
    const int q4 = lane >> 4;
    const int kg0 = q4 * 8;
    const int r4 = q4 * 4;

    const int c0 = (t & 15) * 4;   // stage c base (16 slots)
    const int lw = t >> 4;         // stage l-quad 0..31

    // ---- stage: all 16 global loads upfront (deep MLP, one latency hit) ----
    f32x4 Breg[4][4];
    #pragma unroll
    for (int kt = 0; kt < 4; ++kt)
        #pragma unroll
        for (int j = 0; j < 4; ++j)
            Breg[kt][j] = *(const f32x4*)(xb + (size_t)(kt * 64 + c0 + j) * HW_ + l0 + lw * 4);

    // in-reg 4x4 transpose -> bf16 -> x^T[l][c] (stride 264)
    #pragma unroll
    for (int kt = 0; kt < 4; ++kt)
        #pragma unroll
        for (int r = 0; r < 4; ++r) {
            ushort4 wv;
            wv.x = f2bf(Breg[kt][0][r]); wv.y = f2bf(Breg[kt][1][r]);
            wv.z = f2bf(Breg[kt][2][r]); wv.w = f2bf(Breg[kt][3][r]);
            *(ushort4*)&SH[(lw * 4 + r) * 264 + kt * 64 + c0] = wv;
        }
    __syncthreads();

    // ---- proj GEMM: D[l][oc], unbroken K=256 MFMA loop ----
    f32x4 acc[4][4] = {};
    #pragma unroll
    for (int ks = 0; ks < 8; ++ks) {
        const int kg = ks * 32 + kg0;
        bf16x8 al[4], bo[4];
        #pragma unroll
        for (int mi = 0; mi < 4; ++mi)
            al[mi] = *(const bf16x8*)&SH[(wl * 64 + mi * 16 + lf) * 264 + kg];
        #pragma unroll
        for (int ni = 0; ni < 4; ++ni)
            bo[ni] = *(const bf16x8*)(Wc + (wo * 64 + ni * 16 + lf) * 256 + kg);
        #pragma unroll
        for (int mi = 0; mi < 4; ++mi)
            #pragma unroll
            for (int ni = 0; ni < 4; ++ni)
                acc[mi][ni] = __builtin_amdgcn_mfma_f32_16x16x32_bf16(al[mi], bo[ni], acc[mi][ni], 0, 0, 0);
    }
    __syncthreads();

    // ---- phase 2: BN + relu ----
    if (wo < 3) {          // xs/xp rows -> P[oc][l] (stride 136), vector writes
        #pragma unroll
        for (int ni = 0; ni < 4; ++ni) {
            const int oc = wo * 64 + ni * 16 + lf;
            const float sc = pscale[oc];
            const float bt = pbeta[oc];
            #pragma unroll
            for (int mi = 0; mi < 4; ++mi) {
                const int lcol = wl * 64 + mi * 16 + r4;
                ushort4 pk;
                #pragma unroll
                for (int r = 0; r < 4; ++r) {
                    float y = acc[mi][ni][r] * sc + bt;
                    y = y > 0.f ? y : 0.f;
                    ((unsigned short*)&pk)[r] = f2bf(y);
                }
                *(ushort4*)&SH[oc * 136 + lcol] = pk;
            }
        }
    } else {               // xr rows -> xrt[b][l][n] straight from acc
        #pragma unroll
        for (int ni = 0; ni < 4; ++ni) {
            const int oc = 192 + ni * 16 + lf;
            const float sc = pscale[oc];
            const float bt = pbeta[oc];
            const int n = ni * 16 + lf;
            #pragma unroll
            for (int mi = 0; mi < 4; ++mi) {
                const int lbase = wl * 64 + mi * 16 + r4;
                #pragma unroll
                for (int r = 0; r < 4; ++r) {
                    float y = acc[mi][ni][r] * sc + bt;
                    y = y > 0.f ? y : 0.f;
                    xrt[((size_t)b * HW_ + l0 + lbase + r) * 64 + n] = f2bf(y);
                }
            }
        }
    }
    __syncthreads();

    // ---- phase 3: gram partial  D[s][n] = sum_l P[s][l]*P[128+n][l] ----
    {
        const int ws_ = w >> 1;      // 0..3  s-wave (32 each)
        const int wn  = w & 1;       // 0..1  n-wave (32 each)
        f32x4 acc2[2][2] = {};
        #pragma unroll
        for (int ks = 0; ks < 4; ++ks) {
            const int kg = ks * 32 + kg0;
            bf16x8 sa[2], nb[2];
            #pragma unroll
            for (int mi = 0; mi < 2; ++mi) {
                const int row = ws_ * 32 + mi * 16 + lf;
                sa[mi] = *(const bf16x8*)&SH[row * 136 + kg];
            }
            #pragma unroll
            for (int ni = 0; ni < 2; ++ni) {
                const int row = 128 + wn * 32 + ni * 16 + lf;
                nb[ni] = *(const bf16x8*)&SH[row * 136 + kg];
            }
            #pragma unroll
            for (int mi = 0; mi < 2; ++mi)
                #pragma unroll
                for (int ni = 0; ni < 2; ++ni)
                    acc2[mi][ni] = __builtin_amdgcn_mfma_f32_16x16x32_bf16(sa[mi], nb[ni], acc2[mi][ni], 0, 0, 0);
        }
        float* gp = gpart + (size_t)(lt * 16 + b) * (S_ * N_);
        #pragma unroll
        for (int mi = 0; mi < 2; ++mi)
            #pragma unroll
            for (int ni = 0; ni < 2; ++ni) {
                const int n = wn * 32 + ni * 16 + lf;
                #pragma unroll
                for (int r = 0; r < 4; ++r) {
                    const int s = ws_ * 32 + mi * 16 + r4 + r;
                    gp[s * 64 + n] = acc2[mi][ni][r];
                }
            }
    }
}

// ---------------------------------------------------------------------------
// KRED: g[b][s*64+n] = (sum_lt gpart[lt][b][s*64+n]) / HW  -> bf16
// ---------------------------------------------------------------------------
__global__ __launch_bounds__(128) void kred(
    const float* __restrict__ gpart, unsigned short* __restrict__ gred)
{
    const int id = blockIdx.x * 128 + threadIdx.x;    // 0..32767, f32x4 units
    f32x4 s = {};
    const float* p = gpart + (size_t)id * 4;
    #pragma unroll 8
    for (int ltc = 0; ltc < LT_; ++ltc)
        s += *(const f32x4*)(p + (size_t)ltc * 16 * (S_ * N_));
    s *= (1.0f / (float)HW_);
    ushort4 h;
    h.x = f2bf(s[0]); h.y = f2bf(s[1]); h.z = f2bf(s[2]); h.w = f2bf(s[3]);
    *(ushort4*)&gred[(size_t)id * 4] = h;
}

// ---------------------------------------------------------------------------
// K_gcn (MFMA): per batch, 4 waves; 6 barrier-separated MFMA stages.
// ---------------------------------------------------------------------------
__global__ __launch_bounds__(256) void k_gcn(
    const unsigned short* __restrict__ gred, const unsigned short* __restrict__ wbf,
    const float* __restrict__ b1a, const float* __restrict__ b1b,
    unsigned short* __restrict__ hc)
{
    __shared__ unsigned short G[128 * 72];
    __shared__ unsigned short HT[64 * 136];
    __shared__ unsigned short T2[64 * 136];
    const int b = blockIdx.x;
    const int t = threadIdx.x;
    const int lane = t & 63;
    const int w = t >> 6;
    const int lf = lane & 15;
    const int kg0 = (lane >> 4) * 8;
    const int r4 = (lane >> 4) * 4;

    const unsigned short* w1a = wbf;
    const unsigned short* w2a = wbf + 4096;
    const unsigned short* w1b = wbf + 20480;
    const unsigned short* w2b = wbf + 24576;
    const unsigned short* fc2 = wbf + 40960;

    #pragma unroll
    for (int i = 0; i < 4; ++i) {
        const int chunk = t + i * 256;        // 0..1023, 8 ush each
        const u16x8 v = *(const u16x8*)(gred + (size_t)b * (S_ * N_) + chunk * 8);
        const int s = chunk >> 3, n = (chunk & 7) * 8;
        *(u16x8*)&G[s * 72 + n] = v;
    }
    __syncthreads();

    for (int pass = 0; pass < 2; ++pass) {
        const unsigned short* w1 = pass ? w1b : w1a;
        const unsigned short* w2 = pass ? w2b : w2a;
        const float* b1 = pass ? b1b : b1a;

        {   // node mix: Y[s,m]=sum_n G[s,n]*w1[m,n]; h=leaky(Y+b1+G) -> HT[m][s]
            f32x4 acc[2][4] = {};
            #pragma unroll
            for (int ks = 0; ks < 2; ++ks) {
                const int kg = ks * 32 + kg0;
                bf16x8 a[2], bv[4];
                #pragma unroll
                for (int mi = 0; mi < 2; ++mi)
                    a[mi] = *(const bf16x8*)&G[(w * 32 + mi * 16 + lf) * 72 + kg];
                #pragma unroll
                for (int ni = 0; ni < 4; ++ni)
                    bv[ni] = *(const bf16x8*)(w1 + (ni * 16 + lf) * 64 + kg);
                #pragma unroll
                for (int mi = 0; mi < 2; ++mi)
                    #pragma unroll
                    for (int ni = 0; ni < 4; ++ni)
                        acc[mi][ni] = __builtin_amdgcn_mfma_f32_16x16x32_bf16(a[mi], bv[ni], acc[mi][ni], 0, 0, 0);
            }
            #pragma unroll
            for (int mi = 0; mi < 2; ++mi) {
                const int s0 = w * 32 + mi * 16 + r4;
                #pragma unroll
                for (int ni = 0; ni < 4; ++ni) {
                    const int m = ni * 16 + lf;
                    const float bm = b1[m];
                    ushort4 pk;
                    #pragma unroll
                    for (int r = 0; r < 4; ++r) {
                        float v = acc[mi][ni][r] + bm + bf2f(G[(s0 + r) * 72 + m]);
                        v = v > 0.f ? v : 0.2f * v;
                        ((unsigned short*)&pk)[r] = f2bf(v);
                    }
                    *(ushort4*)&HT[m * 136 + s0] = pk;
                }
            }
        }
        __syncthreads();

        {   // state mix: Z[t,m] = sum_s w2[t,s]*h[s,m]
            f32x4 acc[2][4] = {};
            #pragma unroll
            for (int ks = 0; ks < 4; ++ks) {
                const int kg = ks * 32 + kg0;
                bf16x8 a[2], bv[4];
                #pragma unroll
                for (int mi = 0; mi < 2; ++mi)
                    a[mi] = *(const bf16x8*)(w2 + (w * 32 + mi * 16 + lf) * 128 + kg);
                #pragma unroll
                for (int ni = 0; ni < 4; ++ni)
                    bv[ni] = *(const bf16x8*)&HT[(ni * 16 + lf) * 136 + kg];
                #pragma unroll
                for (int mi = 0; mi < 2; ++mi)
                    #pragma unroll
                    for (int ni = 0; ni < 4; ++ni)
                        acc[mi][ni] = __builtin_amdgcn_mfma_f32_16x16x32_bf16(a[mi], bv[ni], acc[mi][ni], 0, 0, 0);
            }
            if (pass == 0) {
                #pragma unroll
                for (int mi = 0; mi < 2; ++mi) {
                    const int t0 = w * 32 + mi * 16 + r4;
                    #pragma unroll
                    for (int ni = 0; ni < 4; ++ni) {
                        const int m = ni * 16 + lf;
                        #pragma unroll
                        for (int r = 0; r < 4; ++r)
                            G[(t0 + r) * 72 + m] = f2bf(acc[mi][ni][r]);
                    }
                }
            } else {
                #pragma unroll
                for (int mi = 0; mi < 2; ++mi) {
                    const int t0 = w * 32 + mi * 16 + r4;
                    #pragma unroll
                    for (int ni = 0; ni < 4; ++ni) {
                        const int m = ni * 16 + lf;
                        ushort4 pk;
                        #pragma unroll
                        for (int r = 0; r < 4; ++r)
                            ((unsigned short*)&pk)[r] = f2bf(acc[mi][ni][r]);
                        *(ushort4*)&T2[m * 136 + t0] = pk;
                    }
                }
            }
        }
        __syncthreads();
    }

    {   // fc2 fold: hc[c,n] = sum_t fc2[c,t]*g2[t,n]
        f32x4 acc[4][4] = {};
        #pragma unroll
        for (int ks = 0; ks < 4; ++ks) {
            const int kg = ks * 32 + kg0;
            bf16x8 a[4], bv[4];
            #pragma unroll
            for (int mi = 0; mi < 4; ++mi)
                a[mi] = *(const bf16x8*)(fc2 + (w * 64 + mi * 16 + lf) * 128 + kg);
            #pragma unroll
            for (int ni = 0; ni < 4; ++ni)
                bv[ni] = *(const bf16x8*)&T2[(ni * 16 + lf) * 136 + kg];
            #pragma unroll
            for (int mi = 0; mi < 4; ++mi)
                #pragma unroll
                for (int ni = 0; ni < 4; ++ni)
                    acc[mi][ni] = __builtin_amdgcn_mfma_f32_16x16x32_bf16(a[mi], bv[ni], acc[mi][ni], 0, 0, 0);
        }
        #pragma unroll
        for (int mi = 0; mi < 4; ++mi) {
            const int c0 = w * 64 + mi * 16 + r4;
            #pragma unroll
            for (int ni = 0; ni < 4; ++ni) {
                const int n = ni * 16 + lf;
                #pragma unroll
                for (int r = 0; r < 4; ++r)
                    hc[((size_t)b * 256 + c0 + r) * 64 + n] = f2bf(acc[mi][ni][r]);
            }
        }
    }
}

// ---------------------------------------------------------------------------
// K3 (no-LDS): out[b][c][l] = x[b][c][l] + oscale[c]*(hc[b][c,:]·xr[:,l]) + obeta[c]
// Fragments direct from global (L2/L3-hot), zero LDS/barriers, D[l][c] swap.
// ---------------------------------------------------------------------------
__global__ __launch_bounds__(256) void k3_out(
    const float* __restrict__ x, const unsigned short* __restrict__ hc,
    const unsigned short* __restrict__ xrt,
    const float* __restrict__ oscale, const float* __restrict__ obeta,
    float* __restrict__ out)
{
    const int t = threadIdx.x;
    const int lane = t & 63;
    const int w = t >> 6;
    const int wr = w >> 1, wc = w & 1;
    const int l0 = blockIdx.x * 128;
    const int moff = blockIdx.y * 128;
    const int b = blockIdx.z;
    const int lf = lane & 15;
    const int q4 = lane >> 4;
    const int kg0 = q4 * 8;
    const int r4 = q4 * 4;

    const unsigned short* hb = hc + (size_t)b * 256 * 64 + (size_t)(moff + wr * 64) * 64;
    const unsigned short* xrb = xrt + ((size_t)b * HW_ + l0 + wc * 64) * 64;

    f32x4 acc[4][4] = {};   // [mi = l][ni = c]
    #pragma unroll
    for (int ks = 0; ks < 2; ++ks) {
        const int kg = ks * 32 + kg0;
        bf16x8 al[4], bc[4];
        #pragma unroll
        for (int mi = 0; mi < 4; ++mi)
            al[mi] = *(const bf16x8*)(xrb + (size_t)(mi * 16 + lf) * 64 + kg);
        #pragma unroll
        for (int ni = 0; ni < 4; ++ni)
            bc[ni] = *(const bf16x8*)(hb + (size_t)(ni * 16 + lf) * 64 + kg);
        #pragma unroll
        for (int mi = 0; mi < 4; ++mi)
            #pragma unroll
            for (int ni = 0; ni < 4; ++ni)
                acc[mi][ni] = __builtin_amdgcn_mfma_f32_16x16x32_bf16(al[mi], bc[ni], acc[mi][ni], 0, 0, 0);
    }
    #pragma unroll
    for (int ni = 0; ni < 4; ++ni) {
        const int c = moff + wr * 64 + ni * 16 + lf;
        const float sc = oscale[c];
        const float bt = obeta[c];
        const size_t rowb = ((size_t)b * 256 + c) * HW_;
        #pragma unroll
        for (int mi = 0; mi < 4; ++mi) {
            const int l = l0 + wc * 64 + mi * 16 + r4;
            const f32x4 xv = *(const f32x4*)(x + rowb + l);
            f32x4 o;
            #pragma unroll
            for (int r = 0; r < 4; ++r)
                o[r] = xv[r] + acc[mi][ni][r] * sc + bt;
            *(f32x4*)(out + rowb + l) = o;
        }
    }
}

// ---------------------------------------------------------------------------
extern "C" void kernel_launch(void* const* d_in, const int* in_sizes, int n_in,
                              void* d_out, int out_size, void* d_ws, size_t ws_size,
                              hipStream_t stream) {
    (void)in_sizes; (void)n_in; (void)out_size;
    const float* x     = (const float*)d_in[0];
    const float* w_s   = (const float*)d_in[1];
    const float* b_s   = (const float*)d_in[2];
    const float* g_s   = (const float*)d_in[3];
    const float* bb_s  = (const float*)d_in[4];
    const float* m_s   = (const float*)d_in[5];
    const float* v_s   = (const float*)d_in[6];
    const float* w_p   = (const float*)d_in[7];
    const float* b_p   = (const float*)d_in[8];
    const float* g_p   = (const float*)d_in[9];
    const float* bb_p  = (const float*)d_in[10];
    const float* m_p   = (const float*)d_in[11];
    const float* v_p   = (const float*)d_in[12];
    const float* w_r   = (const float*)d_in[13];
    const float* b_r   = (const float*)d_in[14];
    const float* g_r   = (const float*)d_in[15];
    const float* bb_r  = (const float*)d_in[16];
    const float* m_r   = (const float*)d_in[17];
    const float* v_r   = (const float*)d_in[18];
    const float* g1w1  = (const float*)d_in[19];
    const float* g1b1  = (const float*)d_in[20];
    const float* g1w2  = (const float*)d_in[21];
    const float* g2w1  = (const float*)d_in[22];
    const float* g2b1  = (const float*)d_in[23];
    const float* g2w2  = (const float*)d_in[24];
    const float* fc2w  = (const float*)d_in[25];
    const float* bn_og = (const float*)d_in[26];
    const float* bn_ob = (const float*)d_in[27];
    const float* bn_om = (const float*)d_in[28];
    const float* bn_ov = (const float*)d_in[29];

    char* ws = (char*)d_ws;
    unsigned short* Wc = (unsigned short*)(ws + 0);          // 131072 B
    float* pscale = (float*)(ws + 131072);
    float* pbeta  = (float*)(ws + 132096);
    float* oscale = (float*)(ws + 133120);
    float* obeta  = (float*)(ws + 134144);
    unsigned short* wbf = (unsigned short*)(ws + 135168);    // 147456 B
    const size_t o_fix = 135168 + 147456;                    // 282624
    const size_t sz_xrt = (size_t)B_ * HW_ * 64 * 2;         // 18,874,368
    const size_t sz_gr  = (size_t)B_ * S_ * N_ * 2;          //    262,144
    const size_t sz_hc  = (size_t)B_ * 256 * 64 * 2;         //    524,288
    const size_t sz_gp  = (size_t)LT_ * B_ * S_ * N_ * 4;    // 37,748,736
    const size_t need_full = o_fix + sz_xrt + sz_gr + sz_hc + sz_gp;

    unsigned short* xrt  = (unsigned short*)(ws + o_fix);
    unsigned short* gred = (unsigned short*)(ws + o_fix + sz_xrt);
    unsigned short* hc   = (unsigned short*)(ws + o_fix + sz_xrt + sz_gr);
    float* gpart;
    if (ws_size >= need_full)
        gpart = (float*)(ws + o_fix + sz_xrt + sz_gr + sz_hc);
    else  // fall back: gpart in d_out (fully consumed by kred before k3 writes out)
        gpart = (float*)d_out;

    k0_prep<<<256, 256, 0, stream>>>(
        w_s, w_p, w_r,
        b_s, g_s, bb_s, m_s, v_s,
        b_p, g_p, bb_p, m_p, v_p,
        b_r, g_r, bb_r, m_r, v_r,
        bn_og, bn_ob, bn_om, bn_ov,
        Wc, pscale, pbeta, oscale, obeta);

    k0b_wbf<<<288, 256, 0, stream>>>(g1w1, g1w2, g2w1, g2w2, fc2w, wbf);

    k1_fused<<<dim3(LT_, B_), 512, 0, stream>>>(x, Wc, pscale, pbeta, xrt, gpart);

    kred<<<256, 128, 0, stream>>>(gpart, gred);

    k_gcn<<<16, 256, 0, stream>>>(gred, wbf, g1b1, g2b1, hc);

    k3_out<<<dim3(72, 2, 16), 256, 0, stream>>>(x, hc, xrt, oscale, obeta, (float*)d_out);
}

// Round 8
// 160.019 us; speedup vs baseline: 2.5994x; 1.1492x over previous
//
#include <hip/hip_runtime.h>
#include <cstdint>
#include <cstddef>

#define B_ 16
#define C_ 256
#define HW_ 9216
#define S_ 128
#define N_ 64
#define LT_ 144         // number of 64-wide l tiles
#define KSPLIT 12
#define LCHUNK 768

typedef __attribute__((ext_vector_type(8))) short bf16x8;
typedef __attribute__((ext_vector_type(4))) float f32x4;
typedef __attribute__((ext_vector_type(8))) unsigned short u16x8;

__device__ __forceinline__ unsigned short f2bf(float f) {
    unsigned int u = __builtin_bit_cast(unsigned int, f);
    u += 0x7fffu + ((u >> 16) & 1u);   // RNE; inputs are finite
    return (unsigned short)(u >> 16);
}
__device__ __forceinline__ float bf2f(unsigned short u) {
    unsigned int x = ((unsigned int)u) << 16;
    return __builtin_bit_cast(float, x);
}

// ---------------------------------------------------------------------------
// K0: fold conv bias + BN into (scale, beta); build FRAGMENT-ORDERED bf16
// weights Wcf[kchunk=32][oc=256][8]  (kchunk = c>>3) so k1's B-fragment loads
// are fully coalesced (16 lanes x 16B contiguous per 16-lane group).
// ---------------------------------------------------------------------------
__global__ void k0_prep(
    const float* __restrict__ w_s, const float* __restrict__ w_p, const float* __restrict__ w_r,
    const float* __restrict__ b_s, const float* __restrict__ g_s, const float* __restrict__ bb_s,
    const float* __restrict__ m_s, const float* __restrict__ v_s,
    const float* __restrict__ b_p, const float* __restrict__ g_p, const float* __restrict__ bb_p,
    const float* __restrict__ m_p, const float* __restrict__ v_p,
    const float* __restrict__ b_r, const float* __restrict__ g_r, const float* __restrict__ bb_r,
    const float* __restrict__ m_r, const float* __restrict__ v_r,
    const float* __restrict__ og, const float* __restrict__ ob,
    const float* __restrict__ om, const float* __restrict__ ov,
    unsigned short* __restrict__ Wcf, float* __restrict__ pscale, float* __restrict__ pbeta,
    float* __restrict__ oscale, float* __restrict__ obeta)
{
    const int gid = blockIdx.x * 256 + threadIdx.x;   // 0..65535
    const int oc = gid >> 8, c = gid & 255;
    const float* wsrc;
    if (oc < 128)      wsrc = w_s + oc * 256;
    else if (oc < 192) wsrc = w_p + (oc - 128) * 256;
    else               wsrc = w_r + (oc - 192) * 256;
    Wcf[(c >> 3) * 2048 + oc * 8 + (c & 7)] = f2bf(wsrc[c]);
    if (gid < 256) {
        int i; const float *bp, *gp, *bbp, *mp, *vp;
        if (gid < 128)      { i = gid;       bp = b_s; gp = g_s; bbp = bb_s; mp = m_s; vp = v_s; }
        else if (gid < 192) { i = gid - 128; bp = b_p; gp = g_p; bbp = bb_p; mp = m_p; vp = v_p; }
        else                { i = gid - 192; bp = b_r; gp = g_r; bbp = bb_r; mp = m_r; vp = v_r; }
        const float sc = gp[i] / sqrtf(vp[i] + 1e-5f);
        pscale[gid] = sc;
        pbeta[gid]  = (bp[i] - mp[i]) * sc + bbp[i];
        const float so = og[gid] / sqrtf(ov[gid] + 1e-5f);
        oscale[gid] = so;
        obeta[gid]  = ob[gid] - om[gid] * so;
    }
}

// ---------------------------------------------------------------------------
// K0b: bf16-ify the GCN + fc2 weights into one flat buffer.
// ---------------------------------------------------------------------------
__global__ void k0b_wbf(
    const float* __restrict__ g1w1, const float* __restrict__ g1w2,
    const float* __restrict__ g2w1, const float* __restrict__ g2w2,
    const float* __restrict__ fc2w, unsigned short* __restrict__ wbf)
{
    const int gid = blockIdx.x * 256 + threadIdx.x;   // 0..73727
    float v;
    if (gid < 4096)       v = g1w1[gid];
    else if (gid < 20480) v = g1w2[gid - 4096];
    else if (gid < 24576) v = g2w1[gid - 20480];
    else if (gid < 40960) v = g2w2[gid - 24576];
    else                  v = fc2w[gid - 40960];
    wbf[gid] = f2bf(v);
}

// ---------------------------------------------------------------------------
// K1 v4 (pure proj GEMM): 256 thr / 4 waves, l-tile 64, all 256 oc.
//  - x^T staged in double-buffered LDS [2][64][72], XOR-swizzled, 1 barrier/kt
//  - B fragments from Wcf global, fully coalesced
//  - epilogue: BN+relu; waves 0..2 -> P[192][72] LDS -> coalesced xsp stores;
//    wave 3 -> xrt direct from acc.
// ---------------------------------------------------------------------------
__global__ __launch_bounds__(256, 3) void k1_proj(
    const float* __restrict__ x, const unsigned short* __restrict__ Wcf,
    const float* __restrict__ pscale, const float* __restrict__ pbeta,
    unsigned short* __restrict__ xsp, unsigned short* __restrict__ xrt)
{
    __shared__ unsigned short SH[18432];      // 36864 B: dbuf[2][64][72]; P[192][72] alias
    const int t = threadIdx.x;
    const int lane = t & 63;
    const int w = t >> 6;          // 0..3 = oc quarter
    const int lt = blockIdx.x;
    const int b  = blockIdx.y;
    const int l0 = lt * 64;
    const float* xb = x + (size_t)b * C_ * HW_;
    const int lf = lane & 15;
    const int q4 = lane >> 4;
    const int kg0 = q4 * 8;
    const int r4 = q4 * 4;

    const int lq = t & 15;         // stage l-quad (l = lq*4)
    const int cs = t >> 4;         // stage c-slot (c0 = cs*4)
    const int c0 = cs * 4;

    f32x4 acc[4][4] = {};          // [mi = l][ni = oc]
    f32x4 Breg[4];

    // prologue loads kt=0
    #pragma unroll
    for (int j = 0; j < 4; ++j)
        Breg[j] = *(const f32x4*)(xb + (size_t)(c0 + j) * HW_ + l0 + lq * 4);

    for (int kt = 0; kt < 4; ++kt) {
        unsigned short* buf = SH + (kt & 1) * 4608;   // 64*72
        // stage: in-reg 4x4 transpose -> bf16, XOR-swizzled cols
        #pragma unroll
        for (int r = 0; r < 4; ++r) {
            const int ll = lq * 4 + r;
            ushort4 wv;
            wv.x = f2bf(Breg[0][r]); wv.y = f2bf(Breg[1][r]);
            wv.z = f2bf(Breg[2][r]); wv.w = f2bf(Breg[3][r]);
            *(ushort4*)&buf[ll * 72 + (c0 ^ ((lq & 7) << 3))] = wv;
        }
        __syncthreads();
        // issue next k-tile's loads (hide under MFMA)
        if (kt < 3) {
            const int k0n = (kt + 1) * 64;
            #pragma unroll
            for (int j = 0; j < 4; ++j)
                Breg[j] = *(const f32x4*)(xb + (size_t)(k0n + c0 + j) * HW_ + l0 + lq * 4);
        }
        // MFMA
        #pragma unroll
        for (int ks = 0; ks < 2; ++ks) {
            const int kg = ks * 32 + kg0;
            bf16x8 al[4], bo[4];
            #pragma unroll
            for (int mi = 0; mi < 4; ++mi) {
                const int rr = mi * 16 + lf;
                al[mi] = *(const bf16x8*)&buf[rr * 72 + (kg ^ (((rr >> 2) & 7) << 3))];
            }
            const int chunk = kt * 8 + ks * 4 + q4;
            #pragma unroll
            for (int ni = 0; ni < 4; ++ni)
                bo[ni] = *(const bf16x8*)(Wcf + (size_t)chunk * 2048 + (w * 64 + ni * 16 + lf) * 8);
            #pragma unroll
            for (int mi = 0; mi < 4; ++mi)
                #pragma unroll
                for (int ni = 0; ni < 4; ++ni)
                    acc[mi][ni] = __builtin_amdgcn_mfma_f32_16x16x32_bf16(al[mi], bo[ni], acc[mi][ni], 0, 0, 0);
        }
        __syncthreads();
    }

    // ---- epilogue: BN + relu ----
    if (w < 3) {          // P[oc 0..191][64 l] stride 72
        #pragma unroll
        for (int ni = 0; ni < 4; ++ni) {
            const int oc = w * 64 + ni * 16 + lf;
            const float sc = pscale[oc];
            const float bt = pbeta[oc];
            #pragma unroll
            for (int mi = 0; mi < 4; ++mi) {
                const int lcol = mi * 16 + r4;
                ushort4 pk;
                #pragma unroll
                for (int r = 0; r < 4; ++r) {
                    float y = acc[mi][ni][r] * sc + bt;
                    y = y > 0.f ? y : 0.f;
                    ((unsigned short*)&pk)[r] = f2bf(y);
                }
                *(ushort4*)&SH[oc * 72 + lcol] = pk;
            }
        }
    } else {              // xr -> xrt[b][l][n] straight from acc
        #pragma unroll
        for (int ni = 0; ni < 4; ++ni) {
            const int oc = 192 + ni * 16 + lf;
            const float sc = pscale[oc];
            const float bt = pbeta[oc];
            const int n = ni * 16 + lf;
            #pragma unroll
            for (int mi = 0; mi < 4; ++mi) {
                const int lbase = mi * 16 + r4;
                #pragma unroll
                for (int r = 0; r < 4; ++r) {
                    float y = acc[mi][ni][r] * sc + bt;
                    y = y > 0.f ? y : 0.f;
                    xrt[((size_t)b * HW_ + l0 + lbase + r) * 64 + n] = f2bf(y);
                }
            }
        }
    }
    __syncthreads();

    // ---- coalesced xsp stores (8 rows x 128B per wave) ----
    #pragma unroll
    for (int i = 0; i < 6; ++i) {
        const int id = t + i * 256;          // 0..1535
        const int row = id >> 3;             // 0..191
        const int c8 = (id & 7) * 8;         // 0..56
        const u16x8 v = *(const u16x8*)&SH[row * 72 + c8];
        *(u16x8*)(xsp + ((size_t)b * 192 + row) * HW_ + l0 + c8) = v;
    }
}

// ---------------------------------------------------------------------------
// K2: Gram partials.  gpart[ck][b][s][n] = sum over L-chunk of xs[s,l]*xp[n,l]
// ---------------------------------------------------------------------------
__global__ __launch_bounds__(256) void k2_gram(
    const unsigned short* __restrict__ xsp, float* __restrict__ gpart)
{
    __shared__ unsigned short As[128 * 136];  // xs [128 s][128 l] pad 136
    __shared__ unsigned short Bs[64 * 136];   // xp [ 64 n][128 l] pad 136
    const int t = threadIdx.x;
    const int lane = t & 63;
    const int w = t >> 6;
    const int ck = blockIdx.x;
    const int b = blockIdx.y;

    f32x4 acc[2][4] = {};

    for (int it = 0; it < 6; ++it) {
        const int lg = ck * LCHUNK + it * 128;
        {
            const int rr = t >> 4;
            const int lq2 = (t & 15) * 8;
            #pragma unroll
            for (int i = 0; i < 8; ++i) {
                const int s = rr + 16 * i;
                *(u16x8*)&As[s * 136 + lq2] =
                    *(const u16x8*)(xsp + ((size_t)b * 192 + s) * HW_ + lg + lq2);
            }
            #pragma unroll
            for (int i = 0; i < 4; ++i) {
                const int n = rr + 16 * i;
                *(u16x8*)&Bs[n * 136 + lq2] =
                    *(const u16x8*)(xsp + ((size_t)b * 192 + 128 + n) * HW_ + lg + lq2);
            }
        }
        __syncthreads();
        #pragma unroll
        for (int ks = 0; ks < 4; ++ks) {
            const int kg = ks * 32 + (lane >> 4) * 8;
            bf16x8 a[2], bv[4];
            #pragma unroll
            for (int mi = 0; mi < 2; ++mi)
                a[mi] = *(const bf16x8*)&As[(w * 32 + mi * 16 + (lane & 15)) * 136 + kg];
            #pragma unroll
            for (int ni = 0; ni < 4; ++ni)
                bv[ni] = *(const bf16x8*)&Bs[(ni * 16 + (lane & 15)) * 136 + kg];
            #pragma unroll
            for (int mi = 0; mi < 2; ++mi)
                #pragma unroll
                for (int ni = 0; ni < 4; ++ni)
                    acc[mi][ni] = __builtin_amdgcn_mfma_f32_16x16x32_bf16(a[mi], bv[ni], acc[mi][ni], 0, 0, 0);
        }
        __syncthreads();
    }
    float* gp = gpart + (size_t)(ck * 16 + b) * (S_ * N_);
    const int lf = lane & 15, r4 = (lane >> 4) * 4;
    #pragma unroll
    for (int mi = 0; mi < 2; ++mi)
        #pragma unroll
        for (int ni = 0; ni < 4; ++ni)
            #pragma unroll
            for (int r = 0; r < 4; ++r) {
                const int s = w * 32 + mi * 16 + r4 + r;
                const int n = ni * 16 + lf;
                gp[s * 64 + n] = acc[mi][ni][r];
            }
}

// ---------------------------------------------------------------------------
// KRED: g[b][s*64+n] = (sum_ck gpart[ck][b][s*64+n]) / HW  -> bf16
// ---------------------------------------------------------------------------
__global__ __launch_bounds__(128) void kred(
    const float* __restrict__ gpart, unsigned short* __restrict__ gred)
{
    const int id = blockIdx.x * 128 + threadIdx.x;    // 0..32767, f32x4 units
    f32x4 s = {};
    const float* p = gpart + (size_t)id * 4;
    #pragma unroll
    for (int ck = 0; ck < KSPLIT; ++ck)
        s += *(const f32x4*)(p + (size_t)ck * 16 * (S_ * N_));
    s *= (1.0f / (float)HW_);
    ushort4 h;
    h.x = f2bf(s[0]); h.y = f2bf(s[1]); h.z = f2bf(s[2]); h.w = f2bf(s[3]);
    *(ushort4*)&gred[(size_t)id * 4] = h;
}

// ---------------------------------------------------------------------------
// K_gcn (MFMA): per batch, 4 waves; 6 barrier-separated MFMA stages.
// ---------------------------------------------------------------------------
__global__ __launch_bounds__(256) void k_gcn(
    const unsigned short* __restrict__ gred, const unsigned short* __restrict__ wbf,
    const float* __restrict__ b1a, const float* __restrict__ b1b,
    unsigned short* __restrict__ hc)
{
    __shared__ unsigned short G[128 * 72];
    __shared__ unsigned short HT[64 * 136];
    __shared__ unsigned short T2[64 * 136];
    const int b = blockIdx.x;
    const int t = threadIdx.x;
    const int lane = t & 63;
    const int w = t >> 6;
    const int lf = lane & 15;
    const int kg0 = (lane >> 4) * 8;
    const int r4 = (lane >> 4) * 4;

    const unsigned short* w1a = wbf;
    const unsigned short* w2a = wbf + 4096;
    const unsigned short* w1b = wbf + 20480;
    const unsigned short* w2b = wbf + 24576;
    const unsigned short* fc2 = wbf + 40960;

    #pragma unroll
    for (int i = 0; i < 4; ++i) {
        const int chunk = t + i * 256;        // 0..1023, 8 ush each
        const u16x8 v = *(const u16x8*)(gred + (size_t)b * (S_ * N_) + chunk * 8);
        const int s = chunk >> 3, n = (chunk & 7) * 8;
        *(u16x8*)&G[s * 72 + n] = v;
    }
    __syncthreads();

    for (int pass = 0; pass < 2; ++pass) {
        const unsigned short* w1 = pass ? w1b : w1a;
        const unsigned short* w2 = pass ? w2b : w2a;
        const float* b1 = pass ? b1b : b1a;

        {   // node mix: Y[s,m]=sum_n G[s,n]*w1[m,n]; h=leaky(Y+b1+G) -> HT[m][s]
            f32x4 acc[2][4] = {};
            #pragma unroll
            for (int ks = 0; ks < 2; ++ks) {
                const int kg = ks * 32 + kg0;
                bf16x8 a[2], bv[4];
                #pragma unroll
                for (int mi = 0; mi < 2; ++mi)
                    a[mi] = *(const bf16x8*)&G[(w * 32 + mi * 16 + lf) * 72 + kg];
                #pragma unroll
                for (int ni = 0; ni < 4; ++ni)
                    bv[ni] = *(const bf16x8*)(w1 + (ni * 16 + lf) * 64 + kg);
                #pragma unroll
                for (int mi = 0; mi < 2; ++mi)
                    #pragma unroll
                    for (int ni = 0; ni < 4; ++ni)
                        acc[mi][ni] = __builtin_amdgcn_mfma_f32_16x16x32_bf16(a[mi], bv[ni], acc[mi][ni], 0, 0, 0);
            }
            #pragma unroll
            for (int mi = 0; mi < 2; ++mi) {
                const int s0 = w * 32 + mi * 16 + r4;
                #pragma unroll
                for (int ni = 0; ni < 4; ++ni) {
                    const int m = ni * 16 + lf;
                    const float bm = b1[m];
                    ushort4 pk;
                    #pragma unroll
                    for (int r = 0; r < 4; ++r) {
                        float v = acc[mi][ni][r] + bm + bf2f(G[(s0 + r) * 72 + m]);
                        v = v > 0.f ? v : 0.2f * v;
                        ((unsigned short*)&pk)[r] = f2bf(v);
                    }
                    *(ushort4*)&HT[m * 136 + s0] = pk;
                }
            }
        }
        __syncthreads();

        {   // state mix: Z[t,m] = sum_s w2[t,s]*h[s,m]
            f32x4 acc[2][4] = {};
            #pragma unroll
            for (int ks = 0; ks < 4; ++ks) {
                const int kg = ks * 32 + kg0;
                bf16x8 a[2], bv[4];
                #pragma unroll
                for (int mi = 0; mi < 2; ++mi)
                    a[mi] = *(const bf16x8*)(w2 + (w * 32 + mi * 16 + lf) * 128 + kg);
                #pragma unroll
                for (int ni = 0; ni < 4; ++ni)
                    bv[ni] = *(const bf16x8*)&HT[(ni * 16 + lf) * 136 + kg];
                #pragma unroll
                for (int mi = 0; mi < 2; ++mi)
                    #pragma unroll
                    for (int ni = 0; ni < 4; ++ni)
                        acc[mi][ni] = __builtin_amdgcn_mfma_f32_16x16x32_bf16(a[mi], bv[ni], acc[mi][ni], 0, 0, 0);
            }
            if (pass == 0) {
                #pragma unroll
                for (int mi = 0; mi < 2; ++mi) {
                    const int t0 = w * 32 + mi * 16 + r4;
                    #pragma unroll
                    for (int ni = 0; ni < 4; ++ni) {
                        const int m = ni * 16 + lf;
                        #pragma unroll
                        for (int r = 0; r < 4; ++r)
                            G[(t0 + r) * 72 + m] = f2bf(acc[mi][ni][r]);
                    }
                }
            } else {
                #pragma unroll
                for (int mi = 0; mi < 2; ++mi) {
                    const int t0 = w * 32 + mi * 16 + r4;
                    #pragma unroll
                    for (int ni = 0; ni < 4; ++ni) {
                        const int m = ni * 16 + lf;
                        ushort4 pk;
                        #pragma unroll
                        for (int r = 0; r < 4; ++r)
                            ((unsigned short*)&pk)[r] = f2bf(acc[mi][ni][r]);
                        *(ushort4*)&T2[m * 136 + t0] = pk;
                    }
                }
            }
        }
        __syncthreads();
    }

    {   // fc2 fold: hc[c,n] = sum_t fc2[c,t]*g2[t,n]
        f32x4 acc[4][4] = {};
        #pragma unroll
        for (int ks = 0; ks < 4; ++ks) {
            const int kg = ks * 32 + kg0;
            bf16x8 a[4], bv[4];
            #pragma unroll
            for (int mi = 0; mi < 4; ++mi)
                a[mi] = *(const bf16x8*)(fc2 + (w * 64 + mi * 16 + lf) * 128 + kg);
            #pragma unroll
            for (int ni = 0; ni < 4; ++ni)
                bv[ni] = *(const bf16x8*)&T2[(ni * 16 + lf) * 136 + kg];
            #pragma unroll
            for (int mi = 0; mi < 4; ++mi)
                #pragma unroll
                for (int ni = 0; ni < 4; ++ni)
                    acc[mi][ni] = __builtin_amdgcn_mfma_f32_16x16x32_bf16(a[mi], bv[ni], acc[mi][ni], 0, 0, 0);
        }
        #pragma unroll
        for (int mi = 0; mi < 4; ++mi) {
            const int c0 = w * 64 + mi * 16 + r4;
            #pragma unroll
            for (int ni = 0; ni < 4; ++ni) {
                const int n = ni * 16 + lf;
                #pragma unroll
                for (int r = 0; r < 4; ++r)
                    hc[((size_t)b * 256 + c0 + r) * 64 + n] = f2bf(acc[mi][ni][r]);
            }
        }
    }
}

// ---------------------------------------------------------------------------
// K3 (no-LDS): out[b][c][l] = x[b][c][l] + oscale[c]*(hc[b][c,:]·xr[:,l]) + obeta[c]
// ---------------------------------------------------------------------------
__global__ __launch_bounds__(256) void k3_out(
    const float* __restrict__ x, const unsigned short* __restrict__ hc,
    const unsigned short* __restrict__ xrt,
    const float* __restrict__ oscale, const float* __restrict__ obeta,
    float* __restrict__ out)
{
    const int t = threadIdx.x;
    const int lane = t & 63;
    const int w = t >> 6;
    const int wr = w >> 1, wc = w & 1;
    const int l0 = blockIdx.x * 128;
    const int moff = blockIdx.y * 128;
    const int b = blockIdx.z;
    const int lf = lane & 15;
    const int q4 = lane >> 4;
    const int kg0 = q4 * 8;
    const int r4 = q4 * 4;

    const unsigned short* hb = hc + (size_t)b * 256 * 64 + (size_t)(moff + wr * 64) * 64;
    const unsigned short* xrb = xrt + ((size_t)b * HW_ + l0 + wc * 64) * 64;

    f32x4 acc[4][4] = {};   // [mi = l][ni = c]
    #pragma unroll
    for (int ks = 0; ks < 2; ++ks) {
        const int kg = ks * 32 + kg0;
        bf16x8 al[4], bc[4];
        #pragma unroll
        for (int mi = 0; mi < 4; ++mi)
            al[mi] = *(const bf16x8*)(xrb + (size_t)(mi * 16 + lf) * 64 + kg);
        #pragma unroll
        for (int ni = 0; ni < 4; ++ni)
            bc[ni] = *(const bf16x8*)(hb + (size_t)(ni * 16 + lf) * 64 + kg);
        #pragma unroll
        for (int mi = 0; mi < 4; ++mi)
            #pragma unroll
            for (int ni = 0; ni < 4; ++ni)
                acc[mi][ni] = __builtin_amdgcn_mfma_f32_16x16x32_bf16(al[mi], bc[ni], acc[mi][ni], 0, 0, 0);
    }
    #pragma unroll
    for (int ni = 0; ni < 4; ++ni) {
        const int c = moff + wr * 64 + ni * 16 + lf;
        const float sc = oscale[c];
        const float bt = obeta[c];
        const size_t rowb = ((size_t)b * 256 + c) * HW_;
        #pragma unroll
        for (int mi = 0; mi < 4; ++mi) {
            const int l = l0 + wc * 64 + mi * 16 + r4;
            const f32x4 xv = *(const f32x4*)(x + rowb + l);
            f32x4 o;
            #pragma unroll
            for (int r = 0; r < 4; ++r)
                o[r] = xv[r] + acc[mi][ni][r] * sc + bt;
            *(f32x4*)(out + rowb + l) = o;
        }
    }
}

// ---------------------------------------------------------------------------
extern "C" void kernel_launch(void* const* d_in, const int* in_sizes, int n_in,
                              void* d_out, int out_size, void* d_ws, size_t ws_size,
                              hipStream_t stream) {
    (void)in_sizes; (void)n_in; (void)out_size;
    const float* x     = (const float*)d_in[0];
    const float* w_s   = (const float*)d_in[1];
    const float* b_s   = (const float*)d_in[2];
    const float* g_s   = (const float*)d_in[3];
    const float* bb_s  = (const float*)d_in[4];
    const float* m_s   = (const float*)d_in[5];
    const float* v_s   = (const float*)d_in[6];
    const float* w_p   = (const float*)d_in[7];
    const float* b_p   = (const float*)d_in[8];
    const float* g_p   = (const float*)d_in[9];
    const float* bb_p  = (const float*)d_in[10];
    const float* m_p   = (const float*)d_in[11];
    const float* v_p   = (const float*)d_in[12];
    const float* w_r   = (const float*)d_in[13];
    const float* b_r   = (const float*)d_in[14];
    const float* g_r   = (const float*)d_in[15];
    const float* bb_r  = (const float*)d_in[16];
    const float* m_r   = (const float*)d_in[17];
    const float* v_r   = (const float*)d_in[18];
    const float* g1w1  = (const float*)d_in[19];
    const float* g1b1  = (const float*)d_in[20];
    const float* g1w2  = (const float*)d_in[21];
    const float* g2w1  = (const float*)d_in[22];
    const float* g2b1  = (const float*)d_in[23];
    const float* g2w2  = (const float*)d_in[24];
    const float* fc2w  = (const float*)d_in[25];
    const float* bn_og = (const float*)d_in[26];
    const float* bn_ob = (const float*)d_in[27];
    const float* bn_om = (const float*)d_in[28];
    const float* bn_ov = (const float*)d_in[29];

    char* ws = (char*)d_ws;
    unsigned short* Wcf = (unsigned short*)(ws + 0);         // 131072 B
    float* pscale = (float*)(ws + 131072);
    float* pbeta  = (float*)(ws + 132096);
    float* oscale = (float*)(ws + 133120);
    float* obeta  = (float*)(ws + 134144);
    unsigned short* wbf = (unsigned short*)(ws + 135168);    // 147456 B
    const size_t o_fix = 135168 + 147456;                    // 282624
    const size_t sz_xsp = (size_t)B_ * 192 * HW_ * 2;        // 56,623,104
    const size_t sz_xrt = (size_t)B_ * HW_ * 64 * 2;         // 18,874,368
    const size_t sz_gp  = (size_t)KSPLIT * B_ * S_ * N_ * 4; //  6,291,456
    const size_t sz_gr  = (size_t)B_ * S_ * N_ * 2;          //    262,144
    const size_t sz_hc  = (size_t)B_ * 256 * 64 * 2;         //    524,288
    const size_t need_full = o_fix + sz_xsp + sz_xrt + sz_gp + sz_gr + sz_hc;

    unsigned short* xsp; size_t o2;
    if (ws_size >= need_full) { xsp = (unsigned short*)(ws + o_fix); o2 = o_fix + sz_xsp; }
    else { // fall back: stash xsp in d_out (fully consumed by k2 before k3 writes out)
        xsp = (unsigned short*)d_out; o2 = o_fix;
    }
    unsigned short* xrt  = (unsigned short*)(ws + o2);
    float* gpart         = (float*)(ws + o2 + sz_xrt);
    unsigned short* gred = (unsigned short*)(ws + o2 + sz_xrt + sz_gp);
    unsigned short* hc   = (unsigned short*)(ws + o2 + sz_xrt + sz_gp + sz_gr);

    k0_prep<<<256, 256, 0, stream>>>(
        w_s, w_p, w_r,
        b_s, g_s, bb_s, m_s, v_s,
        b_p, g_p, bb_p, m_p, v_p,
        b_r, g_r, bb_r, m_r, v_r,
        bn_og, bn_ob, bn_om, bn_ov,
        Wcf, pscale, pbeta, oscale, obeta);

    k0b_wbf<<<288, 256, 0, stream>>>(g1w1, g1w2, g2w1, g2w2, fc2w, wbf);

    k1_proj<<<dim3(LT_, B_), 256, 0, stream>>>(x, Wcf, pscale, pbeta, xsp, xrt);

    k2_gram<<<dim3(KSPLIT, B_), 256, 0, stream>>>(xsp, gpart);

    kred<<<256, 128, 0, stream>>>(gpart, gred);

    k_gcn<<<16, 256, 0, stream>>>(gred, wbf, g1b1, g2b1, hc);

    k3_out<<<dim3(72, 2, 16), 256, 0, stream>>>(x, hc, xrt, oscale, obeta, (float*)d_out);
}